// Round 10
// baseline (540.313 us; speedup 1.0000x reference)
//
#include <hip/hip_runtime.h>
#include <hip/hip_bf16.h>

#define HH 64
#define FF 128
#define CC 10
#define LL 4
#define MAXD 32        // LDS neighbor-table depth (tail loop handles deg>32)
#define BN_RSQRT 0.9999950000374997f   // 1/sqrt(1+1e-5)

typedef __hip_bfloat16 bf16;
using short8 = __attribute__((ext_vector_type(8))) short;
using f32x4  = __attribute__((ext_vector_type(4))) float;
using f32x2  = __attribute__((ext_vector_type(2))) float;

__device__ __forceinline__ float us2f(unsigned short u) {
    return __uint_as_float(((unsigned)u) << 16);
}
// RNE f32->bf16 bits (finite inputs)
__device__ __forceinline__ unsigned short f2bf(float v) {
    unsigned u = __float_as_uint(v);
    return (unsigned short)((u + 0x7FFFu + ((u >> 16) & 1u)) >> 16);
}

// ---------- fp8 pack/unpack (HW cvt on gfx950; software fallback) ----------
#if defined(__has_builtin)
#if __has_builtin(__builtin_amdgcn_cvt_pk_f32_fp8) && __has_builtin(__builtin_amdgcn_cvt_pk_fp8_f32)
#define FP8_HW 1
#endif
#endif

#ifdef FP8_HW
template <bool HIGH>
__device__ __forceinline__ f32x2 fp8_dec2(unsigned w) {
    return __builtin_amdgcn_cvt_pk_f32_fp8((int)w, HIGH);
}
__device__ __forceinline__ unsigned fp8_enc4(float f0, float f1, float f2, float f3) {
    int w = 0;
    w = __builtin_amdgcn_cvt_pk_fp8_f32(f0, f1, w, false);
    w = __builtin_amdgcn_cvt_pk_fp8_f32(f2, f3, w, true);
    return (unsigned)w;
}
#else
__device__ __forceinline__ float fp8_dec1(unsigned b) {
    unsigned s = (b & 0x80u) << 24;
    unsigned em = b & 0x7Fu;
    float mag;
    if (em >= 0x08u) mag = __uint_as_float((((em >> 3) + 120u) << 23) | ((em & 7u) << 20));
    else             mag = (float)em * (1.0f / 512.0f);
    return __uint_as_float(__float_as_uint(mag) | s);
}
template <bool HIGH>
__device__ __forceinline__ f32x2 fp8_dec2(unsigned w) {
    unsigned lo = HIGH ? ((w >> 16) & 0xffu) : (w & 0xffu);
    unsigned hi = HIGH ? ((w >> 24) & 0xffu) : ((w >> 8) & 0xffu);
    f32x2 r; r.x = fp8_dec1(lo); r.y = fp8_dec1(hi); return r;
}
__device__ __forceinline__ unsigned fp8_enc1(float v) {
    unsigned u = __float_as_uint(v);
    unsigned s = (u >> 24) & 0x80u;
    float a = fabsf(v);
    if (a >= 448.0f) return s | 0x7Eu;
    if (a < 0.015625f) {
        int m = (int)rintf(a * 512.0f);
        return s | (unsigned)m;
    }
    int e; float m = frexpf(a, &e);
    int E = e + 6;
    int mant = (int)rintf((m * 2.0f - 1.0f) * 8.0f);
    if (mant == 8) { mant = 0; ++E; }
    if (E > 15) return s | 0x7Eu;
    return s | (unsigned)(E << 3) | (unsigned)mant;
}
__device__ __forceinline__ unsigned fp8_enc4(float f0, float f1, float f2, float f3) {
    return fp8_enc1(f0) | (fp8_enc1(f1) << 8) | (fp8_enc1(f2) << 16) | (fp8_enc1(f3) << 24);
}
#endif

// ---------- weight fragment packing ----------
__global__ __launch_bounds__(256) void pack_weights_kernel(
    const float* __restrict__ W0, const float* __restrict__ convW1,
    const float* __restrict__ convW2, const float* __restrict__ Wl1,
    short* __restrict__ wf)
{
    int t = blockIdx.x * 256 + threadIdx.x;
    if (t >= 5632) return;
    const float* W;
    int l, tile, kc, out_idx;
    if (t < 1024) {
        int local = t; int fi = local >> 6; l = local & 63;
        tile = fi >> 2; kc = fi & 3;
        W = W0; out_idx = local;
    } else if (t < 5120) {
        int t2 = t - 1024;
        int m = t2 >> 9;
        int local = t2 & 511;
        int fi = local >> 6; l = local & 63;
        tile = fi >> 1; kc = fi & 1;
        int layer = m >> 1, g = m & 1;
        W = (g ? convW2 : convW1) + (size_t)layer * HH * HH;
        out_idx = 1024 + m * 512 + local;
    } else {
        int local = t - 5120;
        int fi = local >> 6; l = local & 63;
        tile = fi >> 1; kc = fi & 1;
        W = Wl1; out_idx = 5120 + local;
    }
    int k0 = kc * 32 + (l >> 4) * 8;
    int n = tile * 16 + (l & 15);
#pragma unroll
    for (int e = 0; e < 8; ++e)
        wf[out_idx * 8 + e] = (short)f2bf(W[(k0 + e) * HH + n]);
}

// ---------- lin0 (MFMA): h = relu(x @ W0 + b0), out fp8 ----------
__global__ __launch_bounds__(256) void lin0_kernel(
    const float* __restrict__ x, const short8* __restrict__ wf0,
    const float* __restrict__ b0, unsigned char* __restrict__ h, int nrows)
{
    __shared__ __align__(16) short lds_all[4][2048];   // per wave [16][128] bf16
    int wave = __builtin_amdgcn_readfirstlane(threadIdx.x >> 6);
    int lane = threadIdx.x & 63;
    char* ldsb = (char*)&lds_all[wave][0];
    int r0 = (blockIdx.x * 4 + wave) * 16;

#pragma unroll
    for (int r = 0; r < 16; ++r) {
        int row = r0 + r;
        float2 xv = make_float2(0.f, 0.f);
        if (row < nrows) xv = *(const float2*)(x + (size_t)row * FF + lane * 2);
        unsigned pk = (unsigned)f2bf(xv.x) | ((unsigned)f2bf(xv.y) << 16);
        *(int*)(ldsb + r * 256 + ((lane * 4) ^ ((r & 7) << 4))) = pk;
    }
    __syncthreads();

    short8 a[4];
#pragma unroll
    for (int kc = 0; kc < 4; ++kc) {
        int rr = lane & 15;
        a[kc] = *(const short8*)(ldsb + rr * 256 + (((kc * 64 + (lane >> 4) * 16)) ^ ((rr & 7) << 4)));
    }
    f32x4 acc[4];
#pragma unroll
    for (int tile = 0; tile < 4; ++tile) {
        acc[tile] = (f32x4){0.f, 0.f, 0.f, 0.f};
#pragma unroll
        for (int kc = 0; kc < 4; ++kc) {
            short8 b = wf0[(tile * 4 + kc) * 64 + lane];
            acc[tile] = __builtin_amdgcn_mfma_f32_16x16x32_bf16(a[kc], b, acc[tile], 0, 0, 0);
        }
    }
    __syncthreads();
#pragma unroll
    for (int tile = 0; tile < 4; ++tile) {
        int col = tile * 16 + (lane & 15);
        float bia = b0[col];
#pragma unroll
        for (int q = 0; q < 4; ++q) {
            int row = (lane >> 4) * 4 + q;
            float v = fmaxf(acc[tile][q] + bia, 0.0f);
            *(short*)(ldsb + row * 256 + ((col * 2) ^ ((row & 7) << 4))) = (short)f2bf(v);
        }
    }
    __syncthreads();
#pragma unroll
    for (int half = 0; half < 2; ++half) {
        int row = (lane >> 3) + half * 8;
        short8 vv = *(const short8*)(ldsb + row * 256 + ((((lane & 7) * 16)) ^ ((row & 7) << 4)));
        int grow = r0 + row;
        if (grow < nrows) {
            unsigned w0 = fp8_enc4(us2f((unsigned short)vv[0]), us2f((unsigned short)vv[1]),
                                   us2f((unsigned short)vv[2]), us2f((unsigned short)vv[3]));
            unsigned w1 = fp8_enc4(us2f((unsigned short)vv[4]), us2f((unsigned short)vv[5]),
                                   us2f((unsigned short)vv[6]), us2f((unsigned short)vv[7]));
            *(uint2*)(h + (size_t)grow * 64 + (lane & 7) * 8) = make_uint2(w0, w1);
        }
    }
}

// ---------- CSR build ----------
__global__ __launch_bounds__(256) void hist_kernel(
    const int* __restrict__ dst, int* __restrict__ deg, int nedges)
{
    int e = blockIdx.x * 256 + threadIdx.x;
    if (e < nedges) atomicAdd(&deg[dst[e]], 1);
}

__global__ __launch_bounds__(256) void scan_block_kernel(
    const int* __restrict__ deg, int* __restrict__ rowptr,
    int* __restrict__ partials, int n)
{
    __shared__ int sm[256];
    int tid = threadIdx.x;
    int i = blockIdx.x * 256 + tid;
    int v = (i < n) ? deg[i] : 0;
    sm[tid] = v;
    __syncthreads();
    for (int ofs = 1; ofs < 256; ofs <<= 1) {
        int t = (tid >= ofs) ? sm[tid - ofs] : 0;
        __syncthreads();
        sm[tid] += t;
        __syncthreads();
    }
    if (i < n) rowptr[i] = sm[tid] - v;
    if (tid == 255) partials[blockIdx.x] = sm[255];
}

__global__ __launch_bounds__(256) void scan_partials_kernel(int* partials, int nb)
{
    __shared__ int sm[256];
    __shared__ int carry;
    int tid = threadIdx.x;
    if (tid == 0) carry = 0;
    __syncthreads();
    for (int base = 0; base < nb; base += 256) {
        int i = base + tid;
        int v = (i < nb) ? partials[i] : 0;
        sm[tid] = v;
        __syncthreads();
        for (int ofs = 1; ofs < 256; ofs <<= 1) {
            int t = (tid >= ofs) ? sm[tid - ofs] : 0;
            __syncthreads();
            sm[tid] += t;
            __syncthreads();
        }
        int cbase = carry;
        int tot = sm[255];
        if (i < nb) partials[i] = sm[tid] - v + cbase;
        __syncthreads();
        if (tid == 0) carry = cbase + tot;
        __syncthreads();
    }
}

__global__ __launch_bounds__(256) void add_offsets_kernel(
    int* __restrict__ rowptr, const int* __restrict__ partials, int n)
{
    int i = blockIdx.x * 256 + threadIdx.x;
    if (i < n) rowptr[i] += partials[blockIdx.x];
}

// ---------- binned edge scatter (write-locality-friendly CSR fill) ----------
// bucket b = node range [b*128, (b+1)*128); its csr slots = [rowptr[b*128], next)
__global__ __launch_bounds__(256) void bcur_init_kernel(
    const int* __restrict__ rowptr, int* __restrict__ bcur, int nbuck)
{
    int b = blockIdx.x * 256 + threadIdx.x;
    if (b < nbuck) bcur[b] = rowptr[b << 7];
}

// scatter edges into bucket-ordered ebuf; entry = (dst&127)<<25 | src  (needs N < 2^25)
__global__ __launch_bounds__(256) void bin_kernel(
    const int* __restrict__ src, const int* __restrict__ dst,
    int* __restrict__ bcur, unsigned* __restrict__ ebuf, int nedges, int stride)
{
    int t = blockIdx.x * 256 + threadIdx.x;
    int e[4], d[4], pos[4];
    unsigned pk[4];
    bool ok[4];
#pragma unroll
    for (int i = 0; i < 4; ++i) {
        e[i] = t + i * stride;
        ok[i] = e[i] < nedges;
        d[i] = ok[i] ? dst[e[i]] : 0;
        int s = ok[i] ? src[e[i]] : 0;
        pk[i] = ((unsigned)(d[i] & 127) << 25) | (unsigned)s;
    }
#pragma unroll
    for (int i = 0; i < 4; ++i)
        pos[i] = ok[i] ? atomicAdd(&bcur[d[i] >> 7], 1) : 0;
#pragma unroll
    for (int i = 0; i < 4; ++i)
        if (ok[i]) ebuf[pos[i]] = pk[i];
}

// one workgroup per bucket: coalesced ebuf read, csr writes within a ~5KB window
__global__ __launch_bounds__(256) void place2_kernel(
    const unsigned* __restrict__ ebuf, const int* __restrict__ rowptr,
    int* __restrict__ deg, int* __restrict__ csr, int n, int nedges)
{
    int b = blockIdx.x;
    int base = rowptr[b << 7];
    int hin = (b + 1) << 7;
    int end = (hin < n) ? rowptr[hin] : nedges;
    int nb0 = b << 7;
    for (int i = base + threadIdx.x; i < end; i += 256) {
        unsigned pk = ebuf[i];
        int s = (int)(pk & 0x1FFFFFFu);
        int d = nb0 + (int)(pk >> 25);
        int slot = atomicAdd(&deg[d], 1);
        csr[rowptr[d] + slot] = s;
    }
}

// ---------- degree bucketing (counting sort, 64 bins) ----------
__global__ __launch_bounds__(256) void deg_hist_kernel(
    const int* __restrict__ deg, int* __restrict__ dhist, int n)
{
    __shared__ int lh[64];
    int tid = threadIdx.x;
    if (tid < 64) lh[tid] = 0;
    __syncthreads();
    int i = blockIdx.x * 256 + tid;
    if (i < n) atomicAdd(&lh[min(deg[i], 63)], 1);
    __syncthreads();
    if (tid < 64 && lh[tid]) atomicAdd(&dhist[tid], lh[tid]);
}

__global__ __launch_bounds__(64) void bucket_scan_kernel(
    const int* __restrict__ dhist, int* __restrict__ dcnt)
{
    __shared__ int sm[64];
    int t = threadIdx.x;
    sm[t] = dhist[t];
    __syncthreads();
    int acc = 0;
    for (int k = 0; k < t; ++k) acc += sm[k];
    dcnt[t] = acc;          // dcnt starts as the bucket base cursor
}

__global__ __launch_bounds__(256) void perm_place_kernel(
    const int* __restrict__ deg, int* __restrict__ dcnt,
    int* __restrict__ perm, int n)
{
    __shared__ int lh[64], lbase[64];
    int tid = threadIdx.x;
    if (tid < 64) lh[tid] = 0;
    __syncthreads();
    int i = blockIdx.x * 256 + tid;
    int b = 0;
    if (i < n) { b = min(deg[i], 63); atomicAdd(&lh[b], 1); }
    __syncthreads();
    if (tid < 64) {
        int cntb = lh[tid];
        if (cntb) lbase[tid] = atomicAdd(&dcnt[tid], cntb);
        lh[tid] = 0;
    }
    __syncthreads();
    if (i < n) {
        int r = atomicAdd(&lh[b], 1);
        perm[lbase[b] + r] = i;
    }
}

// ---------- fused MFMA layer, fp8 h, LDS neighbor table, zero-row padding ----------
template <int FINAL>
__global__ __launch_bounds__(256) void layer_kernel(
    const unsigned char* __restrict__ h, const int* __restrict__ rowptr,
    const int* __restrict__ deg, const int* __restrict__ csr,
    const int* __restrict__ perm,
    const short8* __restrict__ wfG1, const short8* __restrict__ wfG2,
    const float* __restrict__ b1, const float* __restrict__ g1, const float* __restrict__ bt1,
    const float* __restrict__ b2, const float* __restrict__ g2, const float* __restrict__ bt2,
    unsigned char* __restrict__ out, int nrows,
    const short8* __restrict__ wfL1, const float* __restrict__ bl1,
    const int* __restrict__ batch, float* __restrict__ pooled, float* __restrict__ cnt)
{
    __shared__ __align__(16) short lds_all[4][1024];     // per wave [16][64] bf16
    __shared__ int idx_tab[4][16][MAXD + 4];             // byte offsets; [MAXD] = self
    int wave = __builtin_amdgcn_readfirstlane(threadIdx.x >> 6);
    int lane = threadIdx.x & 63;
    char* ldsb = (char*)&lds_all[wave][0];
    int r0 = (blockIdx.x * 4 + wave) * 16;

    // ---- row metadata (scalar) + neighbor table fill ----
    int s16[16], c16[16], maxc = 0;
#pragma unroll
    for (int r = 0; r < 16; ++r) {
        int gi = r0 + r;
        int pr = nrows;                       // zero row for OOB
        int sv = 0, cv = 0;
        if (gi < nrows) {
            pr = perm ? perm[gi] : gi;
            sv = rowptr[pr]; cv = deg[pr];
        }
        pr = __builtin_amdgcn_readfirstlane(pr);
        s16[r] = __builtin_amdgcn_readfirstlane(sv);
        c16[r] = __builtin_amdgcn_readfirstlane(cv);
        maxc = max(maxc, c16[r]);
        int idxv = nrows;
        if (lane < c16[r]) idxv = csr[s16[r] + lane];
        idxv = min(max(idxv, 0), nrows) << 6;            // byte offset, clamped
        if (lane < MAXD) idx_tab[wave][r][lane] = idxv;
        if (lane == 0) idx_tab[wave][r][MAXD] = pr << 6; // self
    }

    int selrow = lane >> 4;          // row within 4-row group served by this lane
    int fq4 = (lane & 15) * 4;       // fp8 byte offset of this lane's feature quad
    int fq8 = fq4 * 2;               // bf16 byte offset

    // ---- self init (via table, zero-row padded: no masks) ----
    float zg[4][4];
#pragma unroll
    for (int g = 0; g < 4; ++g) {
        int bo = idx_tab[wave][g * 4 + selrow][MAXD];
        unsigned w = *(const unsigned*)(h + bo + fq4);
        f32x2 lo = fp8_dec2<false>(w), hi = fp8_dec2<true>(w);
        zg[g][0] = lo.x; zg[g][1] = lo.y; zg[g][2] = hi.x; zg[g][3] = hi.y;
    }

    // ---- gather main loop: all dummy slots read the zero row (cached) ----
    int jm = min(maxc, MAXD);
    for (int j0 = 0; j0 < jm; j0 += 4) {
        unsigned w[4][4];
#pragma unroll
        for (int jj = 0; jj < 4; ++jj) {
            int jcl = min(j0 + jj, MAXD - 1);
#pragma unroll
            for (int g = 0; g < 4; ++g) {
                int bo = idx_tab[wave][g * 4 + selrow][jcl];
                w[jj][g] = *(const unsigned*)(h + bo + fq4);
            }
        }
#pragma unroll
        for (int jj = 0; jj < 4; ++jj)
#pragma unroll
            for (int g = 0; g < 4; ++g) {
                f32x2 lo = fp8_dec2<false>(w[jj][g]), hi = fp8_dec2<true>(w[jj][g]);
                zg[g][0] += lo.x; zg[g][1] += lo.y; zg[g][2] += hi.x; zg[g][3] += hi.y;
            }
    }
    if (maxc > MAXD) {    // rare tail, scalar per row
#pragma unroll
        for (int g = 0; g < 4; ++g) {
#pragma unroll
            for (int q = 0; q < 4; ++q) {
                int r = g * 4 + q;
                for (int j = MAXD; j < c16[r]; ++j) {
                    int sn = csr[s16[r] + j];
                    sn = min(max(sn, 0), nrows - 1);
                    unsigned w = *(const unsigned*)(h + ((size_t)sn << 6) + fq4);
                    f32x2 lo = fp8_dec2<false>(w), hi = fp8_dec2<true>(w);
                    bool mine = (selrow == q);
                    zg[g][0] += mine ? lo.x : 0.f;
                    zg[g][1] += mine ? lo.y : 0.f;
                    zg[g][2] += mine ? hi.x : 0.f;
                    zg[g][3] += mine ? hi.y : 0.f;
                }
            }
        }
    }

    // ---- z -> LDS bf16 [16][64], XOR-swizzled ----
#pragma unroll
    for (int g = 0; g < 4; ++g) {
        int row = g * 4 + selrow;
        unsigned d0 = (unsigned)f2bf(zg[g][0]) | ((unsigned)f2bf(zg[g][1]) << 16);
        unsigned d1 = (unsigned)f2bf(zg[g][2]) | ((unsigned)f2bf(zg[g][3]) << 16);
        int off = (row * 128 + fq8) ^ ((row & 7) << 4);
        *(uint2*)(ldsb + off) = make_uint2(d0, d1);
    }
    __syncthreads();

    short8 a0, a1;
    f32x4 acc[4];
    // ---- GEMM1 + BN + ReLU ----
    {
        int rr = lane & 15;
        a0 = *(const short8*)(ldsb + rr * 128 + (((lane >> 4) * 16) ^ ((rr & 7) << 4)));
        a1 = *(const short8*)(ldsb + rr * 128 + ((64 + (lane >> 4) * 16) ^ ((rr & 7) << 4)));
    }
#pragma unroll
    for (int tile = 0; tile < 4; ++tile) {
        acc[tile] = (f32x4){0.f, 0.f, 0.f, 0.f};
        acc[tile] = __builtin_amdgcn_mfma_f32_16x16x32_bf16(a0, wfG1[(tile * 2 + 0) * 64 + lane], acc[tile], 0, 0, 0);
        acc[tile] = __builtin_amdgcn_mfma_f32_16x16x32_bf16(a1, wfG1[(tile * 2 + 1) * 64 + lane], acc[tile], 0, 0, 0);
    }
    __syncthreads();
#pragma unroll
    for (int tile = 0; tile < 4; ++tile) {
        int col = tile * 16 + (lane & 15);
        float sc = g1[col] * BN_RSQRT;
        float sh = fmaf(b1[col], sc, bt1[col]);
#pragma unroll
        for (int q = 0; q < 4; ++q) {
            int row = (lane >> 4) * 4 + q;
            float v = fmaxf(fmaf(acc[tile][q], sc, sh), 0.0f);
            *(short*)(ldsb + row * 128 + ((col * 2) ^ ((row & 7) << 4))) = (short)f2bf(v);
        }
    }
    __syncthreads();

    // ---- GEMM2 + BN + ReLU ----
    {
        int rr = lane & 15;
        a0 = *(const short8*)(ldsb + rr * 128 + (((lane >> 4) * 16) ^ ((rr & 7) << 4)));
        a1 = *(const short8*)(ldsb + rr * 128 + ((64 + (lane >> 4) * 16) ^ ((rr & 7) << 4)));
    }
#pragma unroll
    for (int tile = 0; tile < 4; ++tile) {
        acc[tile] = (f32x4){0.f, 0.f, 0.f, 0.f};
        acc[tile] = __builtin_amdgcn_mfma_f32_16x16x32_bf16(a0, wfG2[(tile * 2 + 0) * 64 + lane], acc[tile], 0, 0, 0);
        acc[tile] = __builtin_amdgcn_mfma_f32_16x16x32_bf16(a1, wfG2[(tile * 2 + 1) * 64 + lane], acc[tile], 0, 0, 0);
    }
    __syncthreads();
#pragma unroll
    for (int tile = 0; tile < 4; ++tile) {
        int col = tile * 16 + (lane & 15);
        float sc = g2[col] * BN_RSQRT;
        float sh = fmaf(b2[col], sc, bt2[col]);
#pragma unroll
        for (int q = 0; q < 4; ++q) {
            int row = (lane >> 4) * 4 + q;
            float v = fmaxf(fmaf(acc[tile][q], sc, sh), 0.0f);
            *(short*)(ldsb + row * 128 + ((col * 2) ^ ((row & 7) << 4))) = (short)f2bf(v);
        }
    }
    __syncthreads();

    if (FINAL == 0) {
        // fp8-pack + store (row index from table; zero row excluded by guard)
#pragma unroll
        for (int half = 0; half < 2; ++half) {
            int row = (lane >> 3) + half * 8;
            short8 vv = *(const short8*)(ldsb + row * 128 + ((((lane & 7) * 16)) ^ ((row & 7) << 4)));
            int ro = idx_tab[wave][row][MAXD];
            if (ro < (nrows << 6)) {
                unsigned w0 = fp8_enc4(us2f((unsigned short)vv[0]), us2f((unsigned short)vv[1]),
                                       us2f((unsigned short)vv[2]), us2f((unsigned short)vv[3]));
                unsigned w1 = fp8_enc4(us2f((unsigned short)vv[4]), us2f((unsigned short)vv[5]),
                                       us2f((unsigned short)vv[6]), us2f((unsigned short)vv[7]));
                *(uint2*)(out + ro + (lane & 7) * 8) = make_uint2(w0, w1);
            }
        }
    } else {
        // ---- GEMM3: relu(h4 @ Wl1 + bl1) ----
        {
            int rr = lane & 15;
            a0 = *(const short8*)(ldsb + rr * 128 + (((lane >> 4) * 16) ^ ((rr & 7) << 4)));
            a1 = *(const short8*)(ldsb + rr * 128 + ((64 + (lane >> 4) * 16) ^ ((rr & 7) << 4)));
        }
#pragma unroll
        for (int tile = 0; tile < 4; ++tile) {
            acc[tile] = (f32x4){0.f, 0.f, 0.f, 0.f};
            acc[tile] = __builtin_amdgcn_mfma_f32_16x16x32_bf16(a0, wfL1[(tile * 2 + 0) * 64 + lane], acc[tile], 0, 0, 0);
            acc[tile] = __builtin_amdgcn_mfma_f32_16x16x32_bf16(a1, wfL1[(tile * 2 + 1) * 64 + lane], acc[tile], 0, 0, 0);
        }
        __syncthreads();
#pragma unroll
        for (int tile = 0; tile < 4; ++tile) {
            int col = tile * 16 + (lane & 15);
            float bia = bl1[col];
#pragma unroll
            for (int q = 0; q < 4; ++q) {
                int row = (lane >> 4) * 4 + q;
                float v = fmaxf(acc[tile][q] + bia, 0.0f);
                *(short*)(ldsb + row * 128 + ((col * 2) ^ ((row & 7) << 4))) = (short)f2bf(v);
            }
        }
        __syncthreads();
        // ---- in-kernel mean-pool partials (natural order, batch sorted) ----
        float pacc = 0.0f;
        int curg = -1, rc = 0;
        for (int r = 0; r < 16; ++r) {
            int row = r0 + r;
            if (row >= nrows) break;
            float v = us2f(*(const unsigned short*)(ldsb + r * 128 + ((lane * 2) ^ ((r & 7) << 4))));
            int g = batch[row];
            if (g != curg) {
                if (curg >= 0) {
                    atomicAdd(&pooled[curg * HH + lane], pacc);
                    if (lane == 0) atomicAdd(&cnt[curg], (float)rc);
                }
                curg = g; pacc = v; rc = 1;
            } else { pacc += v; rc += 1; }
        }
        if (curg >= 0) {
            atomicAdd(&pooled[curg * HH + lane], pacc);
            if (lane == 0) atomicAdd(&cnt[curg], (float)rc);
        }
    }
}

__global__ __launch_bounds__(64) void head_kernel(
    const float* __restrict__ pooled, const float* __restrict__ cnt,
    const float* __restrict__ Wl2, const float* __restrict__ bl2,
    float* __restrict__ out, int ngraphs)
{
    int gidx = blockIdx.x * 64 + threadIdx.x;
    if (gidx >= ngraphs) return;
    float logits[CC];
#pragma unroll
    for (int c = 0; c < CC; ++c) logits[c] = bl2[c];
    float inv_n = 1.0f / fmaxf(cnt[gidx], 1.0f);
    for (int k = 0; k < HH; ++k) {
        float p = pooled[gidx * HH + k] * inv_n;
#pragma unroll
        for (int c = 0; c < CC; ++c) logits[c] = fmaf(p, Wl2[k * CC + c], logits[c]);
    }
    float m = logits[0];
#pragma unroll
    for (int c = 1; c < CC; ++c) m = fmaxf(m, logits[c]);
    float ssum = 0.0f;
#pragma unroll
    for (int c = 0; c < CC; ++c) { logits[c] = __expf(logits[c] - m); ssum += logits[c]; }
    float inv = 1.0f / ssum;
#pragma unroll
    for (int c = 0; c < CC; ++c) out[gidx * CC + c] = logits[c] * inv;
}

extern "C" void kernel_launch(void* const* d_in, const int* in_sizes, int n_in,
                              void* d_out, int out_size, void* d_ws, size_t ws_size,
                              hipStream_t stream) {
    const float* x      = (const float*)d_in[0];
    const int*   ei     = (const int*)  d_in[1];
    const int*   batch  = (const int*)  d_in[3];
    const float* W0     = (const float*)d_in[4];
    const float* b0     = (const float*)d_in[5];
    const float* convW1 = (const float*)d_in[6];
    const float* convb1 = (const float*)d_in[7];
    const float* convg1 = (const float*)d_in[8];
    const float* convbt1= (const float*)d_in[9];
    const float* convW2 = (const float*)d_in[10];
    const float* convb2 = (const float*)d_in[11];
    const float* convg2 = (const float*)d_in[12];
    const float* convbt2= (const float*)d_in[13];
    const float* Wl1    = (const float*)d_in[14];
    const float* bl1    = (const float*)d_in[15];
    const float* Wl2    = (const float*)d_in[16];
    const float* bl2    = (const float*)d_in[17];

    const int N = in_sizes[0] / FF;
    const int E = in_sizes[1] / 2;
    const int G = out_size / CC;

    const int* src = ei;
    const int* dst = ei + E;

    size_t off = 0;
    auto take = [&](size_t bytes) { size_t p = off; off = (off + bytes + 255) & ~255ULL; return p; };
    int NB = (N + 255) / 256;
    int EB = (E + 255) / 256;
    int nbuck = (N + 127) >> 7;
    size_t o_rowptr = take((size_t)N * 4);
    size_t o_deg    = take((size_t)N * 4);
    size_t o_csr    = take((size_t)(E > NB ? E : NB) * 4 + 512);
    size_t o_ebuf   = take((size_t)E * 4);
    size_t o_bcur   = take((size_t)nbuck * 4);
    size_t o_perm   = take((size_t)N * 4);
    size_t o_dhist  = take(64 * 4);
    size_t o_dcnt   = take(64 * 4);
    size_t o_pooled = take((size_t)G * HH * 4);
    size_t o_cnt    = take((size_t)G * 4);
    size_t o_wfrag  = take((size_t)5632 * 8 * 2);
    size_t o_hA     = take((size_t)(N + 1) * 64);
    size_t o_hB     = take((size_t)(N + 1) * 64);

    char* base = (char*)d_ws;
    int*      rowptr = (int*)(base + o_rowptr);
    int*      deg    = (int*)(base + o_deg);
    int*      csr    = (int*)(base + o_csr);
    unsigned* ebuf   = (unsigned*)(base + o_ebuf);
    int*      bcur   = (int*)(base + o_bcur);
    int*      perm   = (int*)(base + o_perm);
    int*      dhist  = (int*)(base + o_dhist);
    int*      dcnt   = (int*)(base + o_dcnt);
    float*    pooled = (float*)(base + o_pooled);
    float*    cnt    = (float*)(base + o_cnt);
    short*    wfrag  = (short*)(base + o_wfrag);
    short8*   wf8    = (short8*)wfrag;
    unsigned char* hA = (unsigned char*)(base + o_hA);
    unsigned char* hB = (unsigned char*)(base + o_hB);

    int tile_blocks = (N + 63) / 64;     // 4 waves x 16 rows

    // weight fragment packing
    pack_weights_kernel<<<22, 256, 0, stream>>>(W0, convW1, convW2, Wl1, wfrag);

    // CSR build: deg hist -> rowptr scan
    (void)hipMemsetAsync(deg, 0, (size_t)N * sizeof(int), stream);
    hist_kernel<<<EB, 256, 0, stream>>>(dst, deg, E);
    scan_block_kernel<<<NB, 256, 0, stream>>>(deg, rowptr, csr /*partials*/, N);
    scan_partials_kernel<<<1, 256, 0, stream>>>(csr, NB);
    add_offsets_kernel<<<NB, 256, 0, stream>>>(rowptr, csr, N);

    // binned two-phase edge scatter
    bcur_init_kernel<<<(nbuck + 255) / 256, 256, 0, stream>>>(rowptr, bcur, nbuck);
    (void)hipMemsetAsync(deg, 0, (size_t)N * sizeof(int), stream);
    {
        int stride = ((E + 3) / 4 + 255) & ~255;
        bin_kernel<<<stride / 256, 256, 0, stream>>>(src, dst, bcur, ebuf, E, stride);
    }
    place2_kernel<<<nbuck, 256, 0, stream>>>(ebuf, rowptr, deg, csr, N, E);

    // degree bucketing (uses restored deg)
    (void)hipMemsetAsync(dhist, 0, 64 * sizeof(int), stream);
    deg_hist_kernel<<<NB, 256, 0, stream>>>(deg, dhist, N);
    bucket_scan_kernel<<<1, 64, 0, stream>>>(dhist, dcnt);
    perm_place_kernel<<<NB, 256, 0, stream>>>(deg, dcnt, perm, N);

    // zero rows (index N) of both h buffers
    (void)hipMemsetAsync(hA + (size_t)N * 64, 0, 64, stream);
    (void)hipMemsetAsync(hB + (size_t)N * 64, 0, 64, stream);

    // lin0
    lin0_kernel<<<tile_blocks, 256, 0, stream>>>(x, wf8, b0, hA, N);

    // pooled/cnt init
    (void)hipMemsetAsync(pooled, 0, (size_t)G * HH * sizeof(float), stream);
    (void)hipMemsetAsync(cnt, 0, (size_t)G * sizeof(float), stream);

    // layers (ping-pong); 0..2 degree-bucketed, last natural + fused pool
    const unsigned char* hin = hA; unsigned char* hout = hB;
    const short8* wfL1 = wf8 + 5120;
    for (int l = 0; l < LL; ++l) {
        const short8* wfG1 = wf8 + 1024 + (size_t)(l * 2 + 0) * 512;
        const short8* wfG2 = wf8 + 1024 + (size_t)(l * 2 + 1) * 512;
        if (l < LL - 1) {
            layer_kernel<0><<<tile_blocks, 256, 0, stream>>>(
                hin, rowptr, deg, csr, perm, wfG1, wfG2,
                convb1 + l * HH, convg1 + l * HH, convbt1 + l * HH,
                convb2 + l * HH, convg2 + l * HH, convbt2 + l * HH,
                hout, N, nullptr, nullptr, nullptr, nullptr, nullptr);
        } else {
            layer_kernel<1><<<tile_blocks, 256, 0, stream>>>(
                hin, rowptr, deg, csr, nullptr, wfG1, wfG2,
                convb1 + l * HH, convg1 + l * HH, convbt1 + l * HH,
                convb2 + l * HH, convg2 + l * HH, convbt2 + l * HH,
                nullptr, N, wfL1, bl1, batch, pooled, cnt);
        }
        unsigned char* tswap = (unsigned char*)hin; hin = hout; hout = tswap;
    }

    head_kernel<<<(G + 63) / 64, 64, 0, stream>>>(pooled, cnt, Wl2, bl2, (float*)d_out, G);
}

// Round 11
// 329.445 us; speedup vs baseline: 1.6401x; 1.6401x over previous
//
#include <hip/hip_runtime.h>
#include <hip/hip_bf16.h>

#define HH 64
#define FF 128
#define CC 10
#define LL 4
#define MAXD 32        // LDS neighbor-table depth (tail loop handles deg>32)
#define BN_RSQRT 0.9999950000374997f   // 1/sqrt(1+1e-5)

typedef __hip_bfloat16 bf16;
using short8 = __attribute__((ext_vector_type(8))) short;
using f32x4  = __attribute__((ext_vector_type(4))) float;
using f32x2  = __attribute__((ext_vector_type(2))) float;

__device__ __forceinline__ float us2f(unsigned short u) {
    return __uint_as_float(((unsigned)u) << 16);
}
// RNE f32->bf16 bits (finite inputs)
__device__ __forceinline__ unsigned short f2bf(float v) {
    unsigned u = __float_as_uint(v);
    return (unsigned short)((u + 0x7FFFu + ((u >> 16) & 1u)) >> 16);
}

// ---------- fp8 pack/unpack (HW cvt on gfx950; software fallback) ----------
#if defined(__has_builtin)
#if __has_builtin(__builtin_amdgcn_cvt_pk_f32_fp8) && __has_builtin(__builtin_amdgcn_cvt_pk_fp8_f32)
#define FP8_HW 1
#endif
#endif

#ifdef FP8_HW
template <bool HIGH>
__device__ __forceinline__ f32x2 fp8_dec2(unsigned w) {
    return __builtin_amdgcn_cvt_pk_f32_fp8((int)w, HIGH);
}
__device__ __forceinline__ unsigned fp8_enc4(float f0, float f1, float f2, float f3) {
    int w = 0;
    w = __builtin_amdgcn_cvt_pk_fp8_f32(f0, f1, w, false);
    w = __builtin_amdgcn_cvt_pk_fp8_f32(f2, f3, w, true);
    return (unsigned)w;
}
#else
__device__ __forceinline__ float fp8_dec1(unsigned b) {
    unsigned s = (b & 0x80u) << 24;
    unsigned em = b & 0x7Fu;
    float mag;
    if (em >= 0x08u) mag = __uint_as_float((((em >> 3) + 120u) << 23) | ((em & 7u) << 20));
    else             mag = (float)em * (1.0f / 512.0f);
    return __uint_as_float(__float_as_uint(mag) | s);
}
template <bool HIGH>
__device__ __forceinline__ f32x2 fp8_dec2(unsigned w) {
    unsigned lo = HIGH ? ((w >> 16) & 0xffu) : (w & 0xffu);
    unsigned hi = HIGH ? ((w >> 24) & 0xffu) : ((w >> 8) & 0xffu);
    f32x2 r; r.x = fp8_dec1(lo); r.y = fp8_dec1(hi); return r;
}
__device__ __forceinline__ unsigned fp8_enc1(float v) {
    unsigned u = __float_as_uint(v);
    unsigned s = (u >> 24) & 0x80u;
    float a = fabsf(v);
    if (a >= 448.0f) return s | 0x7Eu;
    if (a < 0.015625f) {
        int m = (int)rintf(a * 512.0f);
        return s | (unsigned)m;
    }
    int e; float m = frexpf(a, &e);
    int E = e + 6;
    int mant = (int)rintf((m * 2.0f - 1.0f) * 8.0f);
    if (mant == 8) { mant = 0; ++E; }
    if (E > 15) return s | 0x7Eu;
    return s | (unsigned)(E << 3) | (unsigned)mant;
}
__device__ __forceinline__ unsigned fp8_enc4(float f0, float f1, float f2, float f3) {
    return fp8_enc1(f0) | (fp8_enc1(f1) << 8) | (fp8_enc1(f2) << 16) | (fp8_enc1(f3) << 24);
}
#endif

// ---------- weight fragment packing ----------
__global__ __launch_bounds__(256) void pack_weights_kernel(
    const float* __restrict__ W0, const float* __restrict__ convW1,
    const float* __restrict__ convW2, const float* __restrict__ Wl1,
    short* __restrict__ wf)
{
    int t = blockIdx.x * 256 + threadIdx.x;
    if (t >= 5632) return;
    const float* W;
    int l, tile, kc, out_idx;
    if (t < 1024) {
        int local = t; int fi = local >> 6; l = local & 63;
        tile = fi >> 2; kc = fi & 3;
        W = W0; out_idx = local;
    } else if (t < 5120) {
        int t2 = t - 1024;
        int m = t2 >> 9;
        int local = t2 & 511;
        int fi = local >> 6; l = local & 63;
        tile = fi >> 1; kc = fi & 1;
        int layer = m >> 1, g = m & 1;
        W = (g ? convW2 : convW1) + (size_t)layer * HH * HH;
        out_idx = 1024 + m * 512 + local;
    } else {
        int local = t - 5120;
        int fi = local >> 6; l = local & 63;
        tile = fi >> 1; kc = fi & 1;
        W = Wl1; out_idx = 5120 + local;
    }
    int k0 = kc * 32 + (l >> 4) * 8;
    int n = tile * 16 + (l & 15);
#pragma unroll
    for (int e = 0; e < 8; ++e)
        wf[out_idx * 8 + e] = (short)f2bf(W[(k0 + e) * HH + n]);
}

// ---------- lin0 (MFMA): h = relu(x @ W0 + b0), out fp8 ----------
__global__ __launch_bounds__(256) void lin0_kernel(
    const float* __restrict__ x, const short8* __restrict__ wf0,
    const float* __restrict__ b0, unsigned char* __restrict__ h, int nrows)
{
    __shared__ __align__(16) short lds_all[4][2048];   // per wave [16][128] bf16
    int wave = __builtin_amdgcn_readfirstlane(threadIdx.x >> 6);
    int lane = threadIdx.x & 63;
    char* ldsb = (char*)&lds_all[wave][0];
    int r0 = (blockIdx.x * 4 + wave) * 16;

#pragma unroll
    for (int r = 0; r < 16; ++r) {
        int row = r0 + r;
        float2 xv = make_float2(0.f, 0.f);
        if (row < nrows) xv = *(const float2*)(x + (size_t)row * FF + lane * 2);
        unsigned pk = (unsigned)f2bf(xv.x) | ((unsigned)f2bf(xv.y) << 16);
        *(int*)(ldsb + r * 256 + ((lane * 4) ^ ((r & 7) << 4))) = pk;
    }
    __syncthreads();

    short8 a[4];
#pragma unroll
    for (int kc = 0; kc < 4; ++kc) {
        int rr = lane & 15;
        a[kc] = *(const short8*)(ldsb + rr * 256 + (((kc * 64 + (lane >> 4) * 16)) ^ ((rr & 7) << 4)));
    }
    f32x4 acc[4];
#pragma unroll
    for (int tile = 0; tile < 4; ++tile) {
        acc[tile] = (f32x4){0.f, 0.f, 0.f, 0.f};
#pragma unroll
        for (int kc = 0; kc < 4; ++kc) {
            short8 b = wf0[(tile * 4 + kc) * 64 + lane];
            acc[tile] = __builtin_amdgcn_mfma_f32_16x16x32_bf16(a[kc], b, acc[tile], 0, 0, 0);
        }
    }
    __syncthreads();
#pragma unroll
    for (int tile = 0; tile < 4; ++tile) {
        int col = tile * 16 + (lane & 15);
        float bia = b0[col];
#pragma unroll
        for (int q = 0; q < 4; ++q) {
            int row = (lane >> 4) * 4 + q;
            float v = fmaxf(acc[tile][q] + bia, 0.0f);
            *(short*)(ldsb + row * 256 + ((col * 2) ^ ((row & 7) << 4))) = (short)f2bf(v);
        }
    }
    __syncthreads();
#pragma unroll
    for (int half = 0; half < 2; ++half) {
        int row = (lane >> 3) + half * 8;
        short8 vv = *(const short8*)(ldsb + row * 256 + ((((lane & 7) * 16)) ^ ((row & 7) << 4)));
        int grow = r0 + row;
        if (grow < nrows) {
            unsigned w0 = fp8_enc4(us2f((unsigned short)vv[0]), us2f((unsigned short)vv[1]),
                                   us2f((unsigned short)vv[2]), us2f((unsigned short)vv[3]));
            unsigned w1 = fp8_enc4(us2f((unsigned short)vv[4]), us2f((unsigned short)vv[5]),
                                   us2f((unsigned short)vv[6]), us2f((unsigned short)vv[7]));
            *(uint2*)(h + (size_t)grow * 64 + (lane & 7) * 8) = make_uint2(w0, w1);
        }
    }
}

// ---------- CSR build ----------
__global__ __launch_bounds__(256) void hist_kernel(
    const int* __restrict__ dst, int* __restrict__ deg, int nedges)
{
    int e = blockIdx.x * 256 + threadIdx.x;
    if (e < nedges) atomicAdd(&deg[dst[e]], 1);
}

__global__ __launch_bounds__(256) void scan_block_kernel(
    const int* __restrict__ deg, int* __restrict__ rowptr,
    int* __restrict__ partials, int n)
{
    __shared__ int sm[256];
    int tid = threadIdx.x;
    int i = blockIdx.x * 256 + tid;
    int v = (i < n) ? deg[i] : 0;
    sm[tid] = v;
    __syncthreads();
    for (int ofs = 1; ofs < 256; ofs <<= 1) {
        int t = (tid >= ofs) ? sm[tid - ofs] : 0;
        __syncthreads();
        sm[tid] += t;
        __syncthreads();
    }
    if (i < n) rowptr[i] = sm[tid] - v;
    if (tid == 255) partials[blockIdx.x] = sm[255];
}

__global__ __launch_bounds__(256) void scan_partials_kernel(int* partials, int nb)
{
    __shared__ int sm[256];
    __shared__ int carry;
    int tid = threadIdx.x;
    if (tid == 0) carry = 0;
    __syncthreads();
    for (int base = 0; base < nb; base += 256) {
        int i = base + tid;
        int v = (i < nb) ? partials[i] : 0;
        sm[tid] = v;
        __syncthreads();
        for (int ofs = 1; ofs < 256; ofs <<= 1) {
            int t = (tid >= ofs) ? sm[tid - ofs] : 0;
            __syncthreads();
            sm[tid] += t;
            __syncthreads();
        }
        int cbase = carry;
        int tot = sm[255];
        if (i < nb) partials[i] = sm[tid] - v + cbase;
        __syncthreads();
        if (tid == 0) carry = cbase + tot;
        __syncthreads();
    }
}

__global__ __launch_bounds__(256) void add_offsets_kernel(
    int* __restrict__ rowptr, const int* __restrict__ partials, int n)
{
    int i = blockIdx.x * 256 + threadIdx.x;
    if (i < n) rowptr[i] += partials[blockIdx.x];
}

// 4 strided edges per thread -> 4 independent atomic->store chains in flight
__global__ __launch_bounds__(256) void place_kernel(
    const int* __restrict__ src, const int* __restrict__ dst,
    const int* __restrict__ rowptr, int* __restrict__ deg,
    int* __restrict__ csr, int nedges, int stride)
{
    int t = blockIdx.x * 256 + threadIdx.x;
    int e[4], d[4], slot[4];
    bool ok[4];
#pragma unroll
    for (int i = 0; i < 4; ++i) {
        e[i] = t + i * stride;
        ok[i] = e[i] < nedges;
        d[i] = ok[i] ? dst[e[i]] : 0;
    }
#pragma unroll
    for (int i = 0; i < 4; ++i)
        slot[i] = ok[i] ? atomicAdd(&deg[d[i]], 1) : 0;
#pragma unroll
    for (int i = 0; i < 4; ++i)
        if (ok[i]) csr[rowptr[d[i]] + slot[i]] = src[e[i]];
}

// ---------- degree bucketing (counting sort, 64 bins) ----------
__global__ __launch_bounds__(256) void deg_hist_kernel(
    const int* __restrict__ deg, int* __restrict__ dhist, int n)
{
    __shared__ int lh[64];
    int tid = threadIdx.x;
    if (tid < 64) lh[tid] = 0;
    __syncthreads();
    int i = blockIdx.x * 256 + tid;
    if (i < n) atomicAdd(&lh[min(deg[i], 63)], 1);
    __syncthreads();
    if (tid < 64 && lh[tid]) atomicAdd(&dhist[tid], lh[tid]);
}

__global__ __launch_bounds__(64) void bucket_scan_kernel(
    const int* __restrict__ dhist, int* __restrict__ dcnt)
{
    __shared__ int sm[64];
    int t = threadIdx.x;
    sm[t] = dhist[t];
    __syncthreads();
    int acc = 0;
    for (int k = 0; k < t; ++k) acc += sm[k];
    dcnt[t] = acc;          // dcnt starts as the bucket base cursor
}

__global__ __launch_bounds__(256) void perm_place_kernel(
    const int* __restrict__ deg, int* __restrict__ dcnt,
    int* __restrict__ perm, int n)
{
    __shared__ int lh[64], lbase[64];
    int tid = threadIdx.x;
    if (tid < 64) lh[tid] = 0;
    __syncthreads();
    int i = blockIdx.x * 256 + tid;
    int b = 0;
    if (i < n) { b = min(deg[i], 63); atomicAdd(&lh[b], 1); }
    __syncthreads();
    if (tid < 64) {
        int cntb = lh[tid];
        if (cntb) lbase[tid] = atomicAdd(&dcnt[tid], cntb);
        lh[tid] = 0;
    }
    __syncthreads();
    if (i < n) {
        int r = atomicAdd(&lh[b], 1);
        perm[lbase[b] + r] = i;
    }
}

// ---------- fused MFMA layer, fp8 h, LDS neighbor table, zero-row padding ----------
// Gather: 8 lanes x 8B per row -> one uint2 load covers 8 rows across the wave.
template <int FINAL>
__global__ __launch_bounds__(256) void layer_kernel(
    const unsigned char* __restrict__ h, const int* __restrict__ rowptr,
    const int* __restrict__ deg, const int* __restrict__ csr,
    const int* __restrict__ perm,
    const short8* __restrict__ wfG1, const short8* __restrict__ wfG2,
    const float* __restrict__ b1, const float* __restrict__ g1, const float* __restrict__ bt1,
    const float* __restrict__ b2, const float* __restrict__ g2, const float* __restrict__ bt2,
    unsigned char* __restrict__ out, int nrows,
    const short8* __restrict__ wfL1, const float* __restrict__ bl1,
    const int* __restrict__ batch, float* __restrict__ pooled, float* __restrict__ cnt)
{
    __shared__ __align__(16) short lds_all[4][1024];     // per wave [16][64] bf16
    __shared__ int idx_tab[4][16][MAXD + 4];             // byte offsets; [MAXD] = self
    int wave = __builtin_amdgcn_readfirstlane(threadIdx.x >> 6);
    int lane = threadIdx.x & 63;
    char* ldsb = (char*)&lds_all[wave][0];
    int r0 = (blockIdx.x * 4 + wave) * 16;

    // ---- row metadata (scalar) + neighbor table fill ----
    int s16[16], c16[16], maxc = 0;
#pragma unroll
    for (int r = 0; r < 16; ++r) {
        int gi = r0 + r;
        int pr = nrows;                       // zero row for OOB
        int sv = 0, cv = 0;
        if (gi < nrows) {
            pr = perm ? perm[gi] : gi;
            sv = rowptr[pr]; cv = deg[pr];
        }
        pr = __builtin_amdgcn_readfirstlane(pr);
        s16[r] = __builtin_amdgcn_readfirstlane(sv);
        c16[r] = __builtin_amdgcn_readfirstlane(cv);
        maxc = max(maxc, c16[r]);
        int idxv = nrows;
        if (lane < c16[r]) idxv = csr[s16[r] + lane];
        idxv = min(max(idxv, 0), nrows) << 6;            // byte offset, clamped
        if (lane < MAXD) idx_tab[wave][r][lane] = idxv;
        if (lane == 0) idx_tab[wave][r][MAXD] = pr << 6; // self
    }

    int selrow = lane >> 3;          // row within 8-row group served by this lane
    int fq4 = (lane & 7) * 8;        // fp8 byte offset of this lane's 8-feature span
    int fq8 = fq4 * 2;               // bf16 byte offset (16B per lane)

    // ---- self init (via table, zero-row padded: no masks) ----
    float zg[2][8];
#pragma unroll
    for (int g = 0; g < 2; ++g) {
        int bo = idx_tab[wave][g * 8 + selrow][MAXD];
        uint2 w = *(const uint2*)(h + bo + fq4);
        f32x2 p0 = fp8_dec2<false>(w.x), p1 = fp8_dec2<true>(w.x);
        f32x2 p2 = fp8_dec2<false>(w.y), p3 = fp8_dec2<true>(w.y);
        zg[g][0] = p0.x; zg[g][1] = p0.y; zg[g][2] = p1.x; zg[g][3] = p1.y;
        zg[g][4] = p2.x; zg[g][5] = p2.y; zg[g][6] = p3.x; zg[g][7] = p3.y;
    }

    // ---- gather main loop: dummy slots read the zero row (cached) ----
    int jm = min(maxc, MAXD);
    for (int j0 = 0; j0 < jm; j0 += 4) {
        uint2 w[4][2];
#pragma unroll
        for (int jj = 0; jj < 4; ++jj) {
            int jcl = min(j0 + jj, MAXD - 1);
#pragma unroll
            for (int g = 0; g < 2; ++g) {
                int bo = idx_tab[wave][g * 8 + selrow][jcl];
                w[jj][g] = *(const uint2*)(h + bo + fq4);
            }
        }
#pragma unroll
        for (int jj = 0; jj < 4; ++jj)
#pragma unroll
            for (int g = 0; g < 2; ++g) {
                f32x2 p0 = fp8_dec2<false>(w[jj][g].x), p1 = fp8_dec2<true>(w[jj][g].x);
                f32x2 p2 = fp8_dec2<false>(w[jj][g].y), p3 = fp8_dec2<true>(w[jj][g].y);
                zg[g][0] += p0.x; zg[g][1] += p0.y; zg[g][2] += p1.x; zg[g][3] += p1.y;
                zg[g][4] += p2.x; zg[g][5] += p2.y; zg[g][6] += p3.x; zg[g][7] += p3.y;
            }
    }
    if (maxc > MAXD) {    // rare tail, scalar per row
#pragma unroll
        for (int g = 0; g < 2; ++g) {
#pragma unroll
            for (int q = 0; q < 8; ++q) {
                int r = g * 8 + q;
                for (int j = MAXD; j < c16[r]; ++j) {
                    int sn = csr[s16[r] + j];
                    sn = min(max(sn, 0), nrows - 1);
                    uint2 w = *(const uint2*)(h + ((size_t)sn << 6) + fq4);
                    f32x2 p0 = fp8_dec2<false>(w.x), p1 = fp8_dec2<true>(w.x);
                    f32x2 p2 = fp8_dec2<false>(w.y), p3 = fp8_dec2<true>(w.y);
                    bool mine = (selrow == q);
                    zg[g][0] += mine ? p0.x : 0.f;
                    zg[g][1] += mine ? p0.y : 0.f;
                    zg[g][2] += mine ? p1.x : 0.f;
                    zg[g][3] += mine ? p1.y : 0.f;
                    zg[g][4] += mine ? p2.x : 0.f;
                    zg[g][5] += mine ? p2.y : 0.f;
                    zg[g][6] += mine ? p3.x : 0.f;
                    zg[g][7] += mine ? p3.y : 0.f;
                }
            }
        }
    }

    // ---- z -> LDS bf16 [16][64], XOR-swizzled (16B stores) ----
#pragma unroll
    for (int g = 0; g < 2; ++g) {
        int row = g * 8 + selrow;
        short8 pk;
#pragma unroll
        for (int k = 0; k < 8; ++k) pk[k] = (short)f2bf(zg[g][k]);
        int off = (row * 128 + fq8) ^ ((row & 7) << 4);
        *(short8*)(ldsb + off) = pk;
    }
    __syncthreads();

    short8 a0, a1;
    f32x4 acc[4];
    // ---- GEMM1 + BN + ReLU ----
    {
        int rr = lane & 15;
        a0 = *(const short8*)(ldsb + rr * 128 + (((lane >> 4) * 16) ^ ((rr & 7) << 4)));
        a1 = *(const short8*)(ldsb + rr * 128 + ((64 + (lane >> 4) * 16) ^ ((rr & 7) << 4)));
    }
#pragma unroll
    for (int tile = 0; tile < 4; ++tile) {
        acc[tile] = (f32x4){0.f, 0.f, 0.f, 0.f};
        acc[tile] = __builtin_amdgcn_mfma_f32_16x16x32_bf16(a0, wfG1[(tile * 2 + 0) * 64 + lane], acc[tile], 0, 0, 0);
        acc[tile] = __builtin_amdgcn_mfma_f32_16x16x32_bf16(a1, wfG1[(tile * 2 + 1) * 64 + lane], acc[tile], 0, 0, 0);
    }
    __syncthreads();
#pragma unroll
    for (int tile = 0; tile < 4; ++tile) {
        int col = tile * 16 + (lane & 15);
        float sc = g1[col] * BN_RSQRT;
        float sh = fmaf(b1[col], sc, bt1[col]);
#pragma unroll
        for (int q = 0; q < 4; ++q) {
            int row = (lane >> 4) * 4 + q;
            float v = fmaxf(fmaf(acc[tile][q], sc, sh), 0.0f);
            *(short*)(ldsb + row * 128 + ((col * 2) ^ ((row & 7) << 4))) = (short)f2bf(v);
        }
    }
    __syncthreads();

    // ---- GEMM2 + BN + ReLU ----
    {
        int rr = lane & 15;
        a0 = *(const short8*)(ldsb + rr * 128 + (((lane >> 4) * 16) ^ ((rr & 7) << 4)));
        a1 = *(const short8*)(ldsb + rr * 128 + ((64 + (lane >> 4) * 16) ^ ((rr & 7) << 4)));
    }
#pragma unroll
    for (int tile = 0; tile < 4; ++tile) {
        acc[tile] = (f32x4){0.f, 0.f, 0.f, 0.f};
        acc[tile] = __builtin_amdgcn_mfma_f32_16x16x32_bf16(a0, wfG2[(tile * 2 + 0) * 64 + lane], acc[tile], 0, 0, 0);
        acc[tile] = __builtin_amdgcn_mfma_f32_16x16x32_bf16(a1, wfG2[(tile * 2 + 1) * 64 + lane], acc[tile], 0, 0, 0);
    }
    __syncthreads();
#pragma unroll
    for (int tile = 0; tile < 4; ++tile) {
        int col = tile * 16 + (lane & 15);
        float sc = g2[col] * BN_RSQRT;
        float sh = fmaf(b2[col], sc, bt2[col]);
#pragma unroll
        for (int q = 0; q < 4; ++q) {
            int row = (lane >> 4) * 4 + q;
            float v = fmaxf(fmaf(acc[tile][q], sc, sh), 0.0f);
            *(short*)(ldsb + row * 128 + ((col * 2) ^ ((row & 7) << 4))) = (short)f2bf(v);
        }
    }
    __syncthreads();

    if (FINAL == 0) {
        // fp8-pack + store (row index from table; zero row excluded by guard)
#pragma unroll
        for (int half = 0; half < 2; ++half) {
            int row = (lane >> 3) + half * 8;
            short8 vv = *(const short8*)(ldsb + row * 128 + ((((lane & 7) * 16)) ^ ((row & 7) << 4)));
            int ro = idx_tab[wave][row][MAXD];
            if (ro < (nrows << 6)) {
                unsigned w0 = fp8_enc4(us2f((unsigned short)vv[0]), us2f((unsigned short)vv[1]),
                                       us2f((unsigned short)vv[2]), us2f((unsigned short)vv[3]));
                unsigned w1 = fp8_enc4(us2f((unsigned short)vv[4]), us2f((unsigned short)vv[5]),
                                       us2f((unsigned short)vv[6]), us2f((unsigned short)vv[7]));
                *(uint2*)(out + ro + (lane & 7) * 8) = make_uint2(w0, w1);
            }
        }
    } else {
        // ---- GEMM3: relu(h4 @ Wl1 + bl1) ----
        {
            int rr = lane & 15;
            a0 = *(const short8*)(ldsb + rr * 128 + (((lane >> 4) * 16) ^ ((rr & 7) << 4)));
            a1 = *(const short8*)(ldsb + rr * 128 + ((64 + (lane >> 4) * 16) ^ ((rr & 7) << 4)));
        }
#pragma unroll
        for (int tile = 0; tile < 4; ++tile) {
            acc[tile] = (f32x4){0.f, 0.f, 0.f, 0.f};
            acc[tile] = __builtin_amdgcn_mfma_f32_16x16x32_bf16(a0, wfL1[(tile * 2 + 0) * 64 + lane], acc[tile], 0, 0, 0);
            acc[tile] = __builtin_amdgcn_mfma_f32_16x16x32_bf16(a1, wfL1[(tile * 2 + 1) * 64 + lane], acc[tile], 0, 0, 0);
        }
        __syncthreads();
#pragma unroll
        for (int tile = 0; tile < 4; ++tile) {
            int col = tile * 16 + (lane & 15);
            float bia = bl1[col];
#pragma unroll
            for (int q = 0; q < 4; ++q) {
                int row = (lane >> 4) * 4 + q;
                float v = fmaxf(acc[tile][q] + bia, 0.0f);
                *(short*)(ldsb + row * 128 + ((col * 2) ^ ((row & 7) << 4))) = (short)f2bf(v);
            }
        }
        __syncthreads();
        // ---- in-kernel mean-pool partials (natural order, batch sorted) ----
        float pacc = 0.0f;
        int curg = -1, rc = 0;
        for (int r = 0; r < 16; ++r) {
            int row = r0 + r;
            if (row >= nrows) break;
            float v = us2f(*(const unsigned short*)(ldsb + r * 128 + ((lane * 2) ^ ((r & 7) << 4))));
            int g = batch[row];
            if (g != curg) {
                if (curg >= 0) {
                    atomicAdd(&pooled[curg * HH + lane], pacc);
                    if (lane == 0) atomicAdd(&cnt[curg], (float)rc);
                }
                curg = g; pacc = v; rc = 1;
            } else { pacc += v; rc += 1; }
        }
        if (curg >= 0) {
            atomicAdd(&pooled[curg * HH + lane], pacc);
            if (lane == 0) atomicAdd(&cnt[curg], (float)rc);
        }
    }
}

__global__ __launch_bounds__(64) void head_kernel(
    const float* __restrict__ pooled, const float* __restrict__ cnt,
    const float* __restrict__ Wl2, const float* __restrict__ bl2,
    float* __restrict__ out, int ngraphs)
{
    int gidx = blockIdx.x * 64 + threadIdx.x;
    if (gidx >= ngraphs) return;
    float logits[CC];
#pragma unroll
    for (int c = 0; c < CC; ++c) logits[c] = bl2[c];
    float inv_n = 1.0f / fmaxf(cnt[gidx], 1.0f);
    for (int k = 0; k < HH; ++k) {
        float p = pooled[gidx * HH + k] * inv_n;
#pragma unroll
        for (int c = 0; c < CC; ++c) logits[c] = fmaf(p, Wl2[k * CC + c], logits[c]);
    }
    float m = logits[0];
#pragma unroll
    for (int c = 1; c < CC; ++c) m = fmaxf(m, logits[c]);
    float ssum = 0.0f;
#pragma unroll
    for (int c = 0; c < CC; ++c) { logits[c] = __expf(logits[c] - m); ssum += logits[c]; }
    float inv = 1.0f / ssum;
#pragma unroll
    for (int c = 0; c < CC; ++c) out[gidx * CC + c] = logits[c] * inv;
}

extern "C" void kernel_launch(void* const* d_in, const int* in_sizes, int n_in,
                              void* d_out, int out_size, void* d_ws, size_t ws_size,
                              hipStream_t stream) {
    const float* x      = (const float*)d_in[0];
    const int*   ei     = (const int*)  d_in[1];
    const int*   batch  = (const int*)  d_in[3];
    const float* W0     = (const float*)d_in[4];
    const float* b0     = (const float*)d_in[5];
    const float* convW1 = (const float*)d_in[6];
    const float* convb1 = (const float*)d_in[7];
    const float* convg1 = (const float*)d_in[8];
    const float* convbt1= (const float*)d_in[9];
    const float* convW2 = (const float*)d_in[10];
    const float* convb2 = (const float*)d_in[11];
    const float* convg2 = (const float*)d_in[12];
    const float* convbt2= (const float*)d_in[13];
    const float* Wl1    = (const float*)d_in[14];
    const float* bl1    = (const float*)d_in[15];
    const float* Wl2    = (const float*)d_in[16];
    const float* bl2    = (const float*)d_in[17];

    const int N = in_sizes[0] / FF;
    const int E = in_sizes[1] / 2;
    const int G = out_size / CC;

    const int* src = ei;
    const int* dst = ei + E;

    size_t off = 0;
    auto take = [&](size_t bytes) { size_t p = off; off = (off + bytes + 255) & ~255ULL; return p; };
    int NB = (N + 255) / 256;
    int EB = (E + 255) / 256;
    size_t o_rowptr = take((size_t)N * 4);
    size_t o_deg    = take((size_t)N * 4);
    size_t o_csr    = take((size_t)(E > NB ? E : NB) * 4 + 512);
    size_t o_perm   = take((size_t)N * 4);
    size_t o_dhist  = take(64 * 4);
    size_t o_dcnt   = take(64 * 4);
    size_t o_pooled = take((size_t)G * HH * 4);
    size_t o_cnt    = take((size_t)G * 4);
    size_t o_wfrag  = take((size_t)5632 * 8 * 2);
    size_t o_hA     = take((size_t)(N + 1) * 64);
    size_t o_hB     = take((size_t)(N + 1) * 64);

    char* base = (char*)d_ws;
    int*    rowptr = (int*)(base + o_rowptr);
    int*    deg    = (int*)(base + o_deg);
    int*    csr    = (int*)(base + o_csr);
    int*    perm   = (int*)(base + o_perm);
    int*    dhist  = (int*)(base + o_dhist);
    int*    dcnt   = (int*)(base + o_dcnt);
    float*  pooled = (float*)(base + o_pooled);
    float*  cnt    = (float*)(base + o_cnt);
    short*  wfrag  = (short*)(base + o_wfrag);
    short8* wf8    = (short8*)wfrag;
    unsigned char* hA = (unsigned char*)(base + o_hA);
    unsigned char* hB = (unsigned char*)(base + o_hB);

    int tile_blocks = (N + 63) / 64;     // 4 waves x 16 rows

    // weight fragment packing
    pack_weights_kernel<<<22, 256, 0, stream>>>(W0, convW1, convW2, Wl1, wfrag);

    // CSR build
    (void)hipMemsetAsync(deg, 0, (size_t)N * sizeof(int), stream);
    hist_kernel<<<EB, 256, 0, stream>>>(dst, deg, E);
    scan_block_kernel<<<NB, 256, 0, stream>>>(deg, rowptr, csr /*partials*/, N);
    scan_partials_kernel<<<1, 256, 0, stream>>>(csr, NB);
    add_offsets_kernel<<<NB, 256, 0, stream>>>(rowptr, csr, N);
    (void)hipMemsetAsync(deg, 0, (size_t)N * sizeof(int), stream);
    {
        int stride = ((E + 3) / 4 + 255) & ~255;
        place_kernel<<<stride / 256, 256, 0, stream>>>(src, dst, rowptr, deg, csr, E, stride);
    }

    // degree bucketing (uses restored deg)
    (void)hipMemsetAsync(dhist, 0, 64 * sizeof(int), stream);
    deg_hist_kernel<<<NB, 256, 0, stream>>>(deg, dhist, N);
    bucket_scan_kernel<<<1, 64, 0, stream>>>(dhist, dcnt);
    perm_place_kernel<<<NB, 256, 0, stream>>>(deg, dcnt, perm, N);

    // zero rows (index N) of both h buffers
    (void)hipMemsetAsync(hA + (size_t)N * 64, 0, 64, stream);
    (void)hipMemsetAsync(hB + (size_t)N * 64, 0, 64, stream);

    // lin0
    lin0_kernel<<<tile_blocks, 256, 0, stream>>>(x, wf8, b0, hA, N);

    // pooled/cnt init
    (void)hipMemsetAsync(pooled, 0, (size_t)G * HH * sizeof(float), stream);
    (void)hipMemsetAsync(cnt, 0, (size_t)G * sizeof(float), stream);

    // layers (ping-pong); 0..2 degree-bucketed, last natural + fused pool
    const unsigned char* hin = hA; unsigned char* hout = hB;
    const short8* wfL1 = wf8 + 5120;
    for (int l = 0; l < LL; ++l) {
        const short8* wfG1 = wf8 + 1024 + (size_t)(l * 2 + 0) * 512;
        const short8* wfG2 = wf8 + 1024 + (size_t)(l * 2 + 1) * 512;
        if (l < LL - 1) {
            layer_kernel<0><<<tile_blocks, 256, 0, stream>>>(
                hin, rowptr, deg, csr, perm, wfG1, wfG2,
                convb1 + l * HH, convg1 + l * HH, convbt1 + l * HH,
                convb2 + l * HH, convg2 + l * HH, convbt2 + l * HH,
                hout, N, nullptr, nullptr, nullptr, nullptr, nullptr);
        } else {
            layer_kernel<1><<<tile_blocks, 256, 0, stream>>>(
                hin, rowptr, deg, csr, nullptr, wfG1, wfG2,
                convb1 + l * HH, convg1 + l * HH, convbt1 + l * HH,
                convb2 + l * HH, convg2 + l * HH, convbt2 + l * HH,
                nullptr, N, wfL1, bl1, batch, pooled, cnt);
        }
        unsigned char* tswap = (unsigned char*)hin; hin = hout; hout = tswap;
    }

    head_kernel<<<(G + 63) / 64, 64, 0, stream>>>(pooled, cnt, Wl2, bl2, (float*)d_out, G);
}

// Round 12
// 325.471 us; speedup vs baseline: 1.6601x; 1.0122x over previous
//
#include <hip/hip_runtime.h>
#include <hip/hip_bf16.h>

#define HH 64
#define FF 128
#define CC 10
#define LL 4
#define MAXD 32        // LDS neighbor-table depth (tail loop handles deg>32)
#define BN_RSQRT 0.9999950000374997f   // 1/sqrt(1+1e-5)

typedef __hip_bfloat16 bf16;
using short8 = __attribute__((ext_vector_type(8))) short;
using f32x4  = __attribute__((ext_vector_type(4))) float;
using f32x2  = __attribute__((ext_vector_type(2))) float;

__device__ __forceinline__ float us2f(unsigned short u) {
    return __uint_as_float(((unsigned)u) << 16);
}
// RNE f32->bf16 bits (finite inputs)
__device__ __forceinline__ unsigned short f2bf(float v) {
    unsigned u = __float_as_uint(v);
    return (unsigned short)((u + 0x7FFFu + ((u >> 16) & 1u)) >> 16);
}

// ---------- fp8 pack/unpack (HW cvt on gfx950; software fallback) ----------
#if defined(__has_builtin)
#if __has_builtin(__builtin_amdgcn_cvt_pk_f32_fp8) && __has_builtin(__builtin_amdgcn_cvt_pk_fp8_f32)
#define FP8_HW 1
#endif
#endif

#ifdef FP8_HW
template <bool HIGH>
__device__ __forceinline__ f32x2 fp8_dec2(unsigned w) {
    return __builtin_amdgcn_cvt_pk_f32_fp8((int)w, HIGH);
}
__device__ __forceinline__ unsigned fp8_enc4(float f0, float f1, float f2, float f3) {
    int w = 0;
    w = __builtin_amdgcn_cvt_pk_fp8_f32(f0, f1, w, false);
    w = __builtin_amdgcn_cvt_pk_fp8_f32(f2, f3, w, true);
    return (unsigned)w;
}
#else
__device__ __forceinline__ float fp8_dec1(unsigned b) {
    unsigned s = (b & 0x80u) << 24;
    unsigned em = b & 0x7Fu;
    float mag;
    if (em >= 0x08u) mag = __uint_as_float((((em >> 3) + 120u) << 23) | ((em & 7u) << 20));
    else             mag = (float)em * (1.0f / 512.0f);
    return __uint_as_float(__float_as_uint(mag) | s);
}
template <bool HIGH>
__device__ __forceinline__ f32x2 fp8_dec2(unsigned w) {
    unsigned lo = HIGH ? ((w >> 16) & 0xffu) : (w & 0xffu);
    unsigned hi = HIGH ? ((w >> 24) & 0xffu) : ((w >> 8) & 0xffu);
    f32x2 r; r.x = fp8_dec1(lo); r.y = fp8_dec1(hi); return r;
}
__device__ __forceinline__ unsigned fp8_enc1(float v) {
    unsigned u = __float_as_uint(v);
    unsigned s = (u >> 24) & 0x80u;
    float a = fabsf(v);
    if (a >= 448.0f) return s | 0x7Eu;
    if (a < 0.015625f) {
        int m = (int)rintf(a * 512.0f);
        return s | (unsigned)m;
    }
    int e; float m = frexpf(a, &e);
    int E = e + 6;
    int mant = (int)rintf((m * 2.0f - 1.0f) * 8.0f);
    if (mant == 8) { mant = 0; ++E; }
    if (E > 15) return s | 0x7Eu;
    return s | (unsigned)(E << 3) | (unsigned)mant;
}
__device__ __forceinline__ unsigned fp8_enc4(float f0, float f1, float f2, float f3) {
    return fp8_enc1(f0) | (fp8_enc1(f1) << 8) | (fp8_enc1(f2) << 16) | (fp8_enc1(f3) << 24);
}
#endif

// ---------- weight fragment packing ----------
__global__ __launch_bounds__(256) void pack_weights_kernel(
    const float* __restrict__ W0, const float* __restrict__ convW1,
    const float* __restrict__ convW2, const float* __restrict__ Wl1,
    short* __restrict__ wf)
{
    int t = blockIdx.x * 256 + threadIdx.x;
    if (t >= 5632) return;
    const float* W;
    int l, tile, kc, out_idx;
    if (t < 1024) {
        int local = t; int fi = local >> 6; l = local & 63;
        tile = fi >> 2; kc = fi & 3;
        W = W0; out_idx = local;
    } else if (t < 5120) {
        int t2 = t - 1024;
        int m = t2 >> 9;
        int local = t2 & 511;
        int fi = local >> 6; l = local & 63;
        tile = fi >> 1; kc = fi & 1;
        int layer = m >> 1, g = m & 1;
        W = (g ? convW2 : convW1) + (size_t)layer * HH * HH;
        out_idx = 1024 + m * 512 + local;
    } else {
        int local = t - 5120;
        int fi = local >> 6; l = local & 63;
        tile = fi >> 1; kc = fi & 1;
        W = Wl1; out_idx = 5120 + local;
    }
    int k0 = kc * 32 + (l >> 4) * 8;
    int n = tile * 16 + (l & 15);
#pragma unroll
    for (int e = 0; e < 8; ++e)
        wf[out_idx * 8 + e] = (short)f2bf(W[(k0 + e) * HH + n]);
}

// ---------- lin0 (MFMA): h = relu(x @ W0 + b0), out fp8 ----------
__global__ __launch_bounds__(256) void lin0_kernel(
    const float* __restrict__ x, const short8* __restrict__ wf0,
    const float* __restrict__ b0, unsigned char* __restrict__ h, int nrows)
{
    __shared__ __align__(16) short lds_all[4][2048];   // per wave [16][128] bf16
    int wave = __builtin_amdgcn_readfirstlane(threadIdx.x >> 6);
    int lane = threadIdx.x & 63;
    char* ldsb = (char*)&lds_all[wave][0];
    int r0 = (blockIdx.x * 4 + wave) * 16;

#pragma unroll
    for (int r = 0; r < 16; ++r) {
        int row = r0 + r;
        float2 xv = make_float2(0.f, 0.f);
        if (row < nrows) xv = *(const float2*)(x + (size_t)row * FF + lane * 2);
        unsigned pk = (unsigned)f2bf(xv.x) | ((unsigned)f2bf(xv.y) << 16);
        *(int*)(ldsb + r * 256 + ((lane * 4) ^ ((r & 7) << 4))) = pk;
    }
    __syncthreads();

    short8 a[4];
#pragma unroll
    for (int kc = 0; kc < 4; ++kc) {
        int rr = lane & 15;
        a[kc] = *(const short8*)(ldsb + rr * 256 + (((kc * 64 + (lane >> 4) * 16)) ^ ((rr & 7) << 4)));
    }
    f32x4 acc[4];
#pragma unroll
    for (int tile = 0; tile < 4; ++tile) {
        acc[tile] = (f32x4){0.f, 0.f, 0.f, 0.f};
#pragma unroll
        for (int kc = 0; kc < 4; ++kc) {
            short8 b = wf0[(tile * 4 + kc) * 64 + lane];
            acc[tile] = __builtin_amdgcn_mfma_f32_16x16x32_bf16(a[kc], b, acc[tile], 0, 0, 0);
        }
    }
    __syncthreads();
#pragma unroll
    for (int tile = 0; tile < 4; ++tile) {
        int col = tile * 16 + (lane & 15);
        float bia = b0[col];
#pragma unroll
        for (int q = 0; q < 4; ++q) {
            int row = (lane >> 4) * 4 + q;
            float v = fmaxf(acc[tile][q] + bia, 0.0f);
            *(short*)(ldsb + row * 256 + ((col * 2) ^ ((row & 7) << 4))) = (short)f2bf(v);
        }
    }
    __syncthreads();
#pragma unroll
    for (int half = 0; half < 2; ++half) {
        int row = (lane >> 3) + half * 8;
        short8 vv = *(const short8*)(ldsb + row * 256 + ((((lane & 7) * 16)) ^ ((row & 7) << 4)));
        int grow = r0 + row;
        if (grow < nrows) {
            unsigned w0 = fp8_enc4(us2f((unsigned short)vv[0]), us2f((unsigned short)vv[1]),
                                   us2f((unsigned short)vv[2]), us2f((unsigned short)vv[3]));
            unsigned w1 = fp8_enc4(us2f((unsigned short)vv[4]), us2f((unsigned short)vv[5]),
                                   us2f((unsigned short)vv[6]), us2f((unsigned short)vv[7]));
            *(uint2*)(h + (size_t)grow * 64 + (lane & 7) * 8) = make_uint2(w0, w1);
        }
    }
}

// ---------- CSR build ----------
__global__ __launch_bounds__(256) void hist_kernel(
    const int* __restrict__ dst, int* __restrict__ deg, int nedges)
{
    int e = blockIdx.x * 256 + threadIdx.x;
    if (e < nedges) atomicAdd(&deg[dst[e]], 1);
}

__global__ __launch_bounds__(256) void scan_block_kernel(
    const int* __restrict__ deg, int* __restrict__ rowptr,
    int* __restrict__ partials, int n)
{
    __shared__ int sm[256];
    int tid = threadIdx.x;
    int i = blockIdx.x * 256 + tid;
    int v = (i < n) ? deg[i] : 0;
    sm[tid] = v;
    __syncthreads();
    for (int ofs = 1; ofs < 256; ofs <<= 1) {
        int t = (tid >= ofs) ? sm[tid - ofs] : 0;
        __syncthreads();
        sm[tid] += t;
        __syncthreads();
    }
    if (i < n) rowptr[i] = sm[tid] - v;
    if (tid == 255) partials[blockIdx.x] = sm[255];
}

__global__ __launch_bounds__(256) void scan_partials_kernel(int* partials, int nb)
{
    __shared__ int sm[256];
    __shared__ int carry;
    int tid = threadIdx.x;
    if (tid == 0) carry = 0;
    __syncthreads();
    for (int base = 0; base < nb; base += 256) {
        int i = base + tid;
        int v = (i < nb) ? partials[i] : 0;
        sm[tid] = v;
        __syncthreads();
        for (int ofs = 1; ofs < 256; ofs <<= 1) {
            int t = (tid >= ofs) ? sm[tid - ofs] : 0;
            __syncthreads();
            sm[tid] += t;
            __syncthreads();
        }
        int cbase = carry;
        int tot = sm[255];
        if (i < nb) partials[i] = sm[tid] - v + cbase;
        __syncthreads();
        if (tid == 0) carry = cbase + tot;
        __syncthreads();
    }
}

__global__ __launch_bounds__(256) void add_offsets_kernel(
    int* __restrict__ rowptr, const int* __restrict__ partials, int n)
{
    int i = blockIdx.x * 256 + threadIdx.x;
    if (i < n) rowptr[i] += partials[blockIdx.x];
}

// 4 strided edges per thread -> 4 independent atomic->store chains in flight
__global__ __launch_bounds__(256) void place_kernel(
    const int* __restrict__ src, const int* __restrict__ dst,
    const int* __restrict__ rowptr, int* __restrict__ deg,
    int* __restrict__ csr, int nedges, int stride)
{
    int t = blockIdx.x * 256 + threadIdx.x;
    int e[4], d[4], slot[4];
    bool ok[4];
#pragma unroll
    for (int i = 0; i < 4; ++i) {
        e[i] = t + i * stride;
        ok[i] = e[i] < nedges;
        d[i] = ok[i] ? dst[e[i]] : 0;
    }
#pragma unroll
    for (int i = 0; i < 4; ++i)
        slot[i] = ok[i] ? atomicAdd(&deg[d[i]], 1) : 0;
#pragma unroll
    for (int i = 0; i < 4; ++i)
        if (ok[i]) csr[rowptr[d[i]] + slot[i]] = src[e[i]];
}

// ---------- degree bucketing (counting sort, 64 bins) ----------
__global__ __launch_bounds__(256) void deg_hist_kernel(
    const int* __restrict__ deg, int* __restrict__ dhist, int n)
{
    __shared__ int lh[64];
    int tid = threadIdx.x;
    if (tid < 64) lh[tid] = 0;
    __syncthreads();
    int i = blockIdx.x * 256 + tid;
    if (i < n) atomicAdd(&lh[min(deg[i], 63)], 1);
    __syncthreads();
    if (tid < 64 && lh[tid]) atomicAdd(&dhist[tid], lh[tid]);
}

__global__ __launch_bounds__(64) void bucket_scan_kernel(
    const int* __restrict__ dhist, int* __restrict__ dcnt)
{
    __shared__ int sm[64];
    int t = threadIdx.x;
    sm[t] = dhist[t];
    __syncthreads();
    int acc = 0;
    for (int k = 0; k < t; ++k) acc += sm[k];
    dcnt[t] = acc;          // dcnt starts as the bucket base cursor
}

__global__ __launch_bounds__(256) void perm_place_kernel(
    const int* __restrict__ deg, int* __restrict__ dcnt,
    int* __restrict__ perm, int n)
{
    __shared__ int lh[64], lbase[64];
    int tid = threadIdx.x;
    if (tid < 64) lh[tid] = 0;
    __syncthreads();
    int i = blockIdx.x * 256 + tid;
    int b = 0;
    if (i < n) { b = min(deg[i], 63); atomicAdd(&lh[b], 1); }
    __syncthreads();
    if (tid < 64) {
        int cntb = lh[tid];
        if (cntb) lbase[tid] = atomicAdd(&dcnt[tid], cntb);
        lh[tid] = 0;
    }
    __syncthreads();
    if (i < n) {
        int r = atomicAdd(&lh[b], 1);
        perm[lbase[b] + r] = i;
    }
}

// ---------- fused MFMA layer, fp8 h, LDS-union idx/z tile, zero-row padding ----------
// LDS per wave: 2KB, time-multiplexed: idx table int[16][32] during gather,
// then z tile bf16[16][64] for the GEMMs. Self row offsets in self_tab.
// Gather: 8 lanes x 8B per row; j unrolled x8 -> 16 uint2 loads in flight.
template <int FINAL>
__global__ __launch_bounds__(256, 5) void layer_kernel(
    const unsigned char* __restrict__ h, const int* __restrict__ rowptr,
    const int* __restrict__ deg, const int* __restrict__ csr,
    const int* __restrict__ perm,
    const short8* __restrict__ wfG1, const short8* __restrict__ wfG2,
    const float* __restrict__ b1, const float* __restrict__ g1, const float* __restrict__ bt1,
    const float* __restrict__ b2, const float* __restrict__ g2, const float* __restrict__ bt2,
    unsigned char* __restrict__ out, int nrows,
    const short8* __restrict__ wfL1, const float* __restrict__ bl1,
    const int* __restrict__ batch, float* __restrict__ pooled, float* __restrict__ cnt)
{
    __shared__ __align__(16) char lds_u[4][2048];   // per-wave union: idx[16][32] / z bf16[16][64]
    __shared__ int self_tab[4][16];
    int wave = __builtin_amdgcn_readfirstlane(threadIdx.x >> 6);
    int lane = threadIdx.x & 63;
    char* ldsb = &lds_u[wave][0];
    int* idxp = (int*)ldsb;
    int r0 = (blockIdx.x * 4 + wave) * 16;

    // ---- row metadata (scalar) + neighbor table fill ----
    int s16[16], c16[16], maxc = 0;
#pragma unroll
    for (int r = 0; r < 16; ++r) {
        int gi = r0 + r;
        int pr = nrows;                       // zero row for OOB
        int sv = 0, cv = 0;
        if (gi < nrows) {
            pr = perm ? perm[gi] : gi;
            sv = rowptr[pr]; cv = deg[pr];
        }
        pr = __builtin_amdgcn_readfirstlane(pr);
        s16[r] = __builtin_amdgcn_readfirstlane(sv);
        c16[r] = __builtin_amdgcn_readfirstlane(cv);
        maxc = max(maxc, c16[r]);
        int idxv = nrows;
        if (lane < c16[r]) idxv = csr[s16[r] + lane];
        idxv = min(max(idxv, 0), nrows) << 6;            // byte offset, clamped
        if (lane < MAXD) idxp[r * MAXD + lane] = idxv;
        if (lane == 0) self_tab[wave][r] = pr << 6;      // self
    }

    int selrow = lane >> 3;          // row within 8-row group served by this lane
    int fq4 = (lane & 7) * 8;        // fp8 byte offset of this lane's 8-feature span
    int fq8 = fq4 * 2;               // bf16 byte offset (16B per lane)

    // ---- self init ----
    float zg[2][8];
#pragma unroll
    for (int g = 0; g < 2; ++g) {
        int bo = self_tab[wave][g * 8 + selrow];
        uint2 w = *(const uint2*)(h + bo + fq4);
        f32x2 p0 = fp8_dec2<false>(w.x), p1 = fp8_dec2<true>(w.x);
        f32x2 p2 = fp8_dec2<false>(w.y), p3 = fp8_dec2<true>(w.y);
        zg[g][0] = p0.x; zg[g][1] = p0.y; zg[g][2] = p1.x; zg[g][3] = p1.y;
        zg[g][4] = p2.x; zg[g][5] = p2.y; zg[g][6] = p3.x; zg[g][7] = p3.y;
    }

    // ---- gather main loop: dummy slots read the zero row (cached) ----
    int jm = min(maxc, MAXD);
    for (int j0 = 0; j0 < jm; j0 += 8) {
        uint2 w[8][2];
#pragma unroll
        for (int jj = 0; jj < 8; ++jj) {
            int jcl = min(j0 + jj, MAXD - 1);
#pragma unroll
            for (int g = 0; g < 2; ++g) {
                int bo = idxp[(g * 8 + selrow) * MAXD + jcl];
                w[jj][g] = *(const uint2*)(h + bo + fq4);
            }
        }
#pragma unroll
        for (int jj = 0; jj < 8; ++jj)
#pragma unroll
            for (int g = 0; g < 2; ++g) {
                f32x2 p0 = fp8_dec2<false>(w[jj][g].x), p1 = fp8_dec2<true>(w[jj][g].x);
                f32x2 p2 = fp8_dec2<false>(w[jj][g].y), p3 = fp8_dec2<true>(w[jj][g].y);
                zg[g][0] += p0.x; zg[g][1] += p0.y; zg[g][2] += p1.x; zg[g][3] += p1.y;
                zg[g][4] += p2.x; zg[g][5] += p2.y; zg[g][6] += p3.x; zg[g][7] += p3.y;
            }
    }
    if (maxc > MAXD) {    // rare tail, scalar per row
#pragma unroll
        for (int g = 0; g < 2; ++g) {
#pragma unroll
            for (int q = 0; q < 8; ++q) {
                int r = g * 8 + q;
                for (int j = MAXD; j < c16[r]; ++j) {
                    int sn = csr[s16[r] + j];
                    sn = min(max(sn, 0), nrows - 1);
                    uint2 w = *(const uint2*)(h + ((size_t)sn << 6) + fq4);
                    f32x2 p0 = fp8_dec2<false>(w.x), p1 = fp8_dec2<true>(w.x);
                    f32x2 p2 = fp8_dec2<false>(w.y), p3 = fp8_dec2<true>(w.y);
                    bool mine = (selrow == q);
                    zg[g][0] += mine ? p0.x : 0.f;
                    zg[g][1] += mine ? p0.y : 0.f;
                    zg[g][2] += mine ? p1.x : 0.f;
                    zg[g][3] += mine ? p1.y : 0.f;
                    zg[g][4] += mine ? p2.x : 0.f;
                    zg[g][5] += mine ? p2.y : 0.f;
                    zg[g][6] += mine ? p3.x : 0.f;
                    zg[g][7] += mine ? p3.y : 0.f;
                }
            }
        }
    }
    __syncthreads();   // all idx reads complete before the union flips to z-tile

    // ---- z -> LDS bf16 [16][64], XOR-swizzled (16B stores) ----
#pragma unroll
    for (int g = 0; g < 2; ++g) {
        int row = g * 8 + selrow;
        short8 pk;
#pragma unroll
        for (int k = 0; k < 8; ++k) pk[k] = (short)f2bf(zg[g][k]);
        int off = (row * 128 + fq8) ^ ((row & 7) << 4);
        *(short8*)(ldsb + off) = pk;
    }
    __syncthreads();

    short8 a0, a1;
    f32x4 acc[4];
    // ---- GEMM1 + BN + ReLU ----
    {
        int rr = lane & 15;
        a0 = *(const short8*)(ldsb + rr * 128 + (((lane >> 4) * 16) ^ ((rr & 7) << 4)));
        a1 = *(const short8*)(ldsb + rr * 128 + ((64 + (lane >> 4) * 16) ^ ((rr & 7) << 4)));
    }
#pragma unroll
    for (int tile = 0; tile < 4; ++tile) {
        acc[tile] = (f32x4){0.f, 0.f, 0.f, 0.f};
        acc[tile] = __builtin_amdgcn_mfma_f32_16x16x32_bf16(a0, wfG1[(tile * 2 + 0) * 64 + lane], acc[tile], 0, 0, 0);
        acc[tile] = __builtin_amdgcn_mfma_f32_16x16x32_bf16(a1, wfG1[(tile * 2 + 1) * 64 + lane], acc[tile], 0, 0, 0);
    }
    __syncthreads();
#pragma unroll
    for (int tile = 0; tile < 4; ++tile) {
        int col = tile * 16 + (lane & 15);
        float sc = g1[col] * BN_RSQRT;
        float sh = fmaf(b1[col], sc, bt1[col]);
#pragma unroll
        for (int q = 0; q < 4; ++q) {
            int row = (lane >> 4) * 4 + q;
            float v = fmaxf(fmaf(acc[tile][q], sc, sh), 0.0f);
            *(short*)(ldsb + row * 128 + ((col * 2) ^ ((row & 7) << 4))) = (short)f2bf(v);
        }
    }
    __syncthreads();

    // ---- GEMM2 + BN + ReLU ----
    {
        int rr = lane & 15;
        a0 = *(const short8*)(ldsb + rr * 128 + (((lane >> 4) * 16) ^ ((rr & 7) << 4)));
        a1 = *(const short8*)(ldsb + rr * 128 + ((64 + (lane >> 4) * 16) ^ ((rr & 7) << 4)));
    }
#pragma unroll
    for (int tile = 0; tile < 4; ++tile) {
        acc[tile] = (f32x4){0.f, 0.f, 0.f, 0.f};
        acc[tile] = __builtin_amdgcn_mfma_f32_16x16x32_bf16(a0, wfG2[(tile * 2 + 0) * 64 + lane], acc[tile], 0, 0, 0);
        acc[tile] = __builtin_amdgcn_mfma_f32_16x16x32_bf16(a1, wfG2[(tile * 2 + 1) * 64 + lane], acc[tile], 0, 0, 0);
    }
    __syncthreads();
#pragma unroll
    for (int tile = 0; tile < 4; ++tile) {
        int col = tile * 16 + (lane & 15);
        float sc = g2[col] * BN_RSQRT;
        float sh = fmaf(b2[col], sc, bt2[col]);
#pragma unroll
        for (int q = 0; q < 4; ++q) {
            int row = (lane >> 4) * 4 + q;
            float v = fmaxf(fmaf(acc[tile][q], sc, sh), 0.0f);
            *(short*)(ldsb + row * 128 + ((col * 2) ^ ((row & 7) << 4))) = (short)f2bf(v);
        }
    }
    __syncthreads();

    if (FINAL == 0) {
        // fp8-pack + store (row offset from self_tab; zero row excluded by guard)
#pragma unroll
        for (int half = 0; half < 2; ++half) {
            int row = (lane >> 3) + half * 8;
            short8 vv = *(const short8*)(ldsb + row * 128 + ((((lane & 7) * 16)) ^ ((row & 7) << 4)));
            int ro = self_tab[wave][row];
            if (ro < (nrows << 6)) {
                unsigned w0 = fp8_enc4(us2f((unsigned short)vv[0]), us2f((unsigned short)vv[1]),
                                       us2f((unsigned short)vv[2]), us2f((unsigned short)vv[3]));
                unsigned w1 = fp8_enc4(us2f((unsigned short)vv[4]), us2f((unsigned short)vv[5]),
                                       us2f((unsigned short)vv[6]), us2f((unsigned short)vv[7]));
                *(uint2*)(out + ro + (lane & 7) * 8) = make_uint2(w0, w1);
            }
        }
    } else {
        // ---- GEMM3: relu(h4 @ Wl1 + bl1) ----
        {
            int rr = lane & 15;
            a0 = *(const short8*)(ldsb + rr * 128 + (((lane >> 4) * 16) ^ ((rr & 7) << 4)));
            a1 = *(const short8*)(ldsb + rr * 128 + ((64 + (lane >> 4) * 16) ^ ((rr & 7) << 4)));
        }
#pragma unroll
        for (int tile = 0; tile < 4; ++tile) {
            acc[tile] = (f32x4){0.f, 0.f, 0.f, 0.f};
            acc[tile] = __builtin_amdgcn_mfma_f32_16x16x32_bf16(a0, wfL1[(tile * 2 + 0) * 64 + lane], acc[tile], 0, 0, 0);
            acc[tile] = __builtin_amdgcn_mfma_f32_16x16x32_bf16(a1, wfL1[(tile * 2 + 1) * 64 + lane], acc[tile], 0, 0, 0);
        }
        __syncthreads();
#pragma unroll
        for (int tile = 0; tile < 4; ++tile) {
            int col = tile * 16 + (lane & 15);
            float bia = bl1[col];
#pragma unroll
            for (int q = 0; q < 4; ++q) {
                int row = (lane >> 4) * 4 + q;
                float v = fmaxf(acc[tile][q] + bia, 0.0f);
                *(short*)(ldsb + row * 128 + ((col * 2) ^ ((row & 7) << 4))) = (short)f2bf(v);
            }
        }
        __syncthreads();
        // ---- in-kernel mean-pool partials (natural order, batch sorted) ----
        float pacc = 0.0f;
        int curg = -1, rc = 0;
        for (int r = 0; r < 16; ++r) {
            int row = r0 + r;
            if (row >= nrows) break;
            float v = us2f(*(const unsigned short*)(ldsb + r * 128 + ((lane * 2) ^ ((r & 7) << 4))));
            int g = batch[row];
            if (g != curg) {
                if (curg >= 0) {
                    atomicAdd(&pooled[curg * HH + lane], pacc);
                    if (lane == 0) atomicAdd(&cnt[curg], (float)rc);
                }
                curg = g; pacc = v; rc = 1;
            } else { pacc += v; rc += 1; }
        }
        if (curg >= 0) {
            atomicAdd(&pooled[curg * HH + lane], pacc);
            if (lane == 0) atomicAdd(&cnt[curg], (float)rc);
        }
    }
}

__global__ __launch_bounds__(64) void head_kernel(
    const float* __restrict__ pooled, const float* __restrict__ cnt,
    const float* __restrict__ Wl2, const float* __restrict__ bl2,
    float* __restrict__ out, int ngraphs)
{
    int gidx = blockIdx.x * 64 + threadIdx.x;
    if (gidx >= ngraphs) return;
    float logits[CC];
#pragma unroll
    for (int c = 0; c < CC; ++c) logits[c] = bl2[c];
    float inv_n = 1.0f / fmaxf(cnt[gidx], 1.0f);
    for (int k = 0; k < HH; ++k) {
        float p = pooled[gidx * HH + k] * inv_n;
#pragma unroll
        for (int c = 0; c < CC; ++c) logits[c] = fmaf(p, Wl2[k * CC + c], logits[c]);
    }
    float m = logits[0];
#pragma unroll
    for (int c = 1; c < CC; ++c) m = fmaxf(m, logits[c]);
    float ssum = 0.0f;
#pragma unroll
    for (int c = 0; c < CC; ++c) { logits[c] = __expf(logits[c] - m); ssum += logits[c]; }
    float inv = 1.0f / ssum;
#pragma unroll
    for (int c = 0; c < CC; ++c) out[gidx * CC + c] = logits[c] * inv;
}

extern "C" void kernel_launch(void* const* d_in, const int* in_sizes, int n_in,
                              void* d_out, int out_size, void* d_ws, size_t ws_size,
                              hipStream_t stream) {
    const float* x      = (const float*)d_in[0];
    const int*   ei     = (const int*)  d_in[1];
    const int*   batch  = (const int*)  d_in[3];
    const float* W0     = (const float*)d_in[4];
    const float* b0     = (const float*)d_in[5];
    const float* convW1 = (const float*)d_in[6];
    const float* convb1 = (const float*)d_in[7];
    const float* convg1 = (const float*)d_in[8];
    const float* convbt1= (const float*)d_in[9];
    const float* convW2 = (const float*)d_in[10];
    const float* convb2 = (const float*)d_in[11];
    const float* convg2 = (const float*)d_in[12];
    const float* convbt2= (const float*)d_in[13];
    const float* Wl1    = (const float*)d_in[14];
    const float* bl1    = (const float*)d_in[15];
    const float* Wl2    = (const float*)d_in[16];
    const float* bl2    = (const float*)d_in[17];

    const int N = in_sizes[0] / FF;
    const int E = in_sizes[1] / 2;
    const int G = out_size / CC;

    const int* src = ei;
    const int* dst = ei + E;

    size_t off = 0;
    auto take = [&](size_t bytes) { size_t p = off; off = (off + bytes + 255) & ~255ULL; return p; };
    int NB = (N + 255) / 256;
    int EB = (E + 255) / 256;
    size_t o_rowptr = take((size_t)N * 4);
    size_t o_deg    = take((size_t)N * 4);
    size_t o_csr    = take((size_t)(E > NB ? E : NB) * 4 + 512);
    size_t o_perm   = take((size_t)N * 4);
    size_t o_dhist  = take(64 * 4);
    size_t o_dcnt   = take(64 * 4);
    size_t o_pooled = take((size_t)G * HH * 4);
    size_t o_cnt    = take((size_t)G * 4);
    size_t o_wfrag  = take((size_t)5632 * 8 * 2);
    size_t o_hA     = take((size_t)(N + 1) * 64);
    size_t o_hB     = take((size_t)(N + 1) * 64);

    char* base = (char*)d_ws;
    int*    rowptr = (int*)(base + o_rowptr);
    int*    deg    = (int*)(base + o_deg);
    int*    csr    = (int*)(base + o_csr);
    int*    perm   = (int*)(base + o_perm);
    int*    dhist  = (int*)(base + o_dhist);
    int*    dcnt   = (int*)(base + o_dcnt);
    float*  pooled = (float*)(base + o_pooled);
    float*  cnt    = (float*)(base + o_cnt);
    short*  wfrag  = (short*)(base + o_wfrag);
    short8* wf8    = (short8*)wfrag;
    unsigned char* hA = (unsigned char*)(base + o_hA);
    unsigned char* hB = (unsigned char*)(base + o_hB);

    int tile_blocks = (N + 63) / 64;     // 4 waves x 16 rows

    // weight fragment packing
    pack_weights_kernel<<<22, 256, 0, stream>>>(W0, convW1, convW2, Wl1, wfrag);

    // CSR build
    (void)hipMemsetAsync(deg, 0, (size_t)N * sizeof(int), stream);
    hist_kernel<<<EB, 256, 0, stream>>>(dst, deg, E);
    scan_block_kernel<<<NB, 256, 0, stream>>>(deg, rowptr, csr /*partials*/, N);
    scan_partials_kernel<<<1, 256, 0, stream>>>(csr, NB);
    add_offsets_kernel<<<NB, 256, 0, stream>>>(rowptr, csr, N);
    (void)hipMemsetAsync(deg, 0, (size_t)N * sizeof(int), stream);
    {
        int stride = ((E + 3) / 4 + 255) & ~255;
        place_kernel<<<stride / 256, 256, 0, stream>>>(src, dst, rowptr, deg, csr, E, stride);
    }

    // degree bucketing (uses restored deg)
    (void)hipMemsetAsync(dhist, 0, 64 * sizeof(int), stream);
    deg_hist_kernel<<<NB, 256, 0, stream>>>(deg, dhist, N);
    bucket_scan_kernel<<<1, 64, 0, stream>>>(dhist, dcnt);
    perm_place_kernel<<<NB, 256, 0, stream>>>(deg, dcnt, perm, N);

    // zero rows (index N) of both h buffers
    (void)hipMemsetAsync(hA + (size_t)N * 64, 0, 64, stream);
    (void)hipMemsetAsync(hB + (size_t)N * 64, 0, 64, stream);

    // lin0
    lin0_kernel<<<tile_blocks, 256, 0, stream>>>(x, wf8, b0, hA, N);

    // pooled/cnt init
    (void)hipMemsetAsync(pooled, 0, (size_t)G * HH * sizeof(float), stream);
    (void)hipMemsetAsync(cnt, 0, (size_t)G * sizeof(float), stream);

    // layers (ping-pong); 0..2 degree-bucketed, last natural + fused pool
    const unsigned char* hin = hA; unsigned char* hout = hB;
    const short8* wfL1 = wf8 + 5120;
    for (int l = 0; l < LL; ++l) {
        const short8* wfG1 = wf8 + 1024 + (size_t)(l * 2 + 0) * 512;
        const short8* wfG2 = wf8 + 1024 + (size_t)(l * 2 + 1) * 512;
        if (l < LL - 1) {
            layer_kernel<0><<<tile_blocks, 256, 0, stream>>>(
                hin, rowptr, deg, csr, perm, wfG1, wfG2,
                convb1 + l * HH, convg1 + l * HH, convbt1 + l * HH,
                convb2 + l * HH, convg2 + l * HH, convbt2 + l * HH,
                hout, N, nullptr, nullptr, nullptr, nullptr, nullptr);
        } else {
            layer_kernel<1><<<tile_blocks, 256, 0, stream>>>(
                hin, rowptr, deg, csr, nullptr, wfG1, wfG2,
                convb1 + l * HH, convg1 + l * HH, convbt1 + l * HH,
                convb2 + l * HH, convg2 + l * HH, convbt2 + l * HH,
                nullptr, N, wfL1, bl1, batch, pooled, cnt);
        }
        unsigned char* tswap = (unsigned char*)hin; hin = hout; hout = tswap;
    }

    head_kernel<<<(G + 63) / 64, 64, 0, stream>>>(pooled, cnt, Wl2, bl2, (float*)d_out, G);
}

// Round 13
// 315.631 us; speedup vs baseline: 1.7118x; 1.0312x over previous
//
#include <hip/hip_runtime.h>
#include <hip/hip_bf16.h>

#define HH 64
#define FF 128
#define CC 10
#define LL 4
#define MAXD 32        // LDS neighbor-table depth (tail loop handles deg>32)
#define BN_RSQRT 0.9999950000374997f   // 1/sqrt(1+1e-5)

typedef __hip_bfloat16 bf16;
using short8 = __attribute__((ext_vector_type(8))) short;
using f32x4  = __attribute__((ext_vector_type(4))) float;
using f32x2  = __attribute__((ext_vector_type(2))) float;

__device__ __forceinline__ float us2f(unsigned short u) {
    return __uint_as_float(((unsigned)u) << 16);
}
// RNE f32->bf16 bits (finite inputs)
__device__ __forceinline__ unsigned short f2bf(float v) {
    unsigned u = __float_as_uint(v);
    return (unsigned short)((u + 0x7FFFu + ((u >> 16) & 1u)) >> 16);
}

// ---------- fp8 pack/unpack (HW cvt on gfx950; software fallback) ----------
#if defined(__has_builtin)
#if __has_builtin(__builtin_amdgcn_cvt_pk_f32_fp8) && __has_builtin(__builtin_amdgcn_cvt_pk_fp8_f32)
#define FP8_HW 1
#endif
#endif

#ifdef FP8_HW
template <bool HIGH>
__device__ __forceinline__ f32x2 fp8_dec2(unsigned w) {
    return __builtin_amdgcn_cvt_pk_f32_fp8((int)w, HIGH);
}
__device__ __forceinline__ unsigned fp8_enc4(float f0, float f1, float f2, float f3) {
    int w = 0;
    w = __builtin_amdgcn_cvt_pk_fp8_f32(f0, f1, w, false);
    w = __builtin_amdgcn_cvt_pk_fp8_f32(f2, f3, w, true);
    return (unsigned)w;
}
#else
__device__ __forceinline__ float fp8_dec1(unsigned b) {
    unsigned s = (b & 0x80u) << 24;
    unsigned em = b & 0x7Fu;
    float mag;
    if (em >= 0x08u) mag = __uint_as_float((((em >> 3) + 120u) << 23) | ((em & 7u) << 20));
    else             mag = (float)em * (1.0f / 512.0f);
    return __uint_as_float(__float_as_uint(mag) | s);
}
template <bool HIGH>
__device__ __forceinline__ f32x2 fp8_dec2(unsigned w) {
    unsigned lo = HIGH ? ((w >> 16) & 0xffu) : (w & 0xffu);
    unsigned hi = HIGH ? ((w >> 24) & 0xffu) : ((w >> 8) & 0xffu);
    f32x2 r; r.x = fp8_dec1(lo); r.y = fp8_dec1(hi); return r;
}
__device__ __forceinline__ unsigned fp8_enc1(float v) {
    unsigned u = __float_as_uint(v);
    unsigned s = (u >> 24) & 0x80u;
    float a = fabsf(v);
    if (a >= 448.0f) return s | 0x7Eu;
    if (a < 0.015625f) {
        int m = (int)rintf(a * 512.0f);
        return s | (unsigned)m;
    }
    int e; float m = frexpf(a, &e);
    int E = e + 6;
    int mant = (int)rintf((m * 2.0f - 1.0f) * 8.0f);
    if (mant == 8) { mant = 0; ++E; }
    if (E > 15) return s | 0x7Eu;
    return s | (unsigned)(E << 3) | (unsigned)mant;
}
__device__ __forceinline__ unsigned fp8_enc4(float f0, float f1, float f2, float f3) {
    return fp8_enc1(f0) | (fp8_enc1(f1) << 8) | (fp8_enc1(f2) << 16) | (fp8_enc1(f3) << 24);
}
#endif

// ---------- weight fragment packing ----------
__global__ __launch_bounds__(256) void pack_weights_kernel(
    const float* __restrict__ W0, const float* __restrict__ convW1,
    const float* __restrict__ convW2, const float* __restrict__ Wl1,
    short* __restrict__ wf)
{
    int t = blockIdx.x * 256 + threadIdx.x;
    if (t >= 5632) return;
    const float* W;
    int l, tile, kc, out_idx;
    if (t < 1024) {
        int local = t; int fi = local >> 6; l = local & 63;
        tile = fi >> 2; kc = fi & 3;
        W = W0; out_idx = local;
    } else if (t < 5120) {
        int t2 = t - 1024;
        int m = t2 >> 9;
        int local = t2 & 511;
        int fi = local >> 6; l = local & 63;
        tile = fi >> 1; kc = fi & 1;
        int layer = m >> 1, g = m & 1;
        W = (g ? convW2 : convW1) + (size_t)layer * HH * HH;
        out_idx = 1024 + m * 512 + local;
    } else {
        int local = t - 5120;
        int fi = local >> 6; l = local & 63;
        tile = fi >> 1; kc = fi & 1;
        W = Wl1; out_idx = 5120 + local;
    }
    int k0 = kc * 32 + (l >> 4) * 8;
    int n = tile * 16 + (l & 15);
#pragma unroll
    for (int e = 0; e < 8; ++e)
        wf[out_idx * 8 + e] = (short)f2bf(W[(k0 + e) * HH + n]);
}

// ---------- lin0 (MFMA): h = relu(x @ W0 + b0), out fp8 ----------
__global__ __launch_bounds__(256) void lin0_kernel(
    const float* __restrict__ x, const short8* __restrict__ wf0,
    const float* __restrict__ b0, unsigned char* __restrict__ h, int nrows)
{
    __shared__ __align__(16) short lds_all[4][2048];   // per wave [16][128] bf16
    int wave = __builtin_amdgcn_readfirstlane(threadIdx.x >> 6);
    int lane = threadIdx.x & 63;
    char* ldsb = (char*)&lds_all[wave][0];
    int r0 = (blockIdx.x * 4 + wave) * 16;

#pragma unroll
    for (int r = 0; r < 16; ++r) {
        int row = r0 + r;
        float2 xv = make_float2(0.f, 0.f);
        if (row < nrows) xv = *(const float2*)(x + (size_t)row * FF + lane * 2);
        unsigned pk = (unsigned)f2bf(xv.x) | ((unsigned)f2bf(xv.y) << 16);
        *(int*)(ldsb + r * 256 + ((lane * 4) ^ ((r & 7) << 4))) = pk;
    }
    __syncthreads();

    short8 a[4];
#pragma unroll
    for (int kc = 0; kc < 4; ++kc) {
        int rr = lane & 15;
        a[kc] = *(const short8*)(ldsb + rr * 256 + (((kc * 64 + (lane >> 4) * 16)) ^ ((rr & 7) << 4)));
    }
    f32x4 acc[4];
#pragma unroll
    for (int tile = 0; tile < 4; ++tile) {
        acc[tile] = (f32x4){0.f, 0.f, 0.f, 0.f};
#pragma unroll
        for (int kc = 0; kc < 4; ++kc) {
            short8 b = wf0[(tile * 4 + kc) * 64 + lane];
            acc[tile] = __builtin_amdgcn_mfma_f32_16x16x32_bf16(a[kc], b, acc[tile], 0, 0, 0);
        }
    }
    __syncthreads();
#pragma unroll
    for (int tile = 0; tile < 4; ++tile) {
        int col = tile * 16 + (lane & 15);
        float bia = b0[col];
#pragma unroll
        for (int q = 0; q < 4; ++q) {
            int row = (lane >> 4) * 4 + q;
            float v = fmaxf(acc[tile][q] + bia, 0.0f);
            *(short*)(ldsb + row * 256 + ((col * 2) ^ ((row & 7) << 4))) = (short)f2bf(v);
        }
    }
    __syncthreads();
#pragma unroll
    for (int half = 0; half < 2; ++half) {
        int row = (lane >> 3) + half * 8;
        short8 vv = *(const short8*)(ldsb + row * 256 + ((((lane & 7) * 16)) ^ ((row & 7) << 4)));
        int grow = r0 + row;
        if (grow < nrows) {
            unsigned w0 = fp8_enc4(us2f((unsigned short)vv[0]), us2f((unsigned short)vv[1]),
                                   us2f((unsigned short)vv[2]), us2f((unsigned short)vv[3]));
            unsigned w1 = fp8_enc4(us2f((unsigned short)vv[4]), us2f((unsigned short)vv[5]),
                                   us2f((unsigned short)vv[6]), us2f((unsigned short)vv[7]));
            *(uint2*)(h + (size_t)grow * 64 + (lane & 7) * 8) = make_uint2(w0, w1);
        }
    }
}

// ---------- CSR build ----------
__global__ __launch_bounds__(256) void hist_kernel(
    const int* __restrict__ dst, int* __restrict__ deg, int nedges)
{
    int e = blockIdx.x * 256 + threadIdx.x;
    if (e < nedges) atomicAdd(&deg[dst[e]], 1);
}

__global__ __launch_bounds__(256) void scan_block_kernel(
    const int* __restrict__ deg, int* __restrict__ rowptr,
    int* __restrict__ partials, int n)
{
    __shared__ int sm[256];
    int tid = threadIdx.x;
    int i = blockIdx.x * 256 + tid;
    int v = (i < n) ? deg[i] : 0;
    sm[tid] = v;
    __syncthreads();
    for (int ofs = 1; ofs < 256; ofs <<= 1) {
        int t = (tid >= ofs) ? sm[tid - ofs] : 0;
        __syncthreads();
        sm[tid] += t;
        __syncthreads();
    }
    if (i < n) rowptr[i] = sm[tid] - v;
    if (tid == 255) partials[blockIdx.x] = sm[255];
}

__global__ __launch_bounds__(256) void scan_partials_kernel(int* partials, int nb)
{
    __shared__ int sm[256];
    __shared__ int carry;
    int tid = threadIdx.x;
    if (tid == 0) carry = 0;
    __syncthreads();
    for (int base = 0; base < nb; base += 256) {
        int i = base + tid;
        int v = (i < nb) ? partials[i] : 0;
        sm[tid] = v;
        __syncthreads();
        for (int ofs = 1; ofs < 256; ofs <<= 1) {
            int t = (tid >= ofs) ? sm[tid - ofs] : 0;
            __syncthreads();
            sm[tid] += t;
            __syncthreads();
        }
        int cbase = carry;
        int tot = sm[255];
        if (i < nb) partials[i] = sm[tid] - v + cbase;
        __syncthreads();
        if (tid == 0) carry = cbase + tot;
        __syncthreads();
    }
}

__global__ __launch_bounds__(256) void add_offsets_kernel(
    int* __restrict__ rowptr, const int* __restrict__ partials, int n)
{
    int i = blockIdx.x * 256 + threadIdx.x;
    if (i < n) rowptr[i] += partials[blockIdx.x];
}

// XCD-partitioned CSR fill: group x = blockIdx&7 owns dst range [x*nspan, x*nspan+nspan);
// each group grid-strides over ALL edges; csr/deg writes stay XCD-local (L2 absorbs
// the 4B-store write amplification). 4-way unrolled for atomic-chain ILP.
__global__ __launch_bounds__(256) void place_kernel(
    const int* __restrict__ src, const int* __restrict__ dst,
    const int* __restrict__ rowptr, int* __restrict__ deg,
    int* __restrict__ csr, int nedges, int n, int nspan)
{
    int x = blockIdx.x & 7;
    int k = blockIdx.x >> 3;
    int lo = x * nspan;
    int hi = min(lo + nspan, n);
    int gs = (int)(gridDim.x >> 3) * 256;     // stride within group
    for (int e0 = k * 256 + (int)threadIdx.x; e0 < nedges; e0 += 4 * gs) {
        int e[4], d[4];
        bool ok[4];
#pragma unroll
        for (int i = 0; i < 4; ++i) {
            e[i] = e0 + i * gs;
            bool in = e[i] < nedges;
            d[i] = in ? dst[e[i]] : 0;
            ok[i] = in && d[i] >= lo && d[i] < hi;
        }
        int s[4], slot[4];
#pragma unroll
        for (int i = 0; i < 4; ++i)
            s[i] = ok[i] ? src[e[i]] : 0;
#pragma unroll
        for (int i = 0; i < 4; ++i)
            slot[i] = ok[i] ? atomicAdd(&deg[d[i]], 1) : 0;
#pragma unroll
        for (int i = 0; i < 4; ++i)
            if (ok[i]) csr[rowptr[d[i]] + slot[i]] = s[i];
    }
}

// ---------- degree bucketing (counting sort, 64 bins) ----------
__global__ __launch_bounds__(256) void deg_hist_kernel(
    const int* __restrict__ deg, int* __restrict__ dhist, int n)
{
    __shared__ int lh[64];
    int tid = threadIdx.x;
    if (tid < 64) lh[tid] = 0;
    __syncthreads();
    int i = blockIdx.x * 256 + tid;
    if (i < n) atomicAdd(&lh[min(deg[i], 63)], 1);
    __syncthreads();
    if (tid < 64 && lh[tid]) atomicAdd(&dhist[tid], lh[tid]);
}

__global__ __launch_bounds__(64) void bucket_scan_kernel(
    const int* __restrict__ dhist, int* __restrict__ dcnt)
{
    __shared__ int sm[64];
    int t = threadIdx.x;
    sm[t] = dhist[t];
    __syncthreads();
    int acc = 0;
    for (int k = 0; k < t; ++k) acc += sm[k];
    dcnt[t] = acc;          // dcnt starts as the bucket base cursor
}

__global__ __launch_bounds__(256) void perm_place_kernel(
    const int* __restrict__ deg, int* __restrict__ dcnt,
    int* __restrict__ perm, int n)
{
    __shared__ int lh[64], lbase[64];
    int tid = threadIdx.x;
    if (tid < 64) lh[tid] = 0;
    __syncthreads();
    int i = blockIdx.x * 256 + tid;
    int b = 0;
    if (i < n) { b = min(deg[i], 63); atomicAdd(&lh[b], 1); }
    __syncthreads();
    if (tid < 64) {
        int cntb = lh[tid];
        if (cntb) lbase[tid] = atomicAdd(&dcnt[tid], cntb);
        lh[tid] = 0;
    }
    __syncthreads();
    if (i < n) {
        int r = atomicAdd(&lh[b], 1);
        perm[lbase[b] + r] = i;
    }
}

// ---------- fused MFMA layer, fp8 h, LDS-union idx/z tile, zero-row padding ----------
// LDS per wave: 2KB, time-multiplexed: idx table int[16][32] during gather,
// then z tile bf16[16][64] for the GEMMs. Self row offsets in self_tab.
// Gather: 8 lanes x 8B per row; j unrolled x8 -> 16 uint2 loads in flight.
template <int FINAL>
__global__ __launch_bounds__(256, 5) void layer_kernel(
    const unsigned char* __restrict__ h, const int* __restrict__ rowptr,
    const int* __restrict__ deg, const int* __restrict__ csr,
    const int* __restrict__ perm,
    const short8* __restrict__ wfG1, const short8* __restrict__ wfG2,
    const float* __restrict__ b1, const float* __restrict__ g1, const float* __restrict__ bt1,
    const float* __restrict__ b2, const float* __restrict__ g2, const float* __restrict__ bt2,
    unsigned char* __restrict__ out, int nrows,
    const short8* __restrict__ wfL1, const float* __restrict__ bl1,
    const int* __restrict__ batch, float* __restrict__ pooled, float* __restrict__ cnt)
{
    __shared__ __align__(16) char lds_u[4][2048];   // per-wave union: idx[16][32] / z bf16[16][64]
    __shared__ int self_tab[4][16];
    int wave = __builtin_amdgcn_readfirstlane(threadIdx.x >> 6);
    int lane = threadIdx.x & 63;
    char* ldsb = &lds_u[wave][0];
    int* idxp = (int*)ldsb;
    int r0 = (blockIdx.x * 4 + wave) * 16;

    // ---- row metadata (scalar) + neighbor table fill ----
    int s16[16], c16[16], maxc = 0;
#pragma unroll
    for (int r = 0; r < 16; ++r) {
        int gi = r0 + r;
        int pr = nrows;                       // zero row for OOB
        int sv = 0, cv = 0;
        if (gi < nrows) {
            pr = perm ? perm[gi] : gi;
            sv = rowptr[pr]; cv = deg[pr];
        }
        pr = __builtin_amdgcn_readfirstlane(pr);
        s16[r] = __builtin_amdgcn_readfirstlane(sv);
        c16[r] = __builtin_amdgcn_readfirstlane(cv);
        maxc = max(maxc, c16[r]);
        int idxv = nrows;
        if (lane < c16[r]) idxv = csr[s16[r] + lane];
        idxv = min(max(idxv, 0), nrows) << 6;            // byte offset, clamped
        if (lane < MAXD) idxp[r * MAXD + lane] = idxv;
        if (lane == 0) self_tab[wave][r] = pr << 6;      // self
    }

    int selrow = lane >> 3;          // row within 8-row group served by this lane
    int fq4 = (lane & 7) * 8;        // fp8 byte offset of this lane's 8-feature span
    int fq8 = fq4 * 2;               // bf16 byte offset (16B per lane)

    // ---- self init ----
    float zg[2][8];
#pragma unroll
    for (int g = 0; g < 2; ++g) {
        int bo = self_tab[wave][g * 8 + selrow];
        uint2 w = *(const uint2*)(h + bo + fq4);
        f32x2 p0 = fp8_dec2<false>(w.x), p1 = fp8_dec2<true>(w.x);
        f32x2 p2 = fp8_dec2<false>(w.y), p3 = fp8_dec2<true>(w.y);
        zg[g][0] = p0.x; zg[g][1] = p0.y; zg[g][2] = p1.x; zg[g][3] = p1.y;
        zg[g][4] = p2.x; zg[g][5] = p2.y; zg[g][6] = p3.x; zg[g][7] = p3.y;
    }

    // ---- gather main loop: dummy slots read the zero row (cached) ----
    int jm = min(maxc, MAXD);
    for (int j0 = 0; j0 < jm; j0 += 8) {
        uint2 w[8][2];
#pragma unroll
        for (int jj = 0; jj < 8; ++jj) {
            int jcl = min(j0 + jj, MAXD - 1);
#pragma unroll
            for (int g = 0; g < 2; ++g) {
                int bo = idxp[(g * 8 + selrow) * MAXD + jcl];
                w[jj][g] = *(const uint2*)(h + bo + fq4);
            }
        }
#pragma unroll
        for (int jj = 0; jj < 8; ++jj)
#pragma unroll
            for (int g = 0; g < 2; ++g) {
                f32x2 p0 = fp8_dec2<false>(w[jj][g].x), p1 = fp8_dec2<true>(w[jj][g].x);
                f32x2 p2 = fp8_dec2<false>(w[jj][g].y), p3 = fp8_dec2<true>(w[jj][g].y);
                zg[g][0] += p0.x; zg[g][1] += p0.y; zg[g][2] += p1.x; zg[g][3] += p1.y;
                zg[g][4] += p2.x; zg[g][5] += p2.y; zg[g][6] += p3.x; zg[g][7] += p3.y;
            }
    }
    if (maxc > MAXD) {    // rare tail, scalar per row
#pragma unroll
        for (int g = 0; g < 2; ++g) {
#pragma unroll
            for (int q = 0; q < 8; ++q) {
                int r = g * 8 + q;
                for (int j = MAXD; j < c16[r]; ++j) {
                    int sn = csr[s16[r] + j];
                    sn = min(max(sn, 0), nrows - 1);
                    uint2 w = *(const uint2*)(h + ((size_t)sn << 6) + fq4);
                    f32x2 p0 = fp8_dec2<false>(w.x), p1 = fp8_dec2<true>(w.x);
                    f32x2 p2 = fp8_dec2<false>(w.y), p3 = fp8_dec2<true>(w.y);
                    bool mine = (selrow == q);
                    zg[g][0] += mine ? p0.x : 0.f;
                    zg[g][1] += mine ? p0.y : 0.f;
                    zg[g][2] += mine ? p1.x : 0.f;
                    zg[g][3] += mine ? p1.y : 0.f;
                    zg[g][4] += mine ? p2.x : 0.f;
                    zg[g][5] += mine ? p2.y : 0.f;
                    zg[g][6] += mine ? p3.x : 0.f;
                    zg[g][7] += mine ? p3.y : 0.f;
                }
            }
        }
    }
    __syncthreads();   // all idx reads complete before the union flips to z-tile

    // ---- z -> LDS bf16 [16][64], XOR-swizzled (16B stores) ----
#pragma unroll
    for (int g = 0; g < 2; ++g) {
        int row = g * 8 + selrow;
        short8 pk;
#pragma unroll
        for (int k = 0; k < 8; ++k) pk[k] = (short)f2bf(zg[g][k]);
        int off = (row * 128 + fq8) ^ ((row & 7) << 4);
        *(short8*)(ldsb + off) = pk;
    }
    __syncthreads();

    short8 a0, a1;
    f32x4 acc[4];
    // ---- GEMM1 + BN + ReLU ----
    {
        int rr = lane & 15;
        a0 = *(const short8*)(ldsb + rr * 128 + (((lane >> 4) * 16) ^ ((rr & 7) << 4)));
        a1 = *(const short8*)(ldsb + rr * 128 + ((64 + (lane >> 4) * 16) ^ ((rr & 7) << 4)));
    }
#pragma unroll
    for (int tile = 0; tile < 4; ++tile) {
        acc[tile] = (f32x4){0.f, 0.f, 0.f, 0.f};
        acc[tile] = __builtin_amdgcn_mfma_f32_16x16x32_bf16(a0, wfG1[(tile * 2 + 0) * 64 + lane], acc[tile], 0, 0, 0);
        acc[tile] = __builtin_amdgcn_mfma_f32_16x16x32_bf16(a1, wfG1[(tile * 2 + 1) * 64 + lane], acc[tile], 0, 0, 0);
    }
    __syncthreads();
#pragma unroll
    for (int tile = 0; tile < 4; ++tile) {
        int col = tile * 16 + (lane & 15);
        float sc = g1[col] * BN_RSQRT;
        float sh = fmaf(b1[col], sc, bt1[col]);
#pragma unroll
        for (int q = 0; q < 4; ++q) {
            int row = (lane >> 4) * 4 + q;
            float v = fmaxf(fmaf(acc[tile][q], sc, sh), 0.0f);
            *(short*)(ldsb + row * 128 + ((col * 2) ^ ((row & 7) << 4))) = (short)f2bf(v);
        }
    }
    __syncthreads();

    // ---- GEMM2 + BN + ReLU ----
    {
        int rr = lane & 15;
        a0 = *(const short8*)(ldsb + rr * 128 + (((lane >> 4) * 16) ^ ((rr & 7) << 4)));
        a1 = *(const short8*)(ldsb + rr * 128 + ((64 + (lane >> 4) * 16) ^ ((rr & 7) << 4)));
    }
#pragma unroll
    for (int tile = 0; tile < 4; ++tile) {
        acc[tile] = (f32x4){0.f, 0.f, 0.f, 0.f};
        acc[tile] = __builtin_amdgcn_mfma_f32_16x16x32_bf16(a0, wfG2[(tile * 2 + 0) * 64 + lane], acc[tile], 0, 0, 0);
        acc[tile] = __builtin_amdgcn_mfma_f32_16x16x32_bf16(a1, wfG2[(tile * 2 + 1) * 64 + lane], acc[tile], 0, 0, 0);
    }
    __syncthreads();
#pragma unroll
    for (int tile = 0; tile < 4; ++tile) {
        int col = tile * 16 + (lane & 15);
        float sc = g2[col] * BN_RSQRT;
        float sh = fmaf(b2[col], sc, bt2[col]);
#pragma unroll
        for (int q = 0; q < 4; ++q) {
            int row = (lane >> 4) * 4 + q;
            float v = fmaxf(fmaf(acc[tile][q], sc, sh), 0.0f);
            *(short*)(ldsb + row * 128 + ((col * 2) ^ ((row & 7) << 4))) = (short)f2bf(v);
        }
    }
    __syncthreads();

    if (FINAL == 0) {
        // fp8-pack + store (row offset from self_tab; zero row excluded by guard)
#pragma unroll
        for (int half = 0; half < 2; ++half) {
            int row = (lane >> 3) + half * 8;
            short8 vv = *(const short8*)(ldsb + row * 128 + ((((lane & 7) * 16)) ^ ((row & 7) << 4)));
            int ro = self_tab[wave][row];
            if (ro < (nrows << 6)) {
                unsigned w0 = fp8_enc4(us2f((unsigned short)vv[0]), us2f((unsigned short)vv[1]),
                                       us2f((unsigned short)vv[2]), us2f((unsigned short)vv[3]));
                unsigned w1 = fp8_enc4(us2f((unsigned short)vv[4]), us2f((unsigned short)vv[5]),
                                       us2f((unsigned short)vv[6]), us2f((unsigned short)vv[7]));
                *(uint2*)(out + ro + (lane & 7) * 8) = make_uint2(w0, w1);
            }
        }
    } else {
        // ---- GEMM3: relu(h4 @ Wl1 + bl1) ----
        {
            int rr = lane & 15;
            a0 = *(const short8*)(ldsb + rr * 128 + (((lane >> 4) * 16) ^ ((rr & 7) << 4)));
            a1 = *(const short8*)(ldsb + rr * 128 + ((64 + (lane >> 4) * 16) ^ ((rr & 7) << 4)));
        }
#pragma unroll
        for (int tile = 0; tile < 4; ++tile) {
            acc[tile] = (f32x4){0.f, 0.f, 0.f, 0.f};
            acc[tile] = __builtin_amdgcn_mfma_f32_16x16x32_bf16(a0, wfL1[(tile * 2 + 0) * 64 + lane], acc[tile], 0, 0, 0);
            acc[tile] = __builtin_amdgcn_mfma_f32_16x16x32_bf16(a1, wfL1[(tile * 2 + 1) * 64 + lane], acc[tile], 0, 0, 0);
        }
        __syncthreads();
#pragma unroll
        for (int tile = 0; tile < 4; ++tile) {
            int col = tile * 16 + (lane & 15);
            float bia = bl1[col];
#pragma unroll
            for (int q = 0; q < 4; ++q) {
                int row = (lane >> 4) * 4 + q;
                float v = fmaxf(acc[tile][q] + bia, 0.0f);
                *(short*)(ldsb + row * 128 + ((col * 2) ^ ((row & 7) << 4))) = (short)f2bf(v);
            }
        }
        __syncthreads();
        // ---- in-kernel mean-pool partials (natural order, batch sorted) ----
        float pacc = 0.0f;
        int curg = -1, rc = 0;
        for (int r = 0; r < 16; ++r) {
            int row = r0 + r;
            if (row >= nrows) break;
            float v = us2f(*(const unsigned short*)(ldsb + r * 128 + ((lane * 2) ^ ((r & 7) << 4))));
            int g = batch[row];
            if (g != curg) {
                if (curg >= 0) {
                    atomicAdd(&pooled[curg * HH + lane], pacc);
                    if (lane == 0) atomicAdd(&cnt[curg], (float)rc);
                }
                curg = g; pacc = v; rc = 1;
            } else { pacc += v; rc += 1; }
        }
        if (curg >= 0) {
            atomicAdd(&pooled[curg * HH + lane], pacc);
            if (lane == 0) atomicAdd(&cnt[curg], (float)rc);
        }
    }
}

__global__ __launch_bounds__(64) void head_kernel(
    const float* __restrict__ pooled, const float* __restrict__ cnt,
    const float* __restrict__ Wl2, const float* __restrict__ bl2,
    float* __restrict__ out, int ngraphs)
{
    int gidx = blockIdx.x * 64 + threadIdx.x;
    if (gidx >= ngraphs) return;
    float logits[CC];
#pragma unroll
    for (int c = 0; c < CC; ++c) logits[c] = bl2[c];
    float inv_n = 1.0f / fmaxf(cnt[gidx], 1.0f);
    for (int k = 0; k < HH; ++k) {
        float p = pooled[gidx * HH + k] * inv_n;
#pragma unroll
        for (int c = 0; c < CC; ++c) logits[c] = fmaf(p, Wl2[k * CC + c], logits[c]);
    }
    float m = logits[0];
#pragma unroll
    for (int c = 1; c < CC; ++c) m = fmaxf(m, logits[c]);
    float ssum = 0.0f;
#pragma unroll
    for (int c = 0; c < CC; ++c) { logits[c] = __expf(logits[c] - m); ssum += logits[c]; }
    float inv = 1.0f / ssum;
#pragma unroll
    for (int c = 0; c < CC; ++c) out[gidx * CC + c] = logits[c] * inv;
}

extern "C" void kernel_launch(void* const* d_in, const int* in_sizes, int n_in,
                              void* d_out, int out_size, void* d_ws, size_t ws_size,
                              hipStream_t stream) {
    const float* x      = (const float*)d_in[0];
    const int*   ei     = (const int*)  d_in[1];
    const int*   batch  = (const int*)  d_in[3];
    const float* W0     = (const float*)d_in[4];
    const float* b0     = (const float*)d_in[5];
    const float* convW1 = (const float*)d_in[6];
    const float* convb1 = (const float*)d_in[7];
    const float* convg1 = (const float*)d_in[8];
    const float* convbt1= (const float*)d_in[9];
    const float* convW2 = (const float*)d_in[10];
    const float* convb2 = (const float*)d_in[11];
    const float* convg2 = (const float*)d_in[12];
    const float* convbt2= (const float*)d_in[13];
    const float* Wl1    = (const float*)d_in[14];
    const float* bl1    = (const float*)d_in[15];
    const float* Wl2    = (const float*)d_in[16];
    const float* bl2    = (const float*)d_in[17];

    const int N = in_sizes[0] / FF;
    const int E = in_sizes[1] / 2;
    const int G = out_size / CC;

    const int* src = ei;
    const int* dst = ei + E;

    size_t off = 0;
    auto take = [&](size_t bytes) { size_t p = off; off = (off + bytes + 255) & ~255ULL; return p; };
    int NB = (N + 255) / 256;
    int EB = (E + 255) / 256;
    size_t o_rowptr = take((size_t)N * 4);
    size_t o_deg    = take((size_t)N * 4);
    size_t o_csr    = take((size_t)(E > NB ? E : NB) * 4 + 512);
    size_t o_perm   = take((size_t)N * 4);
    size_t o_dhist  = take(64 * 4);
    size_t o_dcnt   = take(64 * 4);
    size_t o_pooled = take((size_t)G * HH * 4);
    size_t o_cnt    = take((size_t)G * 4);
    size_t o_wfrag  = take((size_t)5632 * 8 * 2);
    size_t o_hA     = take((size_t)(N + 1) * 64);
    size_t o_hB     = take((size_t)(N + 1) * 64);

    char* base = (char*)d_ws;
    int*    rowptr = (int*)(base + o_rowptr);
    int*    deg    = (int*)(base + o_deg);
    int*    csr    = (int*)(base + o_csr);
    int*    perm   = (int*)(base + o_perm);
    int*    dhist  = (int*)(base + o_dhist);
    int*    dcnt   = (int*)(base + o_dcnt);
    float*  pooled = (float*)(base + o_pooled);
    float*  cnt    = (float*)(base + o_cnt);
    short*  wfrag  = (short*)(base + o_wfrag);
    short8* wf8    = (short8*)wfrag;
    unsigned char* hA = (unsigned char*)(base + o_hA);
    unsigned char* hB = (unsigned char*)(base + o_hB);

    int tile_blocks = (N + 63) / 64;     // 4 waves x 16 rows

    // weight fragment packing
    pack_weights_kernel<<<22, 256, 0, stream>>>(W0, convW1, convW2, Wl1, wfrag);

    // CSR build
    (void)hipMemsetAsync(deg, 0, (size_t)N * sizeof(int), stream);
    hist_kernel<<<EB, 256, 0, stream>>>(dst, deg, E);
    scan_block_kernel<<<NB, 256, 0, stream>>>(deg, rowptr, csr /*partials*/, N);
    scan_partials_kernel<<<1, 256, 0, stream>>>(csr, NB);
    add_offsets_kernel<<<NB, 256, 0, stream>>>(rowptr, csr, N);
    (void)hipMemsetAsync(deg, 0, (size_t)N * sizeof(int), stream);
    {
        int nspan = (N + 7) / 8;
        place_kernel<<<640, 256, 0, stream>>>(src, dst, rowptr, deg, csr, E, N, nspan);
    }

    // degree bucketing (uses restored deg)
    (void)hipMemsetAsync(dhist, 0, 64 * sizeof(int), stream);
    deg_hist_kernel<<<NB, 256, 0, stream>>>(deg, dhist, N);
    bucket_scan_kernel<<<1, 64, 0, stream>>>(dhist, dcnt);
    perm_place_kernel<<<NB, 256, 0, stream>>>(deg, dcnt, perm, N);

    // zero rows (index N) of both h buffers
    (void)hipMemsetAsync(hA + (size_t)N * 64, 0, 64, stream);
    (void)hipMemsetAsync(hB + (size_t)N * 64, 0, 64, stream);

    // lin0
    lin0_kernel<<<tile_blocks, 256, 0, stream>>>(x, wf8, b0, hA, N);

    // pooled/cnt init
    (void)hipMemsetAsync(pooled, 0, (size_t)G * HH * sizeof(float), stream);
    (void)hipMemsetAsync(cnt, 0, (size_t)G * sizeof(float), stream);

    // layers (ping-pong); 0..2 degree-bucketed, last natural + fused pool
    const unsigned char* hin = hA; unsigned char* hout = hB;
    const short8* wfL1 = wf8 + 5120;
    for (int l = 0; l < LL; ++l) {
        const short8* wfG1 = wf8 + 1024 + (size_t)(l * 2 + 0) * 512;
        const short8* wfG2 = wf8 + 1024 + (size_t)(l * 2 + 1) * 512;
        if (l < LL - 1) {
            layer_kernel<0><<<tile_blocks, 256, 0, stream>>>(
                hin, rowptr, deg, csr, perm, wfG1, wfG2,
                convb1 + l * HH, convg1 + l * HH, convbt1 + l * HH,
                convb2 + l * HH, convg2 + l * HH, convbt2 + l * HH,
                hout, N, nullptr, nullptr, nullptr, nullptr, nullptr);
        } else {
            layer_kernel<1><<<tile_blocks, 256, 0, stream>>>(
                hin, rowptr, deg, csr, nullptr, wfG1, wfG2,
                convb1 + l * HH, convg1 + l * HH, convbt1 + l * HH,
                convb2 + l * HH, convg2 + l * HH, convbt2 + l * HH,
                nullptr, N, wfL1, bl1, batch, pooled, cnt);
        }
        unsigned char* tswap = (unsigned char*)hin; hin = hout; hout = tswap;
    }

    head_kernel<<<(G + 63) / 64, 64, 0, stream>>>(pooled, cnt, Wl2, bl2, (float*)d_out, G);
}

// Round 14
// 309.400 us; speedup vs baseline: 1.7463x; 1.0201x over previous
//
#include <hip/hip_runtime.h>
#include <hip/hip_bf16.h>

#define HH 64
#define FF 128
#define CC 10
#define LL 4
#define MAXD 32        // LDS neighbor-table depth (tail loop handles deg>32)
#define BN_RSQRT 0.9999950000374997f   // 1/sqrt(1+1e-5)

typedef __hip_bfloat16 bf16;
using short8 = __attribute__((ext_vector_type(8))) short;
using f32x4  = __attribute__((ext_vector_type(4))) float;
using f32x2  = __attribute__((ext_vector_type(2))) float;

__device__ __forceinline__ float us2f(unsigned short u) {
    return __uint_as_float(((unsigned)u) << 16);
}
// RNE f32->bf16 bits (finite inputs)
__device__ __forceinline__ unsigned short f2bf(float v) {
    unsigned u = __float_as_uint(v);
    return (unsigned short)((u + 0x7FFFu + ((u >> 16) & 1u)) >> 16);
}

// ---------- fp8 pack/unpack (HW cvt on gfx950; software fallback) ----------
#if defined(__has_builtin)
#if __has_builtin(__builtin_amdgcn_cvt_pk_f32_fp8) && __has_builtin(__builtin_amdgcn_cvt_pk_fp8_f32)
#define FP8_HW 1
#endif
#endif

#ifdef FP8_HW
template <bool HIGH>
__device__ __forceinline__ f32x2 fp8_dec2(unsigned w) {
    return __builtin_amdgcn_cvt_pk_f32_fp8((int)w, HIGH);
}
__device__ __forceinline__ unsigned fp8_enc4(float f0, float f1, float f2, float f3) {
    int w = 0;
    w = __builtin_amdgcn_cvt_pk_fp8_f32(f0, f1, w, false);
    w = __builtin_amdgcn_cvt_pk_fp8_f32(f2, f3, w, true);
    return (unsigned)w;
}
#else
__device__ __forceinline__ float fp8_dec1(unsigned b) {
    unsigned s = (b & 0x80u) << 24;
    unsigned em = b & 0x7Fu;
    float mag;
    if (em >= 0x08u) mag = __uint_as_float((((em >> 3) + 120u) << 23) | ((em & 7u) << 20));
    else             mag = (float)em * (1.0f / 512.0f);
    return __uint_as_float(__float_as_uint(mag) | s);
}
template <bool HIGH>
__device__ __forceinline__ f32x2 fp8_dec2(unsigned w) {
    unsigned lo = HIGH ? ((w >> 16) & 0xffu) : (w & 0xffu);
    unsigned hi = HIGH ? ((w >> 24) & 0xffu) : ((w >> 8) & 0xffu);
    f32x2 r; r.x = fp8_dec1(lo); r.y = fp8_dec1(hi); return r;
}
__device__ __forceinline__ unsigned fp8_enc1(float v) {
    unsigned u = __float_as_uint(v);
    unsigned s = (u >> 24) & 0x80u;
    float a = fabsf(v);
    if (a >= 448.0f) return s | 0x7Eu;
    if (a < 0.015625f) {
        int m = (int)rintf(a * 512.0f);
        return s | (unsigned)m;
    }
    int e; float m = frexpf(a, &e);
    int E = e + 6;
    int mant = (int)rintf((m * 2.0f - 1.0f) * 8.0f);
    if (mant == 8) { mant = 0; ++E; }
    if (E > 15) return s | 0x7Eu;
    return s | (unsigned)(E << 3) | (unsigned)mant;
}
__device__ __forceinline__ unsigned fp8_enc4(float f0, float f1, float f2, float f3) {
    return fp8_enc1(f0) | (fp8_enc1(f1) << 8) | (fp8_enc1(f2) << 16) | (fp8_enc1(f3) << 24);
}
#endif

// ---------- weight fragment packing ----------
__global__ __launch_bounds__(256) void pack_weights_kernel(
    const float* __restrict__ W0, const float* __restrict__ convW1,
    const float* __restrict__ convW2, const float* __restrict__ Wl1,
    short* __restrict__ wf)
{
    int t = blockIdx.x * 256 + threadIdx.x;
    if (t >= 5632) return;
    const float* W;
    int l, tile, kc, out_idx;
    if (t < 1024) {
        int local = t; int fi = local >> 6; l = local & 63;
        tile = fi >> 2; kc = fi & 3;
        W = W0; out_idx = local;
    } else if (t < 5120) {
        int t2 = t - 1024;
        int m = t2 >> 9;
        int local = t2 & 511;
        int fi = local >> 6; l = local & 63;
        tile = fi >> 1; kc = fi & 1;
        int layer = m >> 1, g = m & 1;
        W = (g ? convW2 : convW1) + (size_t)layer * HH * HH;
        out_idx = 1024 + m * 512 + local;
    } else {
        int local = t - 5120;
        int fi = local >> 6; l = local & 63;
        tile = fi >> 1; kc = fi & 1;
        W = Wl1; out_idx = 5120 + local;
    }
    int k0 = kc * 32 + (l >> 4) * 8;
    int n = tile * 16 + (l & 15);
#pragma unroll
    for (int e = 0; e < 8; ++e)
        wf[out_idx * 8 + e] = (short)f2bf(W[(k0 + e) * HH + n]);
}

// ---------- lin0 (MFMA): h = relu(x @ W0 + b0), out fp8 ----------
__global__ __launch_bounds__(256) void lin0_kernel(
    const float* __restrict__ x, const short8* __restrict__ wf0,
    const float* __restrict__ b0, unsigned char* __restrict__ h, int nrows)
{
    __shared__ __align__(16) short lds_all[4][2048];   // per wave [16][128] bf16
    int wave = __builtin_amdgcn_readfirstlane(threadIdx.x >> 6);
    int lane = threadIdx.x & 63;
    char* ldsb = (char*)&lds_all[wave][0];
    int r0 = (blockIdx.x * 4 + wave) * 16;

#pragma unroll
    for (int r = 0; r < 16; ++r) {
        int row = r0 + r;
        float2 xv = make_float2(0.f, 0.f);
        if (row < nrows) xv = *(const float2*)(x + (size_t)row * FF + lane * 2);
        unsigned pk = (unsigned)f2bf(xv.x) | ((unsigned)f2bf(xv.y) << 16);
        *(int*)(ldsb + r * 256 + ((lane * 4) ^ ((r & 7) << 4))) = pk;
    }
    __syncthreads();

    short8 a[4];
#pragma unroll
    for (int kc = 0; kc < 4; ++kc) {
        int rr = lane & 15;
        a[kc] = *(const short8*)(ldsb + rr * 256 + (((kc * 64 + (lane >> 4) * 16)) ^ ((rr & 7) << 4)));
    }
    f32x4 acc[4];
#pragma unroll
    for (int tile = 0; tile < 4; ++tile) {
        acc[tile] = (f32x4){0.f, 0.f, 0.f, 0.f};
#pragma unroll
        for (int kc = 0; kc < 4; ++kc) {
            short8 b = wf0[(tile * 4 + kc) * 64 + lane];
            acc[tile] = __builtin_amdgcn_mfma_f32_16x16x32_bf16(a[kc], b, acc[tile], 0, 0, 0);
        }
    }
    __syncthreads();
#pragma unroll
    for (int tile = 0; tile < 4; ++tile) {
        int col = tile * 16 + (lane & 15);
        float bia = b0[col];
#pragma unroll
        for (int q = 0; q < 4; ++q) {
            int row = (lane >> 4) * 4 + q;
            float v = fmaxf(acc[tile][q] + bia, 0.0f);
            *(short*)(ldsb + row * 256 + ((col * 2) ^ ((row & 7) << 4))) = (short)f2bf(v);
        }
    }
    __syncthreads();
#pragma unroll
    for (int half = 0; half < 2; ++half) {
        int row = (lane >> 3) + half * 8;
        short8 vv = *(const short8*)(ldsb + row * 256 + ((((lane & 7) * 16)) ^ ((row & 7) << 4)));
        int grow = r0 + row;
        if (grow < nrows) {
            unsigned w0 = fp8_enc4(us2f((unsigned short)vv[0]), us2f((unsigned short)vv[1]),
                                   us2f((unsigned short)vv[2]), us2f((unsigned short)vv[3]));
            unsigned w1 = fp8_enc4(us2f((unsigned short)vv[4]), us2f((unsigned short)vv[5]),
                                   us2f((unsigned short)vv[6]), us2f((unsigned short)vv[7]));
            *(uint2*)(h + (size_t)grow * 64 + (lane & 7) * 8) = make_uint2(w0, w1);
        }
    }
}

// ---------- CSR build ----------
__global__ __launch_bounds__(256) void hist_kernel(
    const int* __restrict__ dst, int* __restrict__ deg, int nedges)
{
    int e = blockIdx.x * 256 + threadIdx.x;
    if (e < nedges) atomicAdd(&deg[dst[e]], 1);
}

__global__ __launch_bounds__(256) void scan_block_kernel(
    const int* __restrict__ deg, int* __restrict__ rowptr,
    int* __restrict__ partials, int n)
{
    __shared__ int sm[256];
    int tid = threadIdx.x;
    int i = blockIdx.x * 256 + tid;
    int v = (i < n) ? deg[i] : 0;
    sm[tid] = v;
    __syncthreads();
    for (int ofs = 1; ofs < 256; ofs <<= 1) {
        int t = (tid >= ofs) ? sm[tid - ofs] : 0;
        __syncthreads();
        sm[tid] += t;
        __syncthreads();
    }
    if (i < n) rowptr[i] = sm[tid] - v;
    if (tid == 255) partials[blockIdx.x] = sm[255];
}

__global__ __launch_bounds__(256) void scan_partials_kernel(int* partials, int nb)
{
    __shared__ int sm[256];
    __shared__ int carry;
    int tid = threadIdx.x;
    if (tid == 0) carry = 0;
    __syncthreads();
    for (int base = 0; base < nb; base += 256) {
        int i = base + tid;
        int v = (i < nb) ? partials[i] : 0;
        sm[tid] = v;
        __syncthreads();
        for (int ofs = 1; ofs < 256; ofs <<= 1) {
            int t = (tid >= ofs) ? sm[tid - ofs] : 0;
            __syncthreads();
            sm[tid] += t;
            __syncthreads();
        }
        int cbase = carry;
        int tot = sm[255];
        if (i < nb) partials[i] = sm[tid] - v + cbase;
        __syncthreads();
        if (tid == 0) carry = cbase + tot;
        __syncthreads();
    }
}

__global__ __launch_bounds__(256) void add_offsets_kernel(
    int* __restrict__ rowptr, const int* __restrict__ partials, int n)
{
    int i = blockIdx.x * 256 + threadIdx.x;
    if (i < n) rowptr[i] += partials[blockIdx.x];
}

// XCD-partitioned CSR fill: group x = blockIdx&7 owns dst range [x*nspan, x*nspan+nspan);
// each group grid-strides over ALL edges; csr/deg writes stay XCD-local.
__global__ __launch_bounds__(256) void place_kernel(
    const int* __restrict__ src, const int* __restrict__ dst,
    const int* __restrict__ rowptr, int* __restrict__ deg,
    int* __restrict__ csr, int nedges, int n, int nspan)
{
    int x = blockIdx.x & 7;
    int k = blockIdx.x >> 3;
    int lo = x * nspan;
    int hi = min(lo + nspan, n);
    int gs = (int)(gridDim.x >> 3) * 256;     // stride within group
    for (int e0 = k * 256 + (int)threadIdx.x; e0 < nedges; e0 += 4 * gs) {
        int e[4], d[4];
        bool ok[4];
#pragma unroll
        for (int i = 0; i < 4; ++i) {
            e[i] = e0 + i * gs;
            bool in = e[i] < nedges;
            d[i] = in ? dst[e[i]] : 0;
            ok[i] = in && d[i] >= lo && d[i] < hi;
        }
        int s[4], slot[4];
#pragma unroll
        for (int i = 0; i < 4; ++i)
            s[i] = ok[i] ? src[e[i]] : 0;
#pragma unroll
        for (int i = 0; i < 4; ++i)
            slot[i] = ok[i] ? atomicAdd(&deg[d[i]], 1) : 0;
#pragma unroll
        for (int i = 0; i < 4; ++i)
            if (ok[i]) csr[rowptr[d[i]] + slot[i]] = s[i];
    }
}

// ---------- degree bucketing (counting sort, 64 bins) ----------
__global__ __launch_bounds__(256) void deg_hist_kernel(
    const int* __restrict__ deg, int* __restrict__ dhist, int n)
{
    __shared__ int lh[64];
    int tid = threadIdx.x;
    if (tid < 64) lh[tid] = 0;
    __syncthreads();
    int i = blockIdx.x * 256 + tid;
    if (i < n) atomicAdd(&lh[min(deg[i], 63)], 1);
    __syncthreads();
    if (tid < 64 && lh[tid]) atomicAdd(&dhist[tid], lh[tid]);
}

__global__ __launch_bounds__(64) void bucket_scan_kernel(
    const int* __restrict__ dhist, int* __restrict__ dcnt)
{
    __shared__ int sm[64];
    int t = threadIdx.x;
    sm[t] = dhist[t];
    __syncthreads();
    int acc = 0;
    for (int k = 0; k < t; ++k) acc += sm[k];
    dcnt[t] = acc;          // dcnt starts as the bucket base cursor
}

__global__ __launch_bounds__(256) void perm_place_kernel(
    const int* __restrict__ deg, int* __restrict__ dcnt,
    int* __restrict__ perm, int n)
{
    __shared__ int lh[64], lbase[64];
    int tid = threadIdx.x;
    if (tid < 64) lh[tid] = 0;
    __syncthreads();
    int i = blockIdx.x * 256 + tid;
    int b = 0;
    if (i < n) { b = min(deg[i], 63); atomicAdd(&lh[b], 1); }
    __syncthreads();
    if (tid < 64) {
        int cntb = lh[tid];
        if (cntb) lbase[tid] = atomicAdd(&dcnt[tid], cntb);
        lh[tid] = 0;
    }
    __syncthreads();
    if (i < n) {
        int r = atomicAdd(&lh[b], 1);
        perm[lbase[b] + r] = i;
    }
}

// ---------- fused MFMA layer, fp8 h, single-wave blocks ----------
// One wave (64 threads) per 16-row tile: no inter-wave barrier convoy, scheduler
// handles degree imbalance. idx table padded to 33 ints/row -> bank-conflict-free.
template <int FINAL>
__global__ __launch_bounds__(64) void layer_kernel(
    const unsigned char* __restrict__ h, const int* __restrict__ rowptr,
    const int* __restrict__ deg, const int* __restrict__ csr,
    const int* __restrict__ perm,
    const short8* __restrict__ wfG1, const short8* __restrict__ wfG2,
    const float* __restrict__ b1, const float* __restrict__ g1, const float* __restrict__ bt1,
    const float* __restrict__ b2, const float* __restrict__ g2, const float* __restrict__ bt2,
    unsigned char* __restrict__ out, int nrows,
    const short8* __restrict__ wfL1, const float* __restrict__ bl1,
    const int* __restrict__ batch, float* __restrict__ pooled, float* __restrict__ cnt)
{
    __shared__ int idx_s[16][MAXD + 1];            // +1 pad: bank = (row+j)%32
    __shared__ int self_tab[16];
    __shared__ __align__(16) char zt[2048];        // z tile bf16 [16][64]
    int lane = threadIdx.x;
    int r0 = blockIdx.x * 16;

    // ---- row metadata (scalar) + neighbor table fill ----
    int s16[16], c16[16], maxc = 0;
#pragma unroll
    for (int r = 0; r < 16; ++r) {
        int gi = r0 + r;
        int pr = nrows;                       // zero row for OOB
        int sv = 0, cv = 0;
        if (gi < nrows) {
            pr = perm ? perm[gi] : gi;
            sv = rowptr[pr]; cv = deg[pr];
        }
        pr = __builtin_amdgcn_readfirstlane(pr);
        s16[r] = __builtin_amdgcn_readfirstlane(sv);
        c16[r] = __builtin_amdgcn_readfirstlane(cv);
        maxc = max(maxc, c16[r]);
        int idxv = nrows;
        if (lane < c16[r]) idxv = csr[s16[r] + lane];
        idxv = min(max(idxv, 0), nrows) << 6;            // byte offset, clamped
        if (lane < MAXD) idx_s[r][lane] = idxv;
        if (lane == 0) self_tab[r] = pr << 6;            // self
    }
    __syncthreads();   // single wave: trivial

    int selrow = lane >> 3;          // row within 8-row group served by this lane
    int fq4 = (lane & 7) * 8;        // fp8 byte offset of this lane's 8-feature span
    int fq8 = fq4 * 2;               // bf16 byte offset (16B per lane)

    // ---- self init ----
    float zg[2][8];
#pragma unroll
    for (int g = 0; g < 2; ++g) {
        int bo = self_tab[g * 8 + selrow];
        uint2 w = *(const uint2*)(h + bo + fq4);
        f32x2 p0 = fp8_dec2<false>(w.x), p1 = fp8_dec2<true>(w.x);
        f32x2 p2 = fp8_dec2<false>(w.y), p3 = fp8_dec2<true>(w.y);
        zg[g][0] = p0.x; zg[g][1] = p0.y; zg[g][2] = p1.x; zg[g][3] = p1.y;
        zg[g][4] = p2.x; zg[g][5] = p2.y; zg[g][6] = p3.x; zg[g][7] = p3.y;
    }

    // ---- gather main loop: dummy slots read the zero row (cached) ----
    int jm = min(maxc, MAXD);
    for (int j0 = 0; j0 < jm; j0 += 8) {
        uint2 w[8][2];
#pragma unroll
        for (int jj = 0; jj < 8; ++jj) {
            int jcl = min(j0 + jj, MAXD - 1);
#pragma unroll
            for (int g = 0; g < 2; ++g) {
                int bo = idx_s[g * 8 + selrow][jcl];
                w[jj][g] = *(const uint2*)(h + bo + fq4);
            }
        }
#pragma unroll
        for (int jj = 0; jj < 8; ++jj)
#pragma unroll
            for (int g = 0; g < 2; ++g) {
                f32x2 p0 = fp8_dec2<false>(w[jj][g].x), p1 = fp8_dec2<true>(w[jj][g].x);
                f32x2 p2 = fp8_dec2<false>(w[jj][g].y), p3 = fp8_dec2<true>(w[jj][g].y);
                zg[g][0] += p0.x; zg[g][1] += p0.y; zg[g][2] += p1.x; zg[g][3] += p1.y;
                zg[g][4] += p2.x; zg[g][5] += p2.y; zg[g][6] += p3.x; zg[g][7] += p3.y;
            }
    }
    if (maxc > MAXD) {    // rare tail, scalar per row
#pragma unroll
        for (int g = 0; g < 2; ++g) {
#pragma unroll
            for (int q = 0; q < 8; ++q) {
                int r = g * 8 + q;
                for (int j = MAXD; j < c16[r]; ++j) {
                    int sn = csr[s16[r] + j];
                    sn = min(max(sn, 0), nrows - 1);
                    uint2 w = *(const uint2*)(h + ((size_t)sn << 6) + fq4);
                    f32x2 p0 = fp8_dec2<false>(w.x), p1 = fp8_dec2<true>(w.x);
                    f32x2 p2 = fp8_dec2<false>(w.y), p3 = fp8_dec2<true>(w.y);
                    bool mine = (selrow == q);
                    zg[g][0] += mine ? p0.x : 0.f;
                    zg[g][1] += mine ? p0.y : 0.f;
                    zg[g][2] += mine ? p1.x : 0.f;
                    zg[g][3] += mine ? p1.y : 0.f;
                    zg[g][4] += mine ? p2.x : 0.f;
                    zg[g][5] += mine ? p2.y : 0.f;
                    zg[g][6] += mine ? p3.x : 0.f;
                    zg[g][7] += mine ? p3.y : 0.f;
                }
            }
        }
    }

    // ---- z -> LDS bf16 [16][64], XOR-swizzled (16B stores) ----
#pragma unroll
    for (int g = 0; g < 2; ++g) {
        int row = g * 8 + selrow;
        short8 pk;
#pragma unroll
        for (int k = 0; k < 8; ++k) pk[k] = (short)f2bf(zg[g][k]);
        int off = (row * 128 + fq8) ^ ((row & 7) << 4);
        *(short8*)(zt + off) = pk;
    }
    __syncthreads();

    short8 a0, a1;
    f32x4 acc[4];
    // ---- GEMM1 + BN + ReLU ----
    {
        int rr = lane & 15;
        a0 = *(const short8*)(zt + rr * 128 + (((lane >> 4) * 16) ^ ((rr & 7) << 4)));
        a1 = *(const short8*)(zt + rr * 128 + ((64 + (lane >> 4) * 16) ^ ((rr & 7) << 4)));
    }
#pragma unroll
    for (int tile = 0; tile < 4; ++tile) {
        acc[tile] = (f32x4){0.f, 0.f, 0.f, 0.f};
        acc[tile] = __builtin_amdgcn_mfma_f32_16x16x32_bf16(a0, wfG1[(tile * 2 + 0) * 64 + lane], acc[tile], 0, 0, 0);
        acc[tile] = __builtin_amdgcn_mfma_f32_16x16x32_bf16(a1, wfG1[(tile * 2 + 1) * 64 + lane], acc[tile], 0, 0, 0);
    }
    __syncthreads();
#pragma unroll
    for (int tile = 0; tile < 4; ++tile) {
        int col = tile * 16 + (lane & 15);
        float sc = g1[col] * BN_RSQRT;
        float sh = fmaf(b1[col], sc, bt1[col]);
#pragma unroll
        for (int q = 0; q < 4; ++q) {
            int row = (lane >> 4) * 4 + q;
            float v = fmaxf(fmaf(acc[tile][q], sc, sh), 0.0f);
            *(short*)(zt + row * 128 + ((col * 2) ^ ((row & 7) << 4))) = (short)f2bf(v);
        }
    }
    __syncthreads();

    // ---- GEMM2 + BN + ReLU ----
    {
        int rr = lane & 15;
        a0 = *(const short8*)(zt + rr * 128 + (((lane >> 4) * 16) ^ ((rr & 7) << 4)));
        a1 = *(const short8*)(zt + rr * 128 + ((64 + (lane >> 4) * 16) ^ ((rr & 7) << 4)));
    }
#pragma unroll
    for (int tile = 0; tile < 4; ++tile) {
        acc[tile] = (f32x4){0.f, 0.f, 0.f, 0.f};
        acc[tile] = __builtin_amdgcn_mfma_f32_16x16x32_bf16(a0, wfG2[(tile * 2 + 0) * 64 + lane], acc[tile], 0, 0, 0);
        acc[tile] = __builtin_amdgcn_mfma_f32_16x16x32_bf16(a1, wfG2[(tile * 2 + 1) * 64 + lane], acc[tile], 0, 0, 0);
    }
    __syncthreads();
#pragma unroll
    for (int tile = 0; tile < 4; ++tile) {
        int col = tile * 16 + (lane & 15);
        float sc = g2[col] * BN_RSQRT;
        float sh = fmaf(b2[col], sc, bt2[col]);
#pragma unroll
        for (int q = 0; q < 4; ++q) {
            int row = (lane >> 4) * 4 + q;
            float v = fmaxf(fmaf(acc[tile][q], sc, sh), 0.0f);
            *(short*)(zt + row * 128 + ((col * 2) ^ ((row & 7) << 4))) = (short)f2bf(v);
        }
    }
    __syncthreads();

    if (FINAL == 0) {
        // fp8-pack + store (row offset from self_tab; zero row excluded by guard)
#pragma unroll
        for (int half = 0; half < 2; ++half) {
            int row = (lane >> 3) + half * 8;
            short8 vv = *(const short8*)(zt + row * 128 + ((((lane & 7) * 16)) ^ ((row & 7) << 4)));
            int ro = self_tab[row];
            if (ro < (nrows << 6)) {
                unsigned w0 = fp8_enc4(us2f((unsigned short)vv[0]), us2f((unsigned short)vv[1]),
                                       us2f((unsigned short)vv[2]), us2f((unsigned short)vv[3]));
                unsigned w1 = fp8_enc4(us2f((unsigned short)vv[4]), us2f((unsigned short)vv[5]),
                                       us2f((unsigned short)vv[6]), us2f((unsigned short)vv[7]));
                *(uint2*)(out + ro + (lane & 7) * 8) = make_uint2(w0, w1);
            }
        }
    } else {
        // ---- GEMM3: relu(h4 @ Wl1 + bl1) ----
        {
            int rr = lane & 15;
            a0 = *(const short8*)(zt + rr * 128 + (((lane >> 4) * 16) ^ ((rr & 7) << 4)));
            a1 = *(const short8*)(zt + rr * 128 + ((64 + (lane >> 4) * 16) ^ ((rr & 7) << 4)));
        }
#pragma unroll
        for (int tile = 0; tile < 4; ++tile) {
            acc[tile] = (f32x4){0.f, 0.f, 0.f, 0.f};
            acc[tile] = __builtin_amdgcn_mfma_f32_16x16x32_bf16(a0, wfL1[(tile * 2 + 0) * 64 + lane], acc[tile], 0, 0, 0);
            acc[tile] = __builtin_amdgcn_mfma_f32_16x16x32_bf16(a1, wfL1[(tile * 2 + 1) * 64 + lane], acc[tile], 0, 0, 0);
        }
        __syncthreads();
#pragma unroll
        for (int tile = 0; tile < 4; ++tile) {
            int col = tile * 16 + (lane & 15);
            float bia = bl1[col];
#pragma unroll
            for (int q = 0; q < 4; ++q) {
                int row = (lane >> 4) * 4 + q;
                float v = fmaxf(acc[tile][q] + bia, 0.0f);
                *(short*)(zt + row * 128 + ((col * 2) ^ ((row & 7) << 4))) = (short)f2bf(v);
            }
        }
        __syncthreads();
        // ---- in-kernel mean-pool partials (natural order, batch sorted) ----
        float pacc = 0.0f;
        int curg = -1, rc = 0;
        for (int r = 0; r < 16; ++r) {
            int row = r0 + r;
            if (row >= nrows) break;
            float v = us2f(*(const unsigned short*)(zt + r * 128 + ((lane * 2) ^ ((r & 7) << 4))));
            int g = batch[row];
            if (g != curg) {
                if (curg >= 0) {
                    atomicAdd(&pooled[curg * HH + lane], pacc);
                    if (lane == 0) atomicAdd(&cnt[curg], (float)rc);
                }
                curg = g; pacc = v; rc = 1;
            } else { pacc += v; rc += 1; }
        }
        if (curg >= 0) {
            atomicAdd(&pooled[curg * HH + lane], pacc);
            if (lane == 0) atomicAdd(&cnt[curg], (float)rc);
        }
    }
}

__global__ __launch_bounds__(64) void head_kernel(
    const float* __restrict__ pooled, const float* __restrict__ cnt,
    const float* __restrict__ Wl2, const float* __restrict__ bl2,
    float* __restrict__ out, int ngraphs)
{
    int gidx = blockIdx.x * 64 + threadIdx.x;
    if (gidx >= ngraphs) return;
    float logits[CC];
#pragma unroll
    for (int c = 0; c < CC; ++c) logits[c] = bl2[c];
    float inv_n = 1.0f / fmaxf(cnt[gidx], 1.0f);
    for (int k = 0; k < HH; ++k) {
        float p = pooled[gidx * HH + k] * inv_n;
#pragma unroll
        for (int c = 0; c < CC; ++c) logits[c] = fmaf(p, Wl2[k * CC + c], logits[c]);
    }
    float m = logits[0];
#pragma unroll
    for (int c = 1; c < CC; ++c) m = fmaxf(m, logits[c]);
    float ssum = 0.0f;
#pragma unroll
    for (int c = 0; c < CC; ++c) { logits[c] = __expf(logits[c] - m); ssum += logits[c]; }
    float inv = 1.0f / ssum;
#pragma unroll
    for (int c = 0; c < CC; ++c) out[gidx * CC + c] = logits[c] * inv;
}

extern "C" void kernel_launch(void* const* d_in, const int* in_sizes, int n_in,
                              void* d_out, int out_size, void* d_ws, size_t ws_size,
                              hipStream_t stream) {
    const float* x      = (const float*)d_in[0];
    const int*   ei     = (const int*)  d_in[1];
    const int*   batch  = (const int*)  d_in[3];
    const float* W0     = (const float*)d_in[4];
    const float* b0     = (const float*)d_in[5];
    const float* convW1 = (const float*)d_in[6];
    const float* convb1 = (const float*)d_in[7];
    const float* convg1 = (const float*)d_in[8];
    const float* convbt1= (const float*)d_in[9];
    const float* convW2 = (const float*)d_in[10];
    const float* convb2 = (const float*)d_in[11];
    const float* convg2 = (const float*)d_in[12];
    const float* convbt2= (const float*)d_in[13];
    const float* Wl1    = (const float*)d_in[14];
    const float* bl1    = (const float*)d_in[15];
    const float* Wl2    = (const float*)d_in[16];
    const float* bl2    = (const float*)d_in[17];

    const int N = in_sizes[0] / FF;
    const int E = in_sizes[1] / 2;
    const int G = out_size / CC;

    const int* src = ei;
    const int* dst = ei + E;

    size_t off = 0;
    auto take = [&](size_t bytes) { size_t p = off; off = (off + bytes + 255) & ~255ULL; return p; };
    int NB = (N + 255) / 256;
    int EB = (E + 255) / 256;
    size_t o_rowptr = take((size_t)N * 4);
    size_t o_deg    = take((size_t)N * 4);
    size_t o_csr    = take((size_t)(E > NB ? E : NB) * 4 + 512);
    size_t o_perm   = take((size_t)N * 4);
    size_t o_dhist  = take(64 * 4);
    size_t o_dcnt   = take(64 * 4);
    size_t o_pooled = take((size_t)G * HH * 4);
    size_t o_cnt    = take((size_t)G * 4);
    size_t o_wfrag  = take((size_t)5632 * 8 * 2);
    size_t o_hA     = take((size_t)(N + 1) * 64);
    size_t o_hB     = take((size_t)(N + 1) * 64);

    char* base = (char*)d_ws;
    int*    rowptr = (int*)(base + o_rowptr);
    int*    deg    = (int*)(base + o_deg);
    int*    csr    = (int*)(base + o_csr);
    int*    perm   = (int*)(base + o_perm);
    int*    dhist  = (int*)(base + o_dhist);
    int*    dcnt   = (int*)(base + o_dcnt);
    float*  pooled = (float*)(base + o_pooled);
    float*  cnt    = (float*)(base + o_cnt);
    short*  wfrag  = (short*)(base + o_wfrag);
    short8* wf8    = (short8*)wfrag;
    unsigned char* hA = (unsigned char*)(base + o_hA);
    unsigned char* hB = (unsigned char*)(base + o_hB);

    int lin0_blocks = (N + 63) / 64;     // 4 waves x 16 rows
    int layer_blocks = (N + 15) / 16;    // 1 wave x 16 rows

    // weight fragment packing
    pack_weights_kernel<<<22, 256, 0, stream>>>(W0, convW1, convW2, Wl1, wfrag);

    // CSR build
    (void)hipMemsetAsync(deg, 0, (size_t)N * sizeof(int), stream);
    hist_kernel<<<EB, 256, 0, stream>>>(dst, deg, E);
    scan_block_kernel<<<NB, 256, 0, stream>>>(deg, rowptr, csr /*partials*/, N);
    scan_partials_kernel<<<1, 256, 0, stream>>>(csr, NB);
    add_offsets_kernel<<<NB, 256, 0, stream>>>(rowptr, csr, N);
    (void)hipMemsetAsync(deg, 0, (size_t)N * sizeof(int), stream);
    {
        int nspan = (N + 7) / 8;
        place_kernel<<<640, 256, 0, stream>>>(src, dst, rowptr, deg, csr, E, N, nspan);
    }

    // degree bucketing (uses restored deg)
    (void)hipMemsetAsync(dhist, 0, 64 * sizeof(int), stream);
    deg_hist_kernel<<<NB, 256, 0, stream>>>(deg, dhist, N);
    bucket_scan_kernel<<<1, 64, 0, stream>>>(dhist, dcnt);
    perm_place_kernel<<<NB, 256, 0, stream>>>(deg, dcnt, perm, N);

    // zero rows (index N) of both h buffers
    (void)hipMemsetAsync(hA + (size_t)N * 64, 0, 64, stream);
    (void)hipMemsetAsync(hB + (size_t)N * 64, 0, 64, stream);

    // lin0
    lin0_kernel<<<lin0_blocks, 256, 0, stream>>>(x, wf8, b0, hA, N);

    // pooled/cnt init
    (void)hipMemsetAsync(pooled, 0, (size_t)G * HH * sizeof(float), stream);
    (void)hipMemsetAsync(cnt, 0, (size_t)G * sizeof(float), stream);

    // layers (ping-pong); 0..2 degree-bucketed, last natural + fused pool
    const unsigned char* hin = hA; unsigned char* hout = hB;
    const short8* wfL1 = wf8 + 5120;
    for (int l = 0; l < LL; ++l) {
        const short8* wfG1 = wf8 + 1024 + (size_t)(l * 2 + 0) * 512;
        const short8* wfG2 = wf8 + 1024 + (size_t)(l * 2 + 1) * 512;
        if (l < LL - 1) {
            layer_kernel<0><<<layer_blocks, 64, 0, stream>>>(
                hin, rowptr, deg, csr, perm, wfG1, wfG2,
                convb1 + l * HH, convg1 + l * HH, convbt1 + l * HH,
                convb2 + l * HH, convg2 + l * HH, convbt2 + l * HH,
                hout, N, nullptr, nullptr, nullptr, nullptr, nullptr);
        } else {
            layer_kernel<1><<<layer_blocks, 64, 0, stream>>>(
                hin, rowptr, deg, csr, nullptr, wfG1, wfG2,
                convb1 + l * HH, convg1 + l * HH, convbt1 + l * HH,
                convb2 + l * HH, convg2 + l * HH, convbt2 + l * HH,
                nullptr, N, wfL1, bl1, batch, pooled, cnt);
        }
        unsigned char* tswap = (unsigned char*)hin; hin = hout; hout = tswap;
    }

    head_kernel<<<(G + 63) / 64, 64, 0, stream>>>(pooled, cnt, Wl2, bl2, (float*)d_out, G);
}

// Round 15
// 289.544 us; speedup vs baseline: 1.8661x; 1.0686x over previous
//
#include <hip/hip_runtime.h>
#include <hip/hip_bf16.h>

#define HH 64
#define FF 128
#define CC 10
#define LL 4
#define MAXD 32        // LDS neighbor-table depth (tail loop handles deg>32)
#define BN_RSQRT 0.9999950000374997f   // 1/sqrt(1+1e-5)

typedef __hip_bfloat16 bf16;
using short8 = __attribute__((ext_vector_type(8))) short;
using f32x4  = __attribute__((ext_vector_type(4))) float;
using f32x2  = __attribute__((ext_vector_type(2))) float;

__device__ __forceinline__ float us2f(unsigned short u) {
    return __uint_as_float(((unsigned)u) << 16);
}
// RNE f32->bf16 bits (finite inputs)
__device__ __forceinline__ unsigned short f2bf(float v) {
    unsigned u = __float_as_uint(v);
    return (unsigned short)((u + 0x7FFFu + ((u >> 16) & 1u)) >> 16);
}

// ---------- fp8 pack/unpack (HW cvt on gfx950; software fallback) ----------
#if defined(__has_builtin)
#if __has_builtin(__builtin_amdgcn_cvt_pk_f32_fp8) && __has_builtin(__builtin_amdgcn_cvt_pk_fp8_f32)
#define FP8_HW 1
#endif
#endif

#ifdef FP8_HW
template <bool HIGH>
__device__ __forceinline__ f32x2 fp8_dec2(unsigned w) {
    return __builtin_amdgcn_cvt_pk_f32_fp8((int)w, HIGH);
}
__device__ __forceinline__ unsigned fp8_enc4(float f0, float f1, float f2, float f3) {
    int w = 0;
    w = __builtin_amdgcn_cvt_pk_fp8_f32(f0, f1, w, false);
    w = __builtin_amdgcn_cvt_pk_fp8_f32(f2, f3, w, true);
    return (unsigned)w;
}
#else
__device__ __forceinline__ float fp8_dec1(unsigned b) {
    unsigned s = (b & 0x80u) << 24;
    unsigned em = b & 0x7Fu;
    float mag;
    if (em >= 0x08u) mag = __uint_as_float((((em >> 3) + 120u) << 23) | ((em & 7u) << 20));
    else             mag = (float)em * (1.0f / 512.0f);
    return __uint_as_float(__float_as_uint(mag) | s);
}
template <bool HIGH>
__device__ __forceinline__ f32x2 fp8_dec2(unsigned w) {
    unsigned lo = HIGH ? ((w >> 16) & 0xffu) : (w & 0xffu);
    unsigned hi = HIGH ? ((w >> 24) & 0xffu) : ((w >> 8) & 0xffu);
    f32x2 r; r.x = fp8_dec1(lo); r.y = fp8_dec1(hi); return r;
}
__device__ __forceinline__ unsigned fp8_enc1(float v) {
    unsigned u = __float_as_uint(v);
    unsigned s = (u >> 24) & 0x80u;
    float a = fabsf(v);
    if (a >= 448.0f) return s | 0x7Eu;
    if (a < 0.015625f) {
        int m = (int)rintf(a * 512.0f);
        return s | (unsigned)m;
    }
    int e; float m = frexpf(a, &e);
    int E = e + 6;
    int mant = (int)rintf((m * 2.0f - 1.0f) * 8.0f);
    if (mant == 8) { mant = 0; ++E; }
    if (E > 15) return s | 0x7Eu;
    return s | (unsigned)(E << 3) | (unsigned)mant;
}
__device__ __forceinline__ unsigned fp8_enc4(float f0, float f1, float f2, float f3) {
    return fp8_enc1(f0) | (fp8_enc1(f1) << 8) | (fp8_enc1(f2) << 16) | (fp8_enc1(f3) << 24);
}
#endif

// ---------- weight fragment packing ----------
__global__ __launch_bounds__(256) void pack_weights_kernel(
    const float* __restrict__ W0, const float* __restrict__ convW1,
    const float* __restrict__ convW2, const float* __restrict__ Wl1,
    short* __restrict__ wf)
{
    int t = blockIdx.x * 256 + threadIdx.x;
    if (t >= 5632) return;
    const float* W;
    int l, tile, kc, out_idx;
    if (t < 1024) {
        int local = t; int fi = local >> 6; l = local & 63;
        tile = fi >> 2; kc = fi & 3;
        W = W0; out_idx = local;
    } else if (t < 5120) {
        int t2 = t - 1024;
        int m = t2 >> 9;
        int local = t2 & 511;
        int fi = local >> 6; l = local & 63;
        tile = fi >> 1; kc = fi & 1;
        int layer = m >> 1, g = m & 1;
        W = (g ? convW2 : convW1) + (size_t)layer * HH * HH;
        out_idx = 1024 + m * 512 + local;
    } else {
        int local = t - 5120;
        int fi = local >> 6; l = local & 63;
        tile = fi >> 1; kc = fi & 1;
        W = Wl1; out_idx = 5120 + local;
    }
    int k0 = kc * 32 + (l >> 4) * 8;
    int n = tile * 16 + (l & 15);
#pragma unroll
    for (int e = 0; e < 8; ++e)
        wf[out_idx * 8 + e] = (short)f2bf(W[(k0 + e) * HH + n]);
}

// ---------- lin0 (MFMA): h = relu(x @ W0 + b0), out fp8 ----------
__global__ __launch_bounds__(256) void lin0_kernel(
    const float* __restrict__ x, const short8* __restrict__ wf0,
    const float* __restrict__ b0, unsigned char* __restrict__ h, int nrows)
{
    __shared__ __align__(16) short lds_all[4][2048];   // per wave [16][128] bf16
    int wave = __builtin_amdgcn_readfirstlane(threadIdx.x >> 6);
    int lane = threadIdx.x & 63;
    char* ldsb = (char*)&lds_all[wave][0];
    int r0 = (blockIdx.x * 4 + wave) * 16;

#pragma unroll
    for (int r = 0; r < 16; ++r) {
        int row = r0 + r;
        float2 xv = make_float2(0.f, 0.f);
        if (row < nrows) xv = *(const float2*)(x + (size_t)row * FF + lane * 2);
        unsigned pk = (unsigned)f2bf(xv.x) | ((unsigned)f2bf(xv.y) << 16);
        *(int*)(ldsb + r * 256 + ((lane * 4) ^ ((r & 7) << 4))) = pk;
    }
    __syncthreads();

    short8 a[4];
#pragma unroll
    for (int kc = 0; kc < 4; ++kc) {
        int rr = lane & 15;
        a[kc] = *(const short8*)(ldsb + rr * 256 + (((kc * 64 + (lane >> 4) * 16)) ^ ((rr & 7) << 4)));
    }
    f32x4 acc[4];
#pragma unroll
    for (int tile = 0; tile < 4; ++tile) {
        acc[tile] = (f32x4){0.f, 0.f, 0.f, 0.f};
#pragma unroll
        for (int kc = 0; kc < 4; ++kc) {
            short8 b = wf0[(tile * 4 + kc) * 64 + lane];
            acc[tile] = __builtin_amdgcn_mfma_f32_16x16x32_bf16(a[kc], b, acc[tile], 0, 0, 0);
        }
    }
    __syncthreads();
#pragma unroll
    for (int tile = 0; tile < 4; ++tile) {
        int col = tile * 16 + (lane & 15);
        float bia = b0[col];
#pragma unroll
        for (int q = 0; q < 4; ++q) {
            int row = (lane >> 4) * 4 + q;
            float v = fmaxf(acc[tile][q] + bia, 0.0f);
            *(short*)(ldsb + row * 256 + ((col * 2) ^ ((row & 7) << 4))) = (short)f2bf(v);
        }
    }
    __syncthreads();
#pragma unroll
    for (int half = 0; half < 2; ++half) {
        int row = (lane >> 3) + half * 8;
        short8 vv = *(const short8*)(ldsb + row * 256 + ((((lane & 7) * 16)) ^ ((row & 7) << 4)));
        int grow = r0 + row;
        if (grow < nrows) {
            unsigned w0 = fp8_enc4(us2f((unsigned short)vv[0]), us2f((unsigned short)vv[1]),
                                   us2f((unsigned short)vv[2]), us2f((unsigned short)vv[3]));
            unsigned w1 = fp8_enc4(us2f((unsigned short)vv[4]), us2f((unsigned short)vv[5]),
                                   us2f((unsigned short)vv[6]), us2f((unsigned short)vv[7]));
            *(uint2*)(h + (size_t)grow * 64 + (lane & 7) * 8) = make_uint2(w0, w1);
        }
    }
}

// ---------- CSR build ----------
__global__ __launch_bounds__(256) void hist_kernel(
    const int* __restrict__ dst, int* __restrict__ deg, int nedges)
{
    int e = blockIdx.x * 256 + threadIdx.x;
    if (e < nedges) atomicAdd(&deg[dst[e]], 1);
}

__global__ __launch_bounds__(256) void scan_block_kernel(
    const int* __restrict__ deg, int* __restrict__ rowptr,
    int* __restrict__ partials, int n)
{
    __shared__ int sm[256];
    int tid = threadIdx.x;
    int i = blockIdx.x * 256 + tid;
    int v = (i < n) ? deg[i] : 0;
    sm[tid] = v;
    __syncthreads();
    for (int ofs = 1; ofs < 256; ofs <<= 1) {
        int t = (tid >= ofs) ? sm[tid - ofs] : 0;
        __syncthreads();
        sm[tid] += t;
        __syncthreads();
    }
    if (i < n) rowptr[i] = sm[tid] - v;
    if (tid == 255) partials[blockIdx.x] = sm[255];
}

__global__ __launch_bounds__(256) void scan_partials_kernel(int* partials, int nb)
{
    __shared__ int sm[256];
    __shared__ int carry;
    int tid = threadIdx.x;
    if (tid == 0) carry = 0;
    __syncthreads();
    for (int base = 0; base < nb; base += 256) {
        int i = base + tid;
        int v = (i < nb) ? partials[i] : 0;
        sm[tid] = v;
        __syncthreads();
        for (int ofs = 1; ofs < 256; ofs <<= 1) {
            int t = (tid >= ofs) ? sm[tid - ofs] : 0;
            __syncthreads();
            sm[tid] += t;
            __syncthreads();
        }
        int cbase = carry;
        int tot = sm[255];
        if (i < nb) partials[i] = sm[tid] - v + cbase;
        __syncthreads();
        if (tid == 0) carry = cbase + tot;
        __syncthreads();
    }
}

__global__ __launch_bounds__(256) void add_offsets_kernel(
    int* __restrict__ rowptr, const int* __restrict__ partials, int n)
{
    int i = blockIdx.x * 256 + threadIdx.x;
    if (i < n) rowptr[i] += partials[blockIdx.x];
}

// XCD-partitioned CSR fill
__global__ __launch_bounds__(256) void place_kernel(
    const int* __restrict__ src, const int* __restrict__ dst,
    const int* __restrict__ rowptr, int* __restrict__ deg,
    int* __restrict__ csr, int nedges, int n, int nspan)
{
    int x = blockIdx.x & 7;
    int k = blockIdx.x >> 3;
    int lo = x * nspan;
    int hi = min(lo + nspan, n);
    int gs = (int)(gridDim.x >> 3) * 256;     // stride within group
    for (int e0 = k * 256 + (int)threadIdx.x; e0 < nedges; e0 += 4 * gs) {
        int e[4], d[4];
        bool ok[4];
#pragma unroll
        for (int i = 0; i < 4; ++i) {
            e[i] = e0 + i * gs;
            bool in = e[i] < nedges;
            d[i] = in ? dst[e[i]] : 0;
            ok[i] = in && d[i] >= lo && d[i] < hi;
        }
        int s[4], slot[4];
#pragma unroll
        for (int i = 0; i < 4; ++i)
            s[i] = ok[i] ? src[e[i]] : 0;
#pragma unroll
        for (int i = 0; i < 4; ++i)
            slot[i] = ok[i] ? atomicAdd(&deg[d[i]], 1) : 0;
#pragma unroll
        for (int i = 0; i < 4; ++i)
            if (ok[i]) csr[rowptr[d[i]] + slot[i]] = s[i];
    }
}

// ---------- degree bucketing (counting sort, 64 bins) ----------
__global__ __launch_bounds__(256) void deg_hist_kernel(
    const int* __restrict__ deg, int* __restrict__ dhist, int n)
{
    __shared__ int lh[64];
    int tid = threadIdx.x;
    if (tid < 64) lh[tid] = 0;
    __syncthreads();
    int i = blockIdx.x * 256 + tid;
    if (i < n) atomicAdd(&lh[min(deg[i], 63)], 1);
    __syncthreads();
    if (tid < 64 && lh[tid]) atomicAdd(&dhist[tid], lh[tid]);
}

__global__ __launch_bounds__(64) void bucket_scan_kernel(
    const int* __restrict__ dhist, int* __restrict__ dcnt)
{
    __shared__ int sm[64];
    int t = threadIdx.x;
    sm[t] = dhist[t];
    __syncthreads();
    int acc = 0;
    for (int k = 0; k < t; ++k) acc += sm[k];
    dcnt[t] = acc;
}

__global__ __launch_bounds__(256) void perm_place_kernel(
    const int* __restrict__ deg, int* __restrict__ dcnt,
    int* __restrict__ perm, int n)
{
    __shared__ int lh[64], lbase[64];
    int tid = threadIdx.x;
    if (tid < 64) lh[tid] = 0;
    __syncthreads();
    int i = blockIdx.x * 256 + tid;
    int b = 0;
    if (i < n) { b = min(deg[i], 63); atomicAdd(&lh[b], 1); }
    __syncthreads();
    if (tid < 64) {
        int cntb = lh[tid];
        if (cntb) lbase[tid] = atomicAdd(&dcnt[tid], cntb);
        lh[tid] = 0;
    }
    __syncthreads();
    if (i < n) {
        int r = atomicAdd(&lh[b], 1);
        perm[lbase[b] + r] = i;
    }
}

// ---------- fused MFMA layer, fp8 h, single-wave blocks, pipelined gather ----------
template <int FINAL>
__global__ __launch_bounds__(64, 4) void layer_kernel(
    const unsigned char* __restrict__ h, const int* __restrict__ rowptr,
    const int* __restrict__ deg, const int* __restrict__ csr,
    const int* __restrict__ perm,
    const short8* __restrict__ wfG1, const short8* __restrict__ wfG2,
    const float* __restrict__ b1, const float* __restrict__ g1, const float* __restrict__ bt1,
    const float* __restrict__ b2, const float* __restrict__ g2, const float* __restrict__ bt2,
    unsigned char* __restrict__ out, int nrows,
    const short8* __restrict__ wfL1, const float* __restrict__ bl1,
    const int* __restrict__ batch, float* __restrict__ pooled, float* __restrict__ cnt)
{
    __shared__ int idx_s[16][MAXD + 1];            // +1 pad: bank-conflict-free
    __shared__ int self_tab[16];
    __shared__ __align__(16) char zt[2048];        // z tile bf16 [16][64]
    int lane = threadIdx.x;
    int r0 = blockIdx.x * 16;

    // ---- metadata, lane-parallel: 3 dependent vector loads instead of 16 chains ----
    int prv = 0, svv = 0, cvv = 0, prs = nrows;
    if (lane < 16) {
        int gi = r0 + lane;
        bool valid = gi < nrows;
        int pr = valid ? (perm ? perm[gi] : gi) : 0;
        prv = min(pr, nrows - 1);
        svv = rowptr[prv];
        cvv = valid ? deg[prv] : 0;
        prs = valid ? prv : nrows;
    }
    int s16[16], c16[16], maxc = 0;
#pragma unroll
    for (int r = 0; r < 16; ++r) {
        s16[r] = __builtin_amdgcn_readlane(svv, r);
        c16[r] = __builtin_amdgcn_readlane(cvv, r);
        maxc = max(maxc, c16[r]);
        if (lane == 0) self_tab[r] = __builtin_amdgcn_readlane(prs, r) << 6;
    }
    // neighbor table: 16 independent vector loads
#pragma unroll
    for (int r = 0; r < 16; ++r) {
        int idxv = nrows;
        if (lane < c16[r]) idxv = csr[s16[r] + lane];
        idxv = min(max(idxv, 0), nrows) << 6;
        if (lane < MAXD) idx_s[r][lane] = idxv;
    }
    __syncthreads();   // single wave: trivial

    int selrow = lane >> 3;          // row within 8-row group served by this lane
    int fq4 = (lane & 7) * 8;        // fp8 byte offset of this lane's 8-feature span
    int fq8 = fq4 * 2;               // bf16 byte offset
    const unsigned char* hp = h + fq4;

    // ---- self init ----
    float zg[2][8];
#pragma unroll
    for (int g = 0; g < 2; ++g) {
        int bo = self_tab[g * 8 + selrow];
        uint2 w = *(const uint2*)(hp + bo);
        f32x2 p0 = fp8_dec2<false>(w.x), p1 = fp8_dec2<true>(w.x);
        f32x2 p2 = fp8_dec2<false>(w.y), p3 = fp8_dec2<true>(w.y);
        zg[g][0] = p0.x; zg[g][1] = p0.y; zg[g][2] = p1.x; zg[g][3] = p1.y;
        zg[g][4] = p2.x; zg[g][5] = p2.y; zg[g][6] = p3.x; zg[g][7] = p3.y;
    }

    // ---- software-pipelined gather: prefetch next batch's offsets while loads fly ----
    int bo_cur[8][2], bo_nxt[8][2];
#pragma unroll
    for (int jj = 0; jj < 8; ++jj)
#pragma unroll
        for (int g = 0; g < 2; ++g)
            bo_cur[jj][g] = idx_s[g * 8 + selrow][min(jj, MAXD - 1)];

    int jm = min(maxc, MAXD);
    for (int j0 = 0; j0 < jm; j0 += 8) {
        uint2 w[8][2];
#pragma unroll
        for (int jj = 0; jj < 8; ++jj)
#pragma unroll
            for (int g = 0; g < 2; ++g)
                w[jj][g] = *(const uint2*)(hp + bo_cur[jj][g]);
        // prefetch next batch's offsets (LDS) while global loads are in flight
#pragma unroll
        for (int jj = 0; jj < 8; ++jj)
#pragma unroll
            for (int g = 0; g < 2; ++g)
                bo_nxt[jj][g] = idx_s[g * 8 + selrow][min(j0 + 8 + jj, MAXD - 1)];
#pragma unroll
        for (int jj = 0; jj < 8; ++jj)
#pragma unroll
            for (int g = 0; g < 2; ++g) {
                f32x2 p0 = fp8_dec2<false>(w[jj][g].x), p1 = fp8_dec2<true>(w[jj][g].x);
                f32x2 p2 = fp8_dec2<false>(w[jj][g].y), p3 = fp8_dec2<true>(w[jj][g].y);
                zg[g][0] += p0.x; zg[g][1] += p0.y; zg[g][2] += p1.x; zg[g][3] += p1.y;
                zg[g][4] += p2.x; zg[g][5] += p2.y; zg[g][6] += p3.x; zg[g][7] += p3.y;
            }
#pragma unroll
        for (int jj = 0; jj < 8; ++jj)
#pragma unroll
            for (int g = 0; g < 2; ++g)
                bo_cur[jj][g] = bo_nxt[jj][g];
    }
    if (maxc > MAXD) {    // rare tail, scalar per row
#pragma unroll
        for (int g = 0; g < 2; ++g) {
#pragma unroll
            for (int q = 0; q < 8; ++q) {
                int r = g * 8 + q;
                for (int j = MAXD; j < c16[r]; ++j) {
                    int sn = csr[s16[r] + j];
                    sn = min(max(sn, 0), nrows - 1);
                    uint2 w = *(const uint2*)(hp + ((size_t)sn << 6));
                    f32x2 p0 = fp8_dec2<false>(w.x), p1 = fp8_dec2<true>(w.x);
                    f32x2 p2 = fp8_dec2<false>(w.y), p3 = fp8_dec2<true>(w.y);
                    bool mine = (selrow == q);
                    zg[g][0] += mine ? p0.x : 0.f;
                    zg[g][1] += mine ? p0.y : 0.f;
                    zg[g][2] += mine ? p1.x : 0.f;
                    zg[g][3] += mine ? p1.y : 0.f;
                    zg[g][4] += mine ? p2.x : 0.f;
                    zg[g][5] += mine ? p2.y : 0.f;
                    zg[g][6] += mine ? p3.x : 0.f;
                    zg[g][7] += mine ? p3.y : 0.f;
                }
            }
        }
    }

    // ---- z -> LDS bf16 [16][64], XOR-swizzled (16B stores) ----
#pragma unroll
    for (int g = 0; g < 2; ++g) {
        int row = g * 8 + selrow;
        short8 pk;
#pragma unroll
        for (int k = 0; k < 8; ++k) pk[k] = (short)f2bf(zg[g][k]);
        int off = (row * 128 + fq8) ^ ((row & 7) << 4);
        *(short8*)(zt + off) = pk;
    }
    __syncthreads();

    short8 a0, a1;
    f32x4 acc[4];
    // ---- GEMM1 + BN + ReLU ----
    {
        int rr = lane & 15;
        a0 = *(const short8*)(zt + rr * 128 + (((lane >> 4) * 16) ^ ((rr & 7) << 4)));
        a1 = *(const short8*)(zt + rr * 128 + ((64 + (lane >> 4) * 16) ^ ((rr & 7) << 4)));
    }
#pragma unroll
    for (int tile = 0; tile < 4; ++tile) {
        acc[tile] = (f32x4){0.f, 0.f, 0.f, 0.f};
        acc[tile] = __builtin_amdgcn_mfma_f32_16x16x32_bf16(a0, wfG1[(tile * 2 + 0) * 64 + lane], acc[tile], 0, 0, 0);
        acc[tile] = __builtin_amdgcn_mfma_f32_16x16x32_bf16(a1, wfG1[(tile * 2 + 1) * 64 + lane], acc[tile], 0, 0, 0);
    }
    __syncthreads();
#pragma unroll
    for (int tile = 0; tile < 4; ++tile) {
        int col = tile * 16 + (lane & 15);
        float sc = g1[col] * BN_RSQRT;
        float sh = fmaf(b1[col], sc, bt1[col]);
#pragma unroll
        for (int q = 0; q < 4; ++q) {
            int row = (lane >> 4) * 4 + q;
            float v = fmaxf(fmaf(acc[tile][q], sc, sh), 0.0f);
            *(short*)(zt + row * 128 + ((col * 2) ^ ((row & 7) << 4))) = (short)f2bf(v);
        }
    }
    __syncthreads();

    // ---- GEMM2 + BN + ReLU ----
    {
        int rr = lane & 15;
        a0 = *(const short8*)(zt + rr * 128 + (((lane >> 4) * 16) ^ ((rr & 7) << 4)));
        a1 = *(const short8*)(zt + rr * 128 + ((64 + (lane >> 4) * 16) ^ ((rr & 7) << 4)));
    }
#pragma unroll
    for (int tile = 0; tile < 4; ++tile) {
        acc[tile] = (f32x4){0.f, 0.f, 0.f, 0.f};
        acc[tile] = __builtin_amdgcn_mfma_f32_16x16x32_bf16(a0, wfG2[(tile * 2 + 0) * 64 + lane], acc[tile], 0, 0, 0);
        acc[tile] = __builtin_amdgcn_mfma_f32_16x16x32_bf16(a1, wfG2[(tile * 2 + 1) * 64 + lane], acc[tile], 0, 0, 0);
    }
    __syncthreads();
#pragma unroll
    for (int tile = 0; tile < 4; ++tile) {
        int col = tile * 16 + (lane & 15);
        float sc = g2[col] * BN_RSQRT;
        float sh = fmaf(b2[col], sc, bt2[col]);
#pragma unroll
        for (int q = 0; q < 4; ++q) {
            int row = (lane >> 4) * 4 + q;
            float v = fmaxf(fmaf(acc[tile][q], sc, sh), 0.0f);
            *(short*)(zt + row * 128 + ((col * 2) ^ ((row & 7) << 4))) = (short)f2bf(v);
        }
    }
    __syncthreads();

    if (FINAL == 0) {
#pragma unroll
        for (int half = 0; half < 2; ++half) {
            int row = (lane >> 3) + half * 8;
            short8 vv = *(const short8*)(zt + row * 128 + ((((lane & 7) * 16)) ^ ((row & 7) << 4)));
            int ro = self_tab[row];
            if (ro < (nrows << 6)) {
                unsigned w0 = fp8_enc4(us2f((unsigned short)vv[0]), us2f((unsigned short)vv[1]),
                                       us2f((unsigned short)vv[2]), us2f((unsigned short)vv[3]));
                unsigned w1 = fp8_enc4(us2f((unsigned short)vv[4]), us2f((unsigned short)vv[5]),
                                       us2f((unsigned short)vv[6]), us2f((unsigned short)vv[7]));
                *(uint2*)(out + ro + (lane & 7) * 8) = make_uint2(w0, w1);
            }
        }
    } else {
        // ---- GEMM3: relu(h4 @ Wl1 + bl1) ----
        {
            int rr = lane & 15;
            a0 = *(const short8*)(zt + rr * 128 + (((lane >> 4) * 16) ^ ((rr & 7) << 4)));
            a1 = *(const short8*)(zt + rr * 128 + ((64 + (lane >> 4) * 16) ^ ((rr & 7) << 4)));
        }
#pragma unroll
        for (int tile = 0; tile < 4; ++tile) {
            acc[tile] = (f32x4){0.f, 0.f, 0.f, 0.f};
            acc[tile] = __builtin_amdgcn_mfma_f32_16x16x32_bf16(a0, wfL1[(tile * 2 + 0) * 64 + lane], acc[tile], 0, 0, 0);
            acc[tile] = __builtin_amdgcn_mfma_f32_16x16x32_bf16(a1, wfL1[(tile * 2 + 1) * 64 + lane], acc[tile], 0, 0, 0);
        }
        __syncthreads();
#pragma unroll
        for (int tile = 0; tile < 4; ++tile) {
            int col = tile * 16 + (lane & 15);
            float bia = bl1[col];
#pragma unroll
            for (int q = 0; q < 4; ++q) {
                int row = (lane >> 4) * 4 + q;
                float v = fmaxf(acc[tile][q] + bia, 0.0f);
                *(short*)(zt + row * 128 + ((col * 2) ^ ((row & 7) << 4))) = (short)f2bf(v);
            }
        }
        __syncthreads();
        // ---- in-kernel mean-pool partials (natural order, batch sorted) ----
        float pacc = 0.0f;
        int curg = -1, rc = 0;
        for (int r = 0; r < 16; ++r) {
            int row = r0 + r;
            if (row >= nrows) break;
            float v = us2f(*(const unsigned short*)(zt + r * 128 + ((lane * 2) ^ ((r & 7) << 4))));
            int g = batch[row];
            if (g != curg) {
                if (curg >= 0) {
                    atomicAdd(&pooled[curg * HH + lane], pacc);
                    if (lane == 0) atomicAdd(&cnt[curg], (float)rc);
                }
                curg = g; pacc = v; rc = 1;
            } else { pacc += v; rc += 1; }
        }
        if (curg >= 0) {
            atomicAdd(&pooled[curg * HH + lane], pacc);
            if (lane == 0) atomicAdd(&cnt[curg], (float)rc);
        }
    }
}

__global__ __launch_bounds__(64) void head_kernel(
    const float* __restrict__ pooled, const float* __restrict__ cnt,
    const float* __restrict__ Wl2, const float* __restrict__ bl2,
    float* __restrict__ out, int ngraphs)
{
    int gidx = blockIdx.x * 64 + threadIdx.x;
    if (gidx >= ngraphs) return;
    float logits[CC];
#pragma unroll
    for (int c = 0; c < CC; ++c) logits[c] = bl2[c];
    float inv_n = 1.0f / fmaxf(cnt[gidx], 1.0f);
    for (int k = 0; k < HH; ++k) {
        float p = pooled[gidx * HH + k] * inv_n;
#pragma unroll
        for (int c = 0; c < CC; ++c) logits[c] = fmaf(p, Wl2[k * CC + c], logits[c]);
    }
    float m = logits[0];
#pragma unroll
    for (int c = 1; c < CC; ++c) m = fmaxf(m, logits[c]);
    float ssum = 0.0f;
#pragma unroll
    for (int c = 0; c < CC; ++c) { logits[c] = __expf(logits[c] - m); ssum += logits[c]; }
    float inv = 1.0f / ssum;
#pragma unroll
    for (int c = 0; c < CC; ++c) out[gidx * CC + c] = logits[c] * inv;
}

extern "C" void kernel_launch(void* const* d_in, const int* in_sizes, int n_in,
                              void* d_out, int out_size, void* d_ws, size_t ws_size,
                              hipStream_t stream) {
    const float* x      = (const float*)d_in[0];
    const int*   ei     = (const int*)  d_in[1];
    const int*   batch  = (const int*)  d_in[3];
    const float* W0     = (const float*)d_in[4];
    const float* b0     = (const float*)d_in[5];
    const float* convW1 = (const float*)d_in[6];
    const float* convb1 = (const float*)d_in[7];
    const float* convg1 = (const float*)d_in[8];
    const float* convbt1= (const float*)d_in[9];
    const float* convW2 = (const float*)d_in[10];
    const float* convb2 = (const float*)d_in[11];
    const float* convg2 = (const float*)d_in[12];
    const float* convbt2= (const float*)d_in[13];
    const float* Wl1    = (const float*)d_in[14];
    const float* bl1    = (const float*)d_in[15];
    const float* Wl2    = (const float*)d_in[16];
    const float* bl2    = (const float*)d_in[17];

    const int N = in_sizes[0] / FF;
    const int E = in_sizes[1] / 2;
    const int G = out_size / CC;

    const int* src = ei;
    const int* dst = ei + E;

    size_t off = 0;
    auto take = [&](size_t bytes) { size_t p = off; off = (off + bytes + 255) & ~255ULL; return p; };
    int NB = (N + 255) / 256;
    int EB = (E + 255) / 256;
    size_t o_rowptr = take((size_t)N * 4);
    size_t o_deg    = take((size_t)N * 4);
    size_t o_csr    = take((size_t)(E > NB ? E : NB) * 4 + 512);
    size_t o_perm   = take((size_t)N * 4);
    size_t o_dhist  = take(64 * 4);
    size_t o_dcnt   = take(64 * 4);
    size_t o_pooled = take((size_t)G * HH * 4);
    size_t o_cnt    = take((size_t)G * 4);
    size_t o_wfrag  = take((size_t)5632 * 8 * 2);
    size_t o_hA     = take((size_t)(N + 1) * 64);
    size_t o_hB     = take((size_t)(N + 1) * 64);

    char* base = (char*)d_ws;
    int*    rowptr = (int*)(base + o_rowptr);
    int*    deg    = (int*)(base + o_deg);
    int*    csr    = (int*)(base + o_csr);
    int*    perm   = (int*)(base + o_perm);
    int*    dhist  = (int*)(base + o_dhist);
    int*    dcnt   = (int*)(base + o_dcnt);
    float*  pooled = (float*)(base + o_pooled);
    float*  cnt    = (float*)(base + o_cnt);
    short*  wfrag  = (short*)(base + o_wfrag);
    short8* wf8    = (short8*)wfrag;
    unsigned char* hA = (unsigned char*)(base + o_hA);
    unsigned char* hB = (unsigned char*)(base + o_hB);

    int lin0_blocks = (N + 63) / 64;     // 4 waves x 16 rows
    int layer_blocks = (N + 15) / 16;    // 1 wave x 16 rows

    // weight fragment packing
    pack_weights_kernel<<<22, 256, 0, stream>>>(W0, convW1, convW2, Wl1, wfrag);

    // CSR build
    (void)hipMemsetAsync(deg, 0, (size_t)N * sizeof(int), stream);
    hist_kernel<<<EB, 256, 0, stream>>>(dst, deg, E);
    scan_block_kernel<<<NB, 256, 0, stream>>>(deg, rowptr, csr /*partials*/, N);
    scan_partials_kernel<<<1, 256, 0, stream>>>(csr, NB);
    add_offsets_kernel<<<NB, 256, 0, stream>>>(rowptr, csr, N);
    (void)hipMemsetAsync(deg, 0, (size_t)N * sizeof(int), stream);
    {
        int nspan = (N + 7) / 8;
        place_kernel<<<640, 256, 0, stream>>>(src, dst, rowptr, deg, csr, E, N, nspan);
    }

    // degree bucketing (uses restored deg)
    (void)hipMemsetAsync(dhist, 0, 64 * sizeof(int), stream);
    deg_hist_kernel<<<NB, 256, 0, stream>>>(deg, dhist, N);
    bucket_scan_kernel<<<1, 64, 0, stream>>>(dhist, dcnt);
    perm_place_kernel<<<NB, 256, 0, stream>>>(deg, dcnt, perm, N);

    // zero rows (index N) of both h buffers
    (void)hipMemsetAsync(hA + (size_t)N * 64, 0, 64, stream);
    (void)hipMemsetAsync(hB + (size_t)N * 64, 0, 64, stream);

    // lin0
    lin0_kernel<<<lin0_blocks, 256, 0, stream>>>(x, wf8, b0, hA, N);

    // pooled/cnt init
    (void)hipMemsetAsync(pooled, 0, (size_t)G * HH * sizeof(float), stream);
    (void)hipMemsetAsync(cnt, 0, (size_t)G * sizeof(float), stream);

    // layers (ping-pong); 0..2 degree-bucketed, last natural + fused pool
    const unsigned char* hin = hA; unsigned char* hout = hB;
    const short8* wfL1 = wf8 + 5120;
    for (int l = 0; l < LL; ++l) {
        const short8* wfG1 = wf8 + 1024 + (size_t)(l * 2 + 0) * 512;
        const short8* wfG2 = wf8 + 1024 + (size_t)(l * 2 + 1) * 512;
        if (l < LL - 1) {
            layer_kernel<0><<<layer_blocks, 64, 0, stream>>>(
                hin, rowptr, deg, csr, perm, wfG1, wfG2,
                convb1 + l * HH, convg1 + l * HH, convbt1 + l * HH,
                convb2 + l * HH, convg2 + l * HH, convbt2 + l * HH,
                hout, N, nullptr, nullptr, nullptr, nullptr, nullptr);
        } else {
            layer_kernel<1><<<layer_blocks, 64, 0, stream>>>(
                hin, rowptr, deg, csr, nullptr, wfG1, wfG2,
                convb1 + l * HH, convg1 + l * HH, convbt1 + l * HH,
                convb2 + l * HH, convg2 + l * HH, convbt2 + l * HH,
                nullptr, N, wfL1, bl1, batch, pooled, cnt);
        }
        unsigned char* tswap = (unsigned char*)hin; hin = hout; hout = tswap;
    }

    head_kernel<<<(G + 63) / 64, 64, 0, stream>>>(pooled, cnt, Wl2, bl2, (float*)d_out, G);
}